// Round 7
// baseline (980.990 us; speedup 1.0000x reference)
//
#include <hip/hip_runtime.h>
#include <hip/hip_bf16.h>
#include <stdint.h>

typedef __hip_bfloat16 bf16;
typedef __bf16 bf16x8 __attribute__((ext_vector_type(8)));
typedef float floatx4 __attribute__((ext_vector_type(4)));

#define AS_LDS __attribute__((address_space(3)))
#define AS_GLB __attribute__((address_space(1)))

__device__ __forceinline__ void gload_lds16(const bf16* g, bf16* l) {
    __builtin_amdgcn_global_load_lds((const AS_GLB void*)g, (AS_LDS void*)l, 16, 0, 0);
}

// ---------- dtype probe: *flag = 1 if x is fp32, 0 if bf16 ----------
__global__ void probe_dtype(const float* __restrict__ x, int* __restrict__ flag) {
    __shared__ int cnt;
    if (threadIdx.x == 0) cnt = 0;
    __syncthreads();
    int ok = 0;
    for (int i = threadIdx.x; i < 4096; i += 256) {
        float v = x[i];
        if (v == v && fabsf(v) < 1.0e3f) ok++;
    }
    atomicAdd(&cnt, ok);
    __syncthreads();
    if (threadIdx.x == 0) *flag = (cnt > 2048) ? 1 : 0;
}

__global__ __launch_bounds__(256) void zero_f32(float* __restrict__ p, int n) {
    int i = blockIdx.x * 256 + threadIdx.x;
    if (i < n) p[i] = 0.f;
}

// ---------- convert raw (fp32 or bf16 per flag) -> canonical bf16 ----------
__global__ __launch_bounds__(256) void convert_to_bf16(
    const void* __restrict__ in, bf16* __restrict__ out, long n,
    const int* __restrict__ flag)
{
    long i = ((long)blockIdx.x * 256 + threadIdx.x) * 8;
    if (i >= n) return;
    bf16 o[8];
    if (*flag) {
        const float* p = (const float*)in + i;
        float4 a = *(const float4*)p;
        float4 b = *(const float4*)(p + 4);
        o[0] = __float2bfloat16(a.x); o[1] = __float2bfloat16(a.y);
        o[2] = __float2bfloat16(a.z); o[3] = __float2bfloat16(a.w);
        o[4] = __float2bfloat16(b.x); o[5] = __float2bfloat16(b.y);
        o[6] = __float2bfloat16(b.z); o[7] = __float2bfloat16(b.w);
    } else {
        *(float4*)o = *(const float4*)((const bf16*)in + i);
    }
    *(float4*)&out[i] = *(float4*)o;
}

// ---------- emit canonical bf16 -> d_out in flag dtype (fallback tiers) ----
__global__ __launch_bounds__(256) void emit_out(
    const bf16* __restrict__ in, void* __restrict__ out, long n,
    const int* __restrict__ flag)
{
    long i = ((long)blockIdx.x * 256 + threadIdx.x) * 8;
    if (i >= n) return;
    bf16 v[8];
    *(float4*)v = *(const float4*)&in[i];
    if (*flag) {
        float* o = (float*)out + i;
        float4 a, b;
        a.x = __bfloat162float(v[0]); a.y = __bfloat162float(v[1]);
        a.z = __bfloat162float(v[2]); a.w = __bfloat162float(v[3]);
        b.x = __bfloat162float(v[4]); b.y = __bfloat162float(v[5]);
        b.z = __bfloat162float(v[6]); b.w = __bfloat162float(v[7]);
        *(float4*)o = a;
        *(float4*)(o + 4) = b;
    } else {
        *(float4*)((bf16*)out + i) = *(float4*)v;
    }
}

// ---------- transpose raw-dtype input -> bf16 output ----------
__global__ __launch_bounds__(256) void transpose_any(
    const void* __restrict__ inv, bf16* __restrict__ out,
    int ldin, int ldout, const int* __restrict__ flag)
{
    __shared__ bf16 tile[64][80];
    const int fp32 = *flag;
    const int c0 = blockIdx.x * 64;
    const int r0 = blockIdx.y * 64;
    const int tid = threadIdx.x;
#pragma unroll
    for (int it = 0; it < 2; ++it) {
        int ch = tid + it * 256;
        int r = ch >> 3, c = (ch & 7) * 8;
        long eidx = (long)(r0 + r) * ldin + (c0 + c);
        if (fp32) {
            const float* p = (const float*)inv + eidx;
            float4 a = *(const float4*)p;
            float4 b = *(const float4*)(p + 4);
            bf16 o[8];
            o[0] = __float2bfloat16(a.x); o[1] = __float2bfloat16(a.y);
            o[2] = __float2bfloat16(a.z); o[3] = __float2bfloat16(a.w);
            o[4] = __float2bfloat16(b.x); o[5] = __float2bfloat16(b.y);
            o[6] = __float2bfloat16(b.z); o[7] = __float2bfloat16(b.w);
            *(float4*)&tile[r][c] = *(float4*)o;
        } else {
            *(float4*)&tile[r][c] = *(const float4*)((const bf16*)inv + eidx);
        }
    }
    __syncthreads();
#pragma unroll
    for (int it = 0; it < 2; ++it) {
        int ch = tid + it * 256;
        int oc = ch >> 3, rb = (ch & 7) * 8;
        bf16 tmp[8];
#pragma unroll
        for (int i = 0; i < 8; ++i) tmp[i] = tile[rb + i][oc];
        *(float4*)&out[(long)(c0 + oc) * ldout + r0 + rb] = *(float4*)tmp;
    }
}

// ---------- pure-bf16 transpose (fallback tiers) ----------
__global__ __launch_bounds__(256) void transpose_bf16(
    const bf16* __restrict__ in, bf16* __restrict__ out,
    int ldin, int ldout,
    int nz1, long in_z1, long out_z1, long in_z2, long out_z2)
{
    __shared__ bf16 tile[64][80];
    const int z = blockIdx.z;
    const int z1 = z % nz1, z2 = z / nz1;
    in  += (long)z1 * in_z1 + (long)z2 * in_z2;
    out += (long)z1 * out_z1 + (long)z2 * out_z2;
    const int c0 = blockIdx.x * 64;
    const int r0 = blockIdx.y * 64;
    const int tid = threadIdx.x;
#pragma unroll
    for (int it = 0; it < 2; ++it) {
        int ch = tid + it * 256;
        int r = ch >> 3, c = (ch & 7) * 8;
        *(float4*)&tile[r][c] = *(const float4*)&in[(long)(r0 + r) * ldin + c0 + c];
    }
    __syncthreads();
#pragma unroll
    for (int it = 0; it < 2; ++it) {
        int ch = tid + it * 256;
        int oc = ch >> 3, rb = (ch & 7) * 8;
        bf16 tmp[8];
#pragma unroll
        for (int i = 0; i < 8; ++i) tmp[i] = tile[rb + i][oc];
        *(float4*)&out[(long)(c0 + oc) * ldout + r0 + rb] = *(float4*)tmp;
    }
}

// =====================================================================
// 256x256-tile 8-wave 8-phase GEMM. C = A * Bt^T.
// MODE 1 (QK, swapped A=K,B=Q): S[q][s]=exp(acc), 8B stores (NOT
//   nontemporal: S is read exactly once by PV -> let it live in L2/L3);
//   accumulates rowsum L[q] via cross-lane reduce + fp32 atomicAdd.
// MODE 4 (QKV): Q|K part via 4x4 shuffle transpose -> 8B row stores;
//   V part written transposed to Vt.
// SWZ 1: head-per-XCD for grid (8,8,8). SWZ 2: 6-ntile chunks, grid (48,8,1).
// =====================================================================
template <int MODE, int SWZ>
__global__ __launch_bounds__(512, 2) void gemm256(
    const bf16* __restrict__ A, const bf16* __restrict__ Bt,
    bf16* __restrict__ C, const bf16* __restrict__ bias,
    int lda, int ldb, int ldc,
    long az, long bz, long cz, int K, float scale, int qcols,
    bf16* __restrict__ Vt, int vcol0, float* __restrict__ Lsum)
{
    __shared__ bf16 AsL[2][2][256 * 32];
    __shared__ bf16 BsL[2][2][256 * 32];

    const int tid  = threadIdx.x;
    const int lane = tid & 63;
    const int wave = tid >> 6;
    const int wr = wave >> 2;        // 0..1  row half of C tile
    const int wc = wave & 3;         // 0..3  col quarter of C tile
    const int lm = lane & 15;
    const int cl = lane >> 4;        // fragment k-chunk 0..3

    int bxx = blockIdx.x, byy = blockIdx.y, bzz = blockIdx.z;
    if constexpr (SWZ == 1) {        // grid (8,8,8): head z = XCD
        int flat = bxx + (byy << 3) + (bzz << 6);
        int xcd = flat & 7, idx = flat >> 3;
        bzz = xcd; bxx = idx & 7; byy = idx >> 3;
    } else if constexpr (SWZ == 2) { // grid (48,8,1): 6 n-tiles per XCD
        int flat = bxx + byy * 48;
        int xcd = flat & 7, idx = flat >> 3;
        bxx = xcd * 6 + idx % 6; byy = idx / 6; bzz = 0;
    }
    const long zz = bzz;
    A  += zz * az;
    Bt += zz * bz;
    C  += zz * cz;
    float* Lz = (MODE == 1) ? (Lsum + zz * 2048) : nullptr;
    const int m0 = byy * 256;
    const int n0 = bxx * 256;

    // per-lane swizzled ds_read offsets within a [256][32] k-half block
    int offA[8], offB[4];
#pragma unroll
    for (int i = 0; i < 8; ++i) {
        int row = wr * 128 + i * 16 + lm;
        offA[i] = row * 32 + ((cl ^ ((row >> 1) & 3)) << 3);
    }
#pragma unroll
    for (int j = 0; j < 4; ++j) {
        int row = wc * 64 + j * 16 + lm;
        offB[j] = row * 32 + ((cl ^ ((row >> 1) & 3)) << 3);
    }

    const int sr = lane >> 2;        // staging row-in-16
    const int sc = lane & 3;         // staging chunk
    const int NT = K >> 6;           // 64-wide K tiles (NT even)

    floatx4 acc[8][4];
#pragma unroll
    for (int i = 0; i < 8; ++i)
#pragma unroll
        for (int j = 0; j < 4; ++j)
            acc[i][j] = (floatx4){0.f, 0.f, 0.f, 0.f};

    // stage one (operand, khalf) unit of tile t: 2 x global_load_lds
    auto stageU = [&](int which, int t, int kh) {
        if (t >= NT) return;
        const bf16* G = which ? Bt : A;
        const int ldg  = which ? ldb : lda;
        const int g0   = which ? n0 : m0;
        bf16* lb = which ? &BsL[t & 1][kh][0] : &AsL[t & 1][kh][0];
        const int kcol = t * 64 + kh * 32;
#pragma unroll
        for (int ii = 0; ii < 2; ++ii) {
            int row = ii * 128 + wave * 16 + sr;
            int cg  = sc ^ ((row >> 1) & 3);   // pre-swizzled global chunk
            gload_lds16(G + (long)(g0 + row) * ldg + kcol + cg * 8,
                        lb + row * 32 + sc * 8);
        }
    };

    bf16x8 af[8], bfv[2];
    auto dsA = [&](int b, int kh) {
        const bf16* p = &AsL[b][kh][0];
#pragma unroll
        for (int i = 0; i < 8; ++i) af[i] = *(const bf16x8*)(p + offA[i]);
    };
    auto dsB = [&](int b, int kh, int nh) {
        const bf16* p = &BsL[b][kh][0];
        bfv[0] = *(const bf16x8*)(p + offB[nh * 2]);
        bfv[1] = *(const bf16x8*)(p + offB[nh * 2 + 1]);
    };
    auto mfmaQ = [&](int nh) {
        __builtin_amdgcn_s_setprio(1);
#pragma unroll
        for (int i = 0; i < 8; ++i) {
            acc[i][nh * 2] = __builtin_amdgcn_mfma_f32_16x16x32_bf16(
                af[i], bfv[0], acc[i][nh * 2], 0, 0, 0);
            acc[i][nh * 2 + 1] = __builtin_amdgcn_mfma_f32_16x16x32_bf16(
                af[i], bfv[1], acc[i][nh * 2 + 1], 0, 0, 0);
        }
        __builtin_amdgcn_s_setprio(0);
    };

#define BAR    __builtin_amdgcn_s_barrier()
#define SBZ    __builtin_amdgcn_sched_barrier(0)
#define LGKM0  do { asm volatile("s_waitcnt lgkmcnt(0)" ::: "memory"); SBZ; } while (0)
#define VM(n)  do { asm volatile("s_waitcnt vmcnt(" #n ")" ::: "memory"); SBZ; } while (0)

    // ---- prologue: tile0 (all), tile1 k0 ----
    stageU(0, 0, 0); stageU(1, 0, 0); stageU(0, 0, 1); stageU(1, 0, 1);
    stageU(0, 1, 0); stageU(1, 1, 0);
    VM(4);
    BAR;

    for (int t0 = 0; t0 < NT; t0 += 2) {
        const bool last = (t0 + 2 >= NT);
        dsA(0, 0); dsB(0, 0, 0); stageU(0, t0 + 1, 1);
        BAR; LGKM0; mfmaQ(0); BAR;
        dsB(0, 0, 1); stageU(1, t0 + 1, 1);
        BAR; LGKM0; mfmaQ(1); BAR;
        dsA(0, 1); dsB(0, 1, 0); stageU(0, t0 + 2, 0);
        BAR; LGKM0; mfmaQ(0); BAR;
        dsB(0, 1, 1); stageU(1, t0 + 2, 0);
        BAR; LGKM0; mfmaQ(1);
        if (last) { VM(0); } else { VM(4); }
        BAR;
        dsA(1, 0); dsB(1, 0, 0); stageU(0, t0 + 2, 1);
        BAR; LGKM0; mfmaQ(0); BAR;
        dsB(1, 0, 1); stageU(1, t0 + 2, 1);
        BAR; LGKM0; mfmaQ(1); BAR;
        dsA(1, 1); dsB(1, 1, 0); stageU(0, t0 + 3, 0);
        BAR; LGKM0; mfmaQ(0); BAR;
        dsB(1, 1, 1); stageU(1, t0 + 3, 0);
        BAR; LGKM0; mfmaQ(1);
        if (!last) { VM(4); }
        BAR;
    }
#undef BAR
#undef SBZ
#undef LGKM0
#undef VM

    // ---- epilogue ----
    const int cr = (lane >> 4) * 4;
    if constexpr (MODE == 1) {
        // swapped operands: acc(row=s, col=q). Store S[q][s] = exp(acc):
        // lane holds 4 consecutive s -> 8B packet. Also rowsum -> atomic.
#pragma unroll
        for (int j = 0; j < 4; ++j) {
            long q = n0 + wc * 64 + j * 16 + lm;
            bf16* Cr = C + q * ldc + m0 + wr * 128;
            float rs = 0.f;
#pragma unroll
            for (int i = 0; i < 8; ++i) {
                bf16 pk[4];
#pragma unroll
                for (int r = 0; r < 4; ++r) {
                    float e = __expf(acc[i][j][r]);
                    rs += e;
                    pk[r] = __float2bfloat16(e);
                }
                *(uint64_t*)&Cr[i * 16 + cr] = *(const uint64_t*)pk;
            }
            rs += __shfl_xor(rs, 16);
            rs += __shfl_xor(rs, 32);
            if (cl == 0) atomicAdd(&Lz[q], rs);
        }
    } else {   // MODE 4
        if (n0 >= vcol0) {
            // V block: write transposed, packed 4 consecutive t per 8B store
#pragma unroll
            for (int j = 0; j < 4; ++j) {
                int col = n0 + wc * 64 + j * 16 + lm;
                float bv = __bfloat162float(bias[col]);
                int eg = col - vcol0;
                bf16* vt = Vt + ((long)(eg >> 9) * 512 + (eg & 511)) * 2048;
#pragma unroll
                for (int i = 0; i < 8; ++i) {
                    int t0v = m0 + wr * 128 + i * 16 + cr;
                    bf16 pk[4];
#pragma unroll
                    for (int r = 0; r < 4; ++r)
                        pk[r] = __float2bfloat16(acc[i][j][r] + bv);
                    *(uint64_t*)&vt[t0v] = *(const uint64_t*)pk;
                }
            }
        } else {
            // Q|K: bias+scale, then 4x4 shuffle transpose -> 8B row stores
            const int l4 = lane & 3;
            float bvj[4], scj[4];
#pragma unroll
            for (int j = 0; j < 4; ++j) {
                int col = n0 + wc * 64 + j * 16 + lm;
                bvj[j] = __bfloat162float(bias[col]);
                scj[j] = (col < qcols) ? scale : 1.0f;
            }
#pragma unroll
            for (int i = 0; i < 8; ++i) {
                int row = m0 + wr * 128 + i * 16 + cr + l4;
                bf16* Cr = C + (long)row * ldc + n0 + wc * 64 + (lm & ~3);
#pragma unroll
                for (int j = 0; j < 4; ++j) {
                    float x0 = (acc[i][j][0] + bvj[j]) * scj[j];
                    float x1 = (acc[i][j][1] + bvj[j]) * scj[j];
                    float x2 = (acc[i][j][2] + bvj[j]) * scj[j];
                    float x3 = (acc[i][j][3] + bvj[j]) * scj[j];
                    float u = __shfl_xor((l4 & 1) ? x0 : x1, 1);
                    float v = __shfl_xor((l4 & 1) ? x2 : x3, 1);
                    if (l4 & 1) { x0 = u; x2 = v; } else { x1 = u; x3 = v; }
                    u = __shfl_xor((l4 & 2) ? x0 : x2, 2);
                    v = __shfl_xor((l4 & 2) ? x1 : x3, 2);
                    if (l4 & 2) { x0 = u; x1 = v; } else { x2 = u; x3 = v; }
                    bf16 pk[4];
                    pk[0] = __float2bfloat16(x0); pk[1] = __float2bfloat16(x1);
                    pk[2] = __float2bfloat16(x2); pk[3] = __float2bfloat16(x3);
                    *(uint64_t*)&Cr[j * 16] = *(const uint64_t*)pk;
                }
            }
        }
    }
}

// =====================================================================
// PV kernel: BM=512(ch, full head) x BN=64(q) x K=2048(s). 144KB LDS.
// A = Vt [512 x T] (ld=T); B = S rows=q (ld=T). O[q][ch] = acc / L[q].
// S is read EXACTLY ONCE (each q-row owned by one block).
// 8 waves = 4 ch-quarters(128) x 2 q-halves(32); acc[8][2]/wave.
// Stage units: A-khalf = 4 gloads/thread, B-tile(64x64) = 1 gload/thread.
// vmcnt ledger: prologue {A00(4),B0(1),A01(4),A10(4)}=13, VM(4) -> first
// 9 landed. Steady: P1{+A11,B1:5}->9; P2{+A00':4}->13, VM(4) lands
// A10,A11,B1; P3{+A01',B0':5}->9; P4{+A10':4}->13, VM(4) lands A00',
// A01',B0'. Last iter: P2-end VM(0). Every stage is >=1 full barrier
// after its slot's last reader.
// B swizzle: 16B granule g at row r holds logical chunk g^(r&7); applied
// on pre-swizzled global source AND ds_read (involution, rule #21).
// SWZ: grid (32,1,8) -> head = flat&7 = XCD (Vt 2MB L2-resident/head).
// =====================================================================
__global__ __launch_bounds__(512, 2) void gemm_pv(
    const bf16* __restrict__ A, const bf16* __restrict__ Bt,
    bf16* __restrict__ C, const float* __restrict__ L,
    int lda, int ldb, int ldc, long az, long bz, long cz, int K)
{
    __shared__ bf16 AsL[2][2][512 * 32];
    __shared__ bf16 BsL[2][64 * 64];

    const int tid  = threadIdx.x;
    const int lane = tid & 63;
    const int wave = tid >> 6;
    const int wm = wave >> 1;        // 0..3  ch-quarter (128 rows)
    const int wn = wave & 1;         // 0..1  q-half (32 cols)
    const int lm = lane & 15;
    const int cl = lane >> 4;

    int flat = blockIdx.x + (blockIdx.z << 5);   // grid (32,1,8)
    const long zz = flat & 7;                    // head = XCD
    const int qt = flat >> 3;                    // q-tile 0..31
    A  += zz * az;
    Bt += zz * bz;
    C  += zz * cz;
    const float* Lz = L + zz * 2048;
    const int n0 = qt * 64;

    int offA[8];
#pragma unroll
    for (int i = 0; i < 8; ++i) {
        int row = wm * 128 + i * 16 + lm;
        offA[i] = row * 32 + ((cl ^ ((row >> 1) & 3)) << 3);
    }
    int rB[2], gB0[2];
#pragma unroll
    for (int j = 0; j < 2; ++j) {
        rB[j] = wn * 32 + j * 16 + lm;
        gB0[j] = rB[j] & 7;
    }

    const int sr = lane >> 2;
    const int sc = lane & 3;
    const int NT = K >> 6;           // 32, even

    floatx4 acc[8][2];
#pragma unroll
    for (int i = 0; i < 8; ++i)
#pragma unroll
        for (int j = 0; j < 2; ++j)
            acc[i][j] = (floatx4){0.f, 0.f, 0.f, 0.f};

    auto stageA = [&](int t, int kh) {   // 4 loads/thread
        if (t >= NT) return;
        bf16* lb = &AsL[t & 1][kh][0];
        const int kcol = t * 64 + kh * 32;
#pragma unroll
        for (int seg = 0; seg < 4; ++seg) {
            int row = seg * 128 + wave * 16 + sr;
            int cg  = sc ^ ((row >> 1) & 3);
            gload_lds16(A + (long)row * lda + kcol + cg * 8,
                        lb + row * 32 + sc * 8);
        }
    };
    auto stageB = [&](int t) {           // 1 load/thread
        if (t >= NT) return;
        bf16* lb = &BsL[t & 1][0];
        const int kcol = t * 64;
        int row = wave * 8 + (lane >> 3);
        int cg  = (lane & 7) ^ (row & 7);
        gload_lds16(Bt + (long)(n0 + row) * ldb + kcol + cg * 8,
                    lb + row * 64 + (lane & 7) * 8);
    };

    bf16x8 af[8], bfv[2];
    auto dsA = [&](int b, int kh) {
        const bf16* p = &AsL[b][kh][0];
#pragma unroll
        for (int i = 0; i < 8; ++i) af[i] = *(const bf16x8*)(p + offA[i]);
    };
    auto dsB = [&](int b, int kh) {
        const bf16* p = &BsL[b][0];
#pragma unroll
        for (int j = 0; j < 2; ++j) {
            int g = (kh * 4 + cl) ^ gB0[j];
            bfv[j] = *(const bf16x8*)(p + rB[j] * 64 + g * 8);
        }
    };
    auto mfmaQ = [&]() {
        __builtin_amdgcn_s_setprio(1);
#pragma unroll
        for (int i = 0; i < 8; ++i) {
            acc[i][0] = __builtin_amdgcn_mfma_f32_16x16x32_bf16(
                af[i], bfv[0], acc[i][0], 0, 0, 0);
            acc[i][1] = __builtin_amdgcn_mfma_f32_16x16x32_bf16(
                af[i], bfv[1], acc[i][1], 0, 0, 0);
        }
        __builtin_amdgcn_s_setprio(0);
    };

#define BAR    __builtin_amdgcn_s_barrier()
#define SBZ    __builtin_amdgcn_sched_barrier(0)
#define LGKM0  do { asm volatile("s_waitcnt lgkmcnt(0)" ::: "memory"); SBZ; } while (0)
#define VM(n)  do { asm volatile("s_waitcnt vmcnt(" #n ")" ::: "memory"); SBZ; } while (0)

    // prologue: A00(4), B0(1), A01(4), A10(4) = 13; VM(4) lands first 9
    stageA(0, 0); stageB(0); stageA(0, 1); stageA(1, 0);
    VM(4);
    BAR;

    for (int t0 = 0; t0 < NT; t0 += 2) {
        const bool last = (t0 + 2 >= NT);
        // P1: tile t0, khalf0
        dsA(0, 0); dsB(0, 0); stageA(t0 + 1, 1); stageB(t0 + 1);
        BAR; LGKM0; mfmaQ(); BAR;
        // P2: tile t0, khalf1
        dsA(0, 1); dsB(0, 1); stageA(t0 + 2, 0);
        BAR; LGKM0; mfmaQ();
        if (last) { VM(0); } else { VM(4); }
        BAR;
        // P3: tile t0+1, khalf0
        dsA(1, 0); dsB(1, 0); stageA(t0 + 2, 1); stageB(t0 + 2);
        BAR; LGKM0; mfmaQ(); BAR;
        // P4: tile t0+1, khalf1
        dsA(1, 1); dsB(1, 1); stageA(t0 + 3, 0);
        BAR; LGKM0; mfmaQ();
        if (!last) { VM(4); }
        BAR;
    }
#undef BAR
#undef SBZ
#undef LGKM0
#undef VM

    // epilogue: acc rows = ch, cols = q; 8B packets into O[q][ch]
#pragma unroll
    for (int j = 0; j < 2; ++j) {
        int col = n0 + wn * 32 + j * 16 + lm;   // q
        float inv = 1.0f / Lz[col];
        bf16* Cr = C + (long)col * ldc + wm * 128;
#pragma unroll
        for (int i = 0; i < 8; ++i) {
            bf16 pk[4];
#pragma unroll
            for (int r = 0; r < 4; ++r)
                pk[r] = __float2bfloat16(acc[i][j][r] * inv);
            *(uint64_t*)&Cr[i * 16 + cl * 4] = *(const uint64_t*)pk;
        }
    }
}

// =====================================================================
// 128(M)x256(N)-tile 8-wave 8-phase GEMM (out-proj split-K). 96KB LDS.
// MODE 6: P[t][ch] = acc partial, z = k-split (kbase = z*kper).
// SWZ 6: chunked remap, grid (32,4,2).
// =====================================================================
template <int MODE, int SWZ>
__global__ __launch_bounds__(512, 2) void gemm128n(
    const bf16* __restrict__ A, const bf16* __restrict__ Bt,
    bf16* __restrict__ C, const float* __restrict__ L,
    int lda, int ldb, int ldc,
    long az, long bz, long cz, int K, int kper)
{
    __shared__ bf16 AsL[2][2][128 * 32];
    __shared__ bf16 BsL[2][2][256 * 32];

    const int tid  = threadIdx.x;
    const int lane = tid & 63;
    const int wave = tid >> 6;
    const int wr = wave >> 2;        // 0..1  m-half (64 rows)
    const int wc = wave & 3;         // 0..3  n-quarter (64 cols)
    const int lm = lane & 15;
    const int cl = lane >> 4;

    int bxx = blockIdx.x, byy = blockIdx.y, bzz = blockIdx.z;
    if constexpr (SWZ == 5) {        // grid (8,4,8): head z = XCD
        int flat = bxx + (byy << 3) + (bzz << 5);
        int xcd = flat & 7, idx = flat >> 3;
        bzz = xcd; bxx = idx & 7; byy = idx >> 3;
    } else if constexpr (SWZ == 6) { // grid (32,4,2): chunked remap
        int flat = bxx + (byy << 5) + (bzz << 7);
        int nf = (flat & 7) * 32 + (flat >> 3);
        bzz = nf >> 7; int rr = nf & 127; byy = rr >> 5; bxx = rr & 31;
    }
    const long zz = bzz;
    A  += zz * az;
    Bt += zz * bz;
    C  += zz * cz;
    const float* Lz = (MODE == 5) ? (L + zz * 2048) : nullptr;
    const int kbase = (int)(zz * (long)kper);
    const int m0 = byy * 128;
    const int n0 = bxx * 256;

    int offA[4], offB[4];
#pragma unroll
    for (int i = 0; i < 4; ++i) {
        int row = wr * 64 + i * 16 + lm;
        offA[i] = row * 32 + ((cl ^ ((row >> 1) & 3)) << 3);
    }
#pragma unroll
    for (int j = 0; j < 4; ++j) {
        int row = wc * 64 + j * 16 + lm;
        offB[j] = row * 32 + ((cl ^ ((row >> 1) & 3)) << 3);
    }

    const int sr = lane >> 2;
    const int sc = lane & 3;
    const int NT = K >> 6;           // even

    floatx4 acc[4][4];
#pragma unroll
    for (int i = 0; i < 4; ++i)
#pragma unroll
        for (int j = 0; j < 4; ++j)
            acc[i][j] = (floatx4){0.f, 0.f, 0.f, 0.f};

    auto stageA = [&](int t, int kh) {   // 1 load/thread
        if (t >= NT) return;
        bf16* lb = &AsL[t & 1][kh][0];
        const int kcol = kbase + t * 64 + kh * 32;
        int row = wave * 16 + sr;
        int cg  = sc ^ ((row >> 1) & 3);
        gload_lds16(A + (long)(m0 + row) * lda + kcol + cg * 8,
                    lb + row * 32 + sc * 8);
    };
    auto stageB = [&](int t, int kh) {   // 2 loads/thread
        if (t >= NT) return;
        bf16* lb = &BsL[t & 1][kh][0];
        const int kcol = kbase + t * 64 + kh * 32;
#pragma unroll
        for (int ii = 0; ii < 2; ++ii) {
            int row = ii * 128 + wave * 16 + sr;
            int cg  = sc ^ ((row >> 1) & 3);
            gload_lds16(Bt + (long)(n0 + row) * ldb + kcol + cg * 8,
                        lb + row * 32 + sc * 8);
        }
    };

    bf16x8 af[4], bfv[2];
    auto dsA = [&](int b, int kh) {
        const bf16* p = &AsL[b][kh][0];
#pragma unroll
        for (int i = 0; i < 4; ++i) af[i] = *(const bf16x8*)(p + offA[i]);
    };
    auto dsB = [&](int b, int kh, int nh) {
        const bf16* p = &BsL[b][kh][0];
        bfv[0] = *(const bf16x8*)(p + offB[nh * 2]);
        bfv[1] = *(const bf16x8*)(p + offB[nh * 2 + 1]);
    };
    auto mfmaQ = [&](int nh) {
        __builtin_amdgcn_s_setprio(1);
#pragma unroll
        for (int i = 0; i < 4; ++i) {
            acc[i][nh * 2] = __builtin_amdgcn_mfma_f32_16x16x32_bf16(
                af[i], bfv[0], acc[i][nh * 2], 0, 0, 0);
            acc[i][nh * 2 + 1] = __builtin_amdgcn_mfma_f32_16x16x32_bf16(
                af[i], bfv[1], acc[i][nh * 2 + 1], 0, 0, 0);
        }
        __builtin_amdgcn_s_setprio(0);
    };

#define BAR    __builtin_amdgcn_s_barrier()
#define SBZ    __builtin_amdgcn_sched_barrier(0)
#define LGKM0  do { asm volatile("s_waitcnt lgkmcnt(0)" ::: "memory"); SBZ; } while (0)
#define VM(n)  do { asm volatile("s_waitcnt vmcnt(" #n ")" ::: "memory"); SBZ; } while (0)

    stageA(0, 0); stageB(0, 0); stageA(0, 1); stageB(0, 1);
    stageA(1, 0); stageB(1, 0);
    VM(3);
    BAR;

    for (int t0 = 0; t0 < NT; t0 += 2) {
        const bool last = (t0 + 2 >= NT);
        dsA(0, 0); dsB(0, 0, 0); stageA(t0 + 1, 1);
        BAR; LGKM0; mfmaQ(0); BAR;
        dsB(0, 0, 1); stageB(t0 + 1, 1);
        BAR; LGKM0; mfmaQ(1); BAR;
        dsA(0, 1); dsB(0, 1, 0); stageA(t0 + 2, 0);
        BAR; LGKM0; mfmaQ(0); BAR;
        dsB(0, 1, 1); stageB(t0 + 2, 0);
        BAR; LGKM0; mfmaQ(1);
        if (last) { VM(0); } else { VM(3); }
        BAR;
        dsA(1, 0); dsB(1, 0, 0); stageA(t0 + 2, 1);
        BAR; LGKM0; mfmaQ(0); BAR;
        dsB(1, 0, 1); stageB(t0 + 2, 1);
        BAR; LGKM0; mfmaQ(1); BAR;
        dsA(1, 1); dsB(1, 1, 0); stageA(t0 + 3, 0);
        BAR; LGKM0; mfmaQ(0); BAR;
        dsB(1, 1, 1); stageB(t0 + 3, 0);
        BAR; LGKM0; mfmaQ(1);
        if (!last) { VM(3); }
        BAR;
    }
#undef BAR
#undef SBZ
#undef LGKM0
#undef VM

    const int cr = cl * 4;
#pragma unroll
    for (int j = 0; j < 4; ++j) {
        int col = n0 + wc * 64 + j * 16 + lm;
        bf16* Cr = C + (long)col * ldc + m0 + wr * 64;
        float inv = 1.0f;
        if constexpr (MODE == 5) inv = 1.0f / Lz[col];
#pragma unroll
        for (int i = 0; i < 4; ++i) {
            bf16 pk[4];
#pragma unroll
            for (int r = 0; r < 4; ++r)
                pk[r] = __float2bfloat16(acc[i][j][r] * inv);
            *(uint64_t*)&Cr[i * 16 + cr] = *(const uint64_t*)pk;
        }
    }
}

// ---------- GEMM (bf16 in/out, fp32 acc), fallback tiers -----------------
template <int MODE, bool SWAP = false, int SWZ = 0>
__global__ __launch_bounds__(256) void gemm_bt(
    const bf16* __restrict__ A, const bf16* __restrict__ Bt,
    bf16* __restrict__ C, const bf16* __restrict__ bias,
    int lda, int ldb, int ldc,
    long az, long bz, long cz, int K, float scale, int qcols,
    bf16* __restrict__ Vt, int vcol0)
{
    __shared__ bf16 As[128 * 64];
    __shared__ bf16 Bs[128 * 64];

    const int tid  = threadIdx.x;
    const int lane = tid & 63;
    const int wave = tid >> 6;
    const int wx = wave & 1;
    const int wy = wave >> 1;

    int bxx = blockIdx.x, byy = blockIdx.y, bzz = blockIdx.z;
    const long zz = bzz;
    A  += zz * az;
    Bt += zz * bz;
    C  += zz * cz;
    const int bm = SWAP ? bxx : byy;
    const int bn = SWAP ? byy : bxx;
    const int m0 = bm * 128;
    const int n0 = bn * 128;

    const int lm = lane & 15;
    const int kq = (lane >> 4) * 8;

    floatx4 acc[4][4];
#pragma unroll
    for (int i = 0; i < 4; ++i)
#pragma unroll
        for (int j = 0; j < 4; ++j)
            acc[i][j] = (floatx4){0.f, 0.f, 0.f, 0.f};

    for (int kt = 0; kt < K; kt += 64) {
        __syncthreads();
#pragma unroll
        for (int it = 0; it < 4; ++it) {
            int ch = tid + it * 256;
            int r = ch >> 3;
            int c = (ch & 7) * 8;
            gload_lds16(A  + (long)(m0 + r) * lda + (kt + c), &As[ch * 8]);
            gload_lds16(Bt + (long)(n0 + r) * ldb + (kt + c), &Bs[ch * 8]);
        }
        __syncthreads();
#pragma unroll
        for (int kk = 0; kk < 64; kk += 32) {
            bf16x8 af[4], bfv[4];
#pragma unroll
            for (int i = 0; i < 4; ++i)
                af[i] = *(const bf16x8*)&As[(wy * 64 + i * 16 + lm) * 64 + kk + kq];
#pragma unroll
            for (int j = 0; j < 4; ++j)
                bfv[j] = *(const bf16x8*)&Bs[(wx * 64 + j * 16 + lm) * 64 + kk + kq];
#pragma unroll
            for (int i = 0; i < 4; ++i)
#pragma unroll
                for (int j = 0; j < 4; ++j)
                    acc[i][j] = __builtin_amdgcn_mfma_f32_16x16x32_bf16(
                        af[i], bfv[j], acc[i][j], 0, 0, 0);
        }
    }

    const int cr = (lane >> 4) * 4;
    if constexpr (MODE == 1) {
#pragma unroll
        for (int j = 0; j < 4; ++j) {
            int col = n0 + wx * 64 + j * 16 + lm;
#pragma unroll
            for (int i = 0; i < 4; ++i)
#pragma unroll
                for (int r = 0; r < 4; ++r) {
                    int row = m0 + wy * 64 + i * 16 + cr + r;
                    C[(long)row * ldc + col] = __float2bfloat16(__expf(acc[i][j][r]));
                }
        }
    } else {
#pragma unroll
        for (int j = 0; j < 4; ++j) {
            int col = n0 + wx * 64 + j * 16 + lm;
            float bv = (MODE == 0 && bias) ? __bfloat162float(bias[col]) : 0.f;
            float sc = (col < qcols) ? scale : 1.0f;
#pragma unroll
            for (int i = 0; i < 4; ++i) {
#pragma unroll
                for (int r = 0; r < 4; ++r) {
                    int row = m0 + wy * 64 + i * 16 + cr + r;
                    long idx = (long)row * ldc + col;
                    float v;
                    if (MODE == 2) v = acc[i][j][r] + __bfloat162float(C[idx]);
                    else           v = (acc[i][j][r] + bv) * sc;
                    C[idx] = __float2bfloat16(v);
                }
            }
        }
    }
}

// ---------- split-K GEMM, bf16 partials (fallback tiers) ------------------
template <bool SWAP = false>
__global__ __launch_bounds__(256) void gemm_bt_splitk(
    const bf16* __restrict__ A, const bf16* __restrict__ Bt,
    bf16* __restrict__ P, int lda, int ldb, int ldp,
    long az, long bz, long pz, long skStride, int nsk, int Kc)
{
    __shared__ bf16 As[128 * 64];
    __shared__ bf16 Bs[128 * 64];

    const int tid  = threadIdx.x;
    const int lane = tid & 63;
    const int wave = tid >> 6;
    const int wx = wave & 1;
    const int wy = wave >> 1;
    const int zz = blockIdx.z;
    const int ks = zz % nsk;
    const int zh = zz / nsk;
    A  += (long)zh * az;
    Bt += (long)zh * bz;
    bf16* Pz = P + (long)zh * pz + (long)ks * skStride;
    const int bm = SWAP ? blockIdx.x : blockIdx.y;
    const int bn = SWAP ? blockIdx.y : blockIdx.x;
    const int m0 = bm * 128;
    const int n0 = bn * 128;
    const int k0 = ks * Kc;

    const int lm = lane & 15;
    const int kq = (lane >> 4) * 8;

    floatx4 acc[4][4];
#pragma unroll
    for (int i = 0; i < 4; ++i)
#pragma unroll
        for (int j = 0; j < 4; ++j)
            acc[i][j] = (floatx4){0.f, 0.f, 0.f, 0.f};

    for (int kt = k0; kt < k0 + Kc; kt += 64) {
        __syncthreads();
#pragma unroll
        for (int it = 0; it < 4; ++it) {
            int ch = tid + it * 256;
            int r = ch >> 3;
            int c = (ch & 7) * 8;
            gload_lds16(A  + (long)(m0 + r) * lda + (kt + c), &As[ch * 8]);
            gload_lds16(Bt + (long)(n0 + r) * ldb + (kt + c), &Bs[ch * 8]);
        }
        __syncthreads();
#pragma unroll
        for (int kk = 0; kk < 64; kk += 32) {
            bf16x8 af[4], bfv[4];
#pragma unroll
            for (int i = 0; i < 4; ++i)
                af[i] = *(const bf16x8*)&As[(wy * 64 + i * 16 + lm) * 64 + kk + kq];
#pragma unroll
            for (int j = 0; j < 4; ++j)
                bfv[j] = *(const bf16x8*)&Bs[(wx * 64 + j * 16 + lm) * 64 + kk + kq];
#pragma unroll
            for (int i = 0; i < 4; ++i)
#pragma unroll
                for (int j = 0; j < 4; ++j)
                    acc[i][j] = __builtin_amdgcn_mfma_f32_16x16x32_bf16(
                        af[i], bfv[j], acc[i][j], 0, 0, 0);
        }
    }

    const int cr = (lane >> 4) * 4;
#pragma unroll
    for (int j = 0; j < 4; ++j) {
        int col = n0 + wx * 64 + j * 16 + lm;
#pragma unroll
        for (int i = 0; i < 4; ++i)
#pragma unroll
            for (int r = 0; r < 4; ++r) {
                int row = m0 + wy * 64 + i * 16 + cr + r;
                Pz[(long)row * ldp + col] = __float2bfloat16(acc[i][j][r]);
            }
    }
}

// ---------- reduce 2 bf16 split-K partials + bias -> d_out in flag dtype ----
__global__ __launch_bounds__(256) void reduce_emit(
    const bf16* __restrict__ P, const bf16* __restrict__ bias,
    void* __restrict__ out, long MN, int N,
    const int* __restrict__ flag)
{
    long i = ((long)blockIdx.x * 256 + threadIdx.x) * 8;
    if (i >= MN) return;
    bf16 bb[8], a[8], b[8];
    *(float4*)bb = *(const float4*)&bias[i & (N - 1)];
    *(float4*)a  = *(const float4*)&P[i];
    *(float4*)b  = *(const float4*)&P[MN + i];
    float s[8];
#pragma unroll
    for (int k = 0; k < 8; ++k)
        s[k] = __bfloat162float(bb[k]) + __bfloat162float(a[k]) + __bfloat162float(b[k]);
    if (*flag) {
        float* o = (float*)out + i;
        float4 lo = {s[0], s[1], s[2], s[3]};
        float4 hi = {s[4], s[5], s[6], s[7]};
        *(float4*)o = lo;
        *(float4*)(o + 4) = hi;
    } else {
        bf16 o[8];
#pragma unroll
        for (int k = 0; k < 8; ++k) o[k] = __float2bfloat16(s[k]);
        *(float4*)&((bf16*)out)[i] = *(float4*)o;
    }
}

// ---------- reduce bf16 split-K partials + bias -> bf16 (fallback) ----------
__global__ __launch_bounds__(256) void reduce_splitk(
    const bf16* __restrict__ P, const bf16* __restrict__ bias,
    bf16* __restrict__ Out, long MN, int N, int SK)
{
    long i = ((long)blockIdx.x * 256 + threadIdx.x) * 8;
    if (i >= MN) return;
    float s[8];
    if (bias) {
        bf16 bb[8];
        *(float4*)bb = *(const float4*)&bias[i & (N - 1)];
#pragma unroll
        for (int k = 0; k < 8; ++k) s[k] = __bfloat162float(bb[k]);
    } else {
#pragma unroll
        for (int k = 0; k < 8; ++k) s[k] = 0.f;
    }
    for (int z = 0; z < SK; ++z) {
        bf16 a[8];
        *(float4*)a = *(const float4*)&P[(long)z * MN + i];
#pragma unroll
        for (int k = 0; k < 8; ++k) s[k] += __bfloat162float(a[k]);
    }
    bf16 o[8];
#pragma unroll
    for (int k = 0; k < 8; ++k) o[k] = __float2bfloat16(s[k]);
    *(float4*)&Out[i] = *(float4*)o;
}

// ---------- in-place softmax over rows of 2048 bf16 (fallback tiers) -----
__global__ __launch_bounds__(256) void softmax_rows2048(bf16* __restrict__ S)
{
    __shared__ float red[8];
    const long row = blockIdx.x;
    bf16* p = S + row * 2048;
    const int tid = threadIdx.x;
    float4 raw = *(const float4*)&p[tid * 8];
    bf16 vb[8];
    *(float4*)vb = raw;
    float v[8];
#pragma unroll
    for (int i = 0; i < 8; ++i) v[i] = __bfloat162float(vb[i]);
    float m = v[0];
#pragma unroll
    for (int i = 1; i < 8; ++i) m = fmaxf(m, v[i]);
#pragma unroll
    for (int o = 32; o > 0; o >>= 1) m = fmaxf(m, __shfl_xor(m, o));
    if ((tid & 63) == 0) red[tid >> 6] = m;
    __syncthreads();
    m = fmaxf(fmaxf(red[0], red[1]), fmaxf(red[2], red[3]));
    float s = 0.f;
#pragma unroll
    for (int i = 0; i < 8; ++i) { v[i] = __expf(v[i] - m); s += v[i]; }
#pragma unroll
    for (int o = 32; o > 0; o >>= 1) s += __shfl_xor(s, o);
    if ((tid & 63) == 0) red[4 + (tid >> 6)] = s;
    __syncthreads();
    s = (red[4] + red[5]) + (red[6] + red[7]);
    float inv = 1.f / s;
#pragma unroll
    for (int i = 0; i < 8; ++i) vb[i] = __float2bfloat16(v[i] * inv);
    *(float4*)&p[tid * 8] = *(float4*)vb;
}

extern "C" void kernel_launch(void* const* d_in, const int* in_sizes, int n_in,
                              void* d_out, int out_size, void* d_ws, size_t ws_size,
                              hipStream_t stream)
{
    const int Bb = 4, T = 2048, E = 512, H = 8;
    const int HE = H * E;            // 4096
    const int N3 = 3 * HE;           // 12288
    const int N2 = 2 * HE;           // 8192 (Q|K row width)
    const int M  = Bb * T;           // 8192
    const long NX = (long)M * E;     // 4,194,304

    // ---- size-signature input assignment (order-robust) ----
    const void* xr = nullptr;
    const void* Wr[4] = {nullptr, nullptr, nullptr, nullptr};
    const void* br[3] = {nullptr, nullptr, nullptr};
    const void* bor = nullptr;
    int nw = 0, nb = 0;
    for (int i = 0; i < n_in; ++i) {
        int s = in_sizes[i];
        if      (s == (int)NX)      xr = d_in[i];
        else if (s == E * HE)       { if (nw < 4) Wr[nw++] = d_in[i]; }
        else if (s == HE)           { if (nb < 3) br[nb++] = d_in[i]; }
        else if (s == E)            bor = d_in[i];
    }
    if (!xr || nw < 4 || nb < 3 || !bor) {
        xr = d_in[0]; Wr[0] = d_in[1]; br[0] = d_in[2]; Wr[1] = d_in[3];
        br[1] = d_in[4]; Wr[2] = d_in[5]; br[2] = d_in[6]; Wr[3] = d_in[7];
        bor = d_in[8];
    }

    const float qscale = 0.04419417382415922f;  // 1/sqrt(512)
    const int   QC = 1 << 30;
    dim3 blk(256);

    // ---- workspace layout (bf16 elements) ----
    bf16* pool = (bf16*)d_ws;
    int*  flag = (int*)(void*)pool;
    bf16* xc   = pool + 8;
    bf16* bqc  = xc  + NX;
    bf16* bkc  = bqc + HE;
    bf16* bvc  = bkc + HE;
    bf16* boc  = bvc + HE;
    bf16* WqT  = boc + E;
    const size_t w2m = (size_t)E * HE;
    bf16* WkT  = WqT + w2m;
    bf16* WvT  = WkT + w2m;
    bf16* WoT  = WvT + w2m;
    bf16* Ofin = WoT + w2m;
    bf16* p0   = Ofin + NX;

    const size_t wsE    = ws_size / sizeof(bf16);
    const size_t fixedE = (size_t)(p0 - pool);
    const size_t wQK   = (size_t)T * N2;
    const size_t wQKV  = (size_t)T * N3;
    const size_t wBat  = (size_t)T * HE;
    const size_t wHd   = (size_t)T * E;
    const size_t sAll  = (size_t)H * T * T;
    const size_t sOne  = (size_t)T * T;
    const size_t wBig  = (size_t)M * HE;
    const size_t wL    = 32768;  // fp32 L[H][T] as bf16-el units
    const size_t needB2 = fixedE + wQK + wBat + sAll + wBig + wL;
    const size_t needB  = fixedE + wQKV + 2 * wBat + sAll;
    const size_t needC  = fixedE + 5 * wBat + sOne;
    const size_t needD  = fixedE + 5 * wHd  + sOne;
    if (wsE < needD) return;

    // ---- stage 0: dtype probe + canonicalize ----
    probe_dtype<<<dim3(1), blk, 0, stream>>>((const float*)xr, flag);
    convert_to_bf16<<<dim3((unsigned)((NX / 8 + 255) / 256)), blk, 0, stream>>>(
        xr, xc, NX, flag);
    convert_to_bf16<<<dim3(2), blk, 0, stream>>>(br[0], bqc, HE, flag);
    convert_to_bf16<<<dim3(2), blk, 0, stream>>>(br[1], bkc, HE, flag);
    convert_to_bf16<<<dim3(2), blk, 0, stream>>>(br[2], bvc, HE, flag);
    convert_to_bf16<<<dim3(1), blk, 0, stream>>>(bor, boc, E, flag);
    transpose_any<<<dim3(HE / 64, E / 64, 1), blk, 0, stream>>>(Wr[0], WqT, HE, E, flag);
    transpose_any<<<dim3(HE / 64, E / 64, 1), blk, 0, stream>>>(Wr[1], WkT, HE, E, flag);
    transpose_any<<<dim3(HE / 64, E / 64, 1), blk, 0, stream>>>(Wr[2], WvT, HE, E, flag);
    transpose_any<<<dim3(E / 64, HE / 64, 1), blk, 0, stream>>>(Wr[3], WoT, E, HE, flag);

    if (wsE >= needB2) {
        // ---- Tier B2: QKV (256²) -> zeroL -> QK (256², exp+L) ->
        //      PV (512x64, S read once) ; out-proj (128x256 split-K) ----
        bf16* QKb = p0;                  // [t, 8192] = Q|K; aliased for P later
        bf16* Vtb = QKb + wQK;           // [h,e,t]
        bf16* S   = Vtb + wBat;          // exp(scores) [h,t,s]
        bf16* Oatt = S + sAll;           // O_all [M, HE]
        float* Lbuf = (float*)(Oatt + wBig);   // fp32 [H][T]

        for (int b = 0; b < Bb; ++b) {
            const bf16* xb = xc + (size_t)b * T * E;
            gemm256<4, 2><<<dim3(N3 / 256, T / 256, 1), dim3(512), 0, stream>>>(
                xb, WqT, QKb, bqc, E, E, N2, 0, 0, 0, E, qscale, HE, Vtb, N2,
                nullptr);
            zero_f32<<<dim3(64), blk, 0, stream>>>(Lbuf, H * T);
            gemm256<1, 1><<<dim3(T / 256, T / 256, H), dim3(512), 0, stream>>>(
                QKb + HE, QKb, S, nullptr, N2, N2, T,
                (long)E, (long)E, (long)T * T, E, 1.f, QC, nullptr, 0, Lbuf);
            gemm_pv<<<dim3(T / 64, 1, H), dim3(512), 0, stream>>>(
                Vtb, S, Oatt + (size_t)b * T * HE, Lbuf, T, T, HE,
                (long)E * T, (long)T * T, (long)E, T);
        }
        // out-proj: A=WoT (rows=ch), B=Oatt (rows=t), split-K=2 via z
        gemm128n<6, 6><<<dim3(M / 256, E / 128, 2), dim3(512), 0, stream>>>(
            WoT, Oatt, QKb, nullptr, HE, HE, E,
            0, 0, (long)M * E, HE / 2, HE / 2);
        reduce_emit<<<dim3((unsigned)((NX / 8 + 255) / 256)), blk, 0, stream>>>(
            QKb, boc, d_out, NX, E, flag);
        return;
    }

    if (wsE >= needB) {
        // ---- Tier B fallback: softmax path ----
        bf16* QKVb = p0;
        bf16* Vtb  = QKVb + wQKV;
        bf16* Oatt = Vtb + wBat;
        bf16* S    = Oatt + wBat;

        for (int b = 0; b < Bb; ++b) {
            const bf16* xb = xc + (size_t)b * T * E;
            gemm_bt<0><<<dim3(N3 / 128, T / 128, 1), blk, 0, stream>>>(
                xb, WqT, QKVb, bqc, E, E, N3, 0, 0, 0, E, qscale, HE, nullptr, 0);
            transpose_bf16<<<dim3(E / 64, T / 64, H), blk, 0, stream>>>(
                QKVb + 2 * HE, Vtb, N3, T, H, (long)E, (long)E * T, 0, 0);
            gemm_bt<0><<<dim3(T / 128, T / 128, H), blk, 0, stream>>>(
                QKVb, QKVb + HE, S, nullptr, N3, N3, T,
                (long)E, (long)E, (long)T * T, E, 1.f, QC, nullptr, 0);
            softmax_rows2048<<<dim3(H * T, 1, 1), blk, 0, stream>>>(S);
            gemm_bt<0><<<dim3(E / 128, T / 128, H), blk, 0, stream>>>(
                S, Vtb, Oatt, nullptr, T, T, HE,
                (long)T * T, (long)E * T, (long)E, T, 1.f, QC, nullptr, 0);
            gemm_bt_splitk<false><<<dim3(E / 128, T / 128, 8), blk, 0, stream>>>(
                Oatt, WoT, (bf16*)S, HE, HE, E, 0, 0, 0, (long)T * E, 8, HE / 8);
            reduce_splitk<<<dim3((unsigned)(((long)T * E / 8 + 255) / 256)), blk, 0, stream>>>(
                (bf16*)S, boc, Ofin + (size_t)b * T * E, (long)T * E, E, 8);
        }
    } else if (wsE >= needC) {
        // ---- Tier C fallback ----
        bf16* Qb  = p0;
        bf16* Kb  = Qb  + wBat;
        bf16* Vb  = Kb  + wBat;
        bf16* Vtb = Vb  + wBat;
        bf16* Ob  = Vtb + wBat;
        bf16* S   = Ob  + wBat;

        for (int b = 0; b < Bb; ++b) {
            const bf16* xb = xc + (size_t)b * T * E;
            gemm_bt<0><<<dim3(HE / 128, T / 128, 1), blk, 0, stream>>>(
                xb, WqT, Qb, bqc, E, E, HE, 0, 0, 0, E, qscale, QC, nullptr, 0);
            gemm_bt<0><<<dim3(HE / 128, T / 128, 1), blk, 0, stream>>>(
                xb, WkT, Kb, bkc, E, E, HE, 0, 0, 0, E, 1.f, QC, nullptr, 0);
            gemm_bt<0><<<dim3(HE / 128, T / 128, 1), blk, 0, stream>>>(
                xb, WvT, Vb, bvc, E, E, HE, 0, 0, 0, E, 1.f, QC, nullptr, 0);
            transpose_bf16<<<dim3(E / 64, T / 64, H), blk, 0, stream>>>(
                Vb, Vtb, HE, T, H, (long)E, (long)E * T, 0, 0);
            for (int h = 0; h < H; ++h) {
                gemm_bt<0><<<dim3(T / 128, T / 128, 1), blk, 0, stream>>>(
                    Qb + (size_t)h * E, Kb + (size_t)h * E, S, nullptr,
                    HE, HE, T, 0, 0, 0, E, 1.f, QC, nullptr, 0);
                softmax_rows2048<<<dim3(T, 1, 1), blk, 0, stream>>>(S);
                gemm_bt<0><<<dim3(E / 128, T / 128, 1), blk, 0, stream>>>(
                    S, Vtb + (size_t)h * E * T, Ob + (size_t)h * E, nullptr,
                    T, T, HE, 0, 0, 0, T, 1.f, QC, nullptr, 0);
            }
            gemm_bt<0><<<dim3(E / 128, T / 128, 1), blk, 0, stream>>>(
                Ob, WoT, Ofin + (size_t)b * T * E, boc,
                HE, HE, E, 0, 0, 0, HE, 1.f, QC, nullptr, 0);
        }
    } else {
        // ---- Tier D fallback ----
        bf16* Qh  = p0;
        bf16* Kh  = Qh  + wHd;
        bf16* Vh  = Kh  + wHd;
        bf16* Vth = Vh  + wHd;
        bf16* Oh  = Vth + wHd;
        bf16* S   = Oh  + wHd;

        for (int b = 0; b < Bb; ++b) {
            const bf16* xb = xc + (size_t)b * T * E;
            bf16* outb = Ofin + (size_t)b * T * E;
            for (int h = 0; h < H; ++h) {
                const size_t hw = (size_t)h * E * E;
                gemm_bt<0><<<dim3(E / 128, T / 128, 1), blk, 0, stream>>>(
                    xb, WqT + hw, Qh, bqc + (size_t)h * E, E, E, E,
                    0, 0, 0, E, qscale, QC, nullptr, 0);
                gemm_bt<0><<<dim3(E / 128, T / 128, 1), blk, 0, stream>>>(
                    xb, WkT + hw, Kh, bkc + (size_t)h * E, E, E, E,
                    0, 0, 0, E, 1.f, QC, nullptr, 0);
                gemm_bt<0><<<dim3(E / 128, T / 128, 1), blk, 0, stream>>>(
                    xb, WvT + hw, Vh, bvc + (size_t)h * E, E, E, E,
                    0, 0, 0, E, 1.f, QC, nullptr, 0);
                transpose_bf16<<<dim3(E / 64, T / 64, 1), blk, 0, stream>>>(
                    Vh, Vth, E, T, 1, 0, 0, 0, 0);
                gemm_bt<0><<<dim3(T / 128, T / 128, 1), blk, 0, stream>>>(
                    Qh, Kh, S, nullptr, E, E, T, 0, 0, 0, E, 1.f, QC, nullptr, 0);
                softmax_rows2048<<<dim3(T, 1, 1), blk, 0, stream>>>(S);
                gemm_bt<0><<<dim3(E / 128, T / 128, 1), blk, 0, stream>>>(
                    S, Vth, Oh, nullptr, T, T, E, 0, 0, 0, T, 1.f, QC, nullptr, 0);
                if (h == 0)
                    gemm_bt<0><<<dim3(E / 128, T / 128, 1), blk, 0, stream>>>(
                        Oh, WoT, outb, boc, E, HE, E, 0, 0, 0, E, 1.f, QC, nullptr, 0);
                else
                    gemm_bt<2><<<dim3(E / 128, T / 128, 1), blk, 0, stream>>>(
                        Oh, WoT + (size_t)h * E, outb, nullptr,
                        E, HE, E, 0, 0, 0, E, 1.f, QC, nullptr, 0);
            }
        }
    }

    // ---- emit in the probed dtype (fallback tiers only) ----
    emit_out<<<dim3((unsigned)((NX / 8 + 255) / 256)), blk, 0, stream>>>(
        Ofin, d_out, NX, flag);
}

// Round 8
// 964.371 us; speedup vs baseline: 1.0172x; 1.0172x over previous
//
#include <hip/hip_runtime.h>
#include <hip/hip_bf16.h>
#include <stdint.h>

typedef __hip_bfloat16 bf16;
typedef __bf16 bf16x8 __attribute__((ext_vector_type(8)));
typedef float floatx4 __attribute__((ext_vector_type(4)));

#define AS_LDS __attribute__((address_space(3)))
#define AS_GLB __attribute__((address_space(1)))

__device__ __forceinline__ void gload_lds16(const bf16* g, bf16* l) {
    __builtin_amdgcn_global_load_lds((const AS_GLB void*)g, (AS_LDS void*)l, 16, 0, 0);
}

// ---------- dtype probe: *flag = 1 if x is fp32, 0 if bf16 ----------
__global__ void probe_dtype(const float* __restrict__ x, int* __restrict__ flag) {
    __shared__ int cnt;
    if (threadIdx.x == 0) cnt = 0;
    __syncthreads();
    int ok = 0;
    for (int i = threadIdx.x; i < 4096; i += 256) {
        float v = x[i];
        if (v == v && fabsf(v) < 1.0e3f) ok++;
    }
    atomicAdd(&cnt, ok);
    __syncthreads();
    if (threadIdx.x == 0) *flag = (cnt > 2048) ? 1 : 0;
}

__global__ __launch_bounds__(256) void zero_f32(float* __restrict__ p, int n) {
    int i = blockIdx.x * 256 + threadIdx.x;
    if (i < n) p[i] = 0.f;
}

// ---------- convert raw (fp32 or bf16 per flag) -> canonical bf16 ----------
__global__ __launch_bounds__(256) void convert_to_bf16(
    const void* __restrict__ in, bf16* __restrict__ out, long n,
    const int* __restrict__ flag)
{
    long i = ((long)blockIdx.x * 256 + threadIdx.x) * 8;
    if (i >= n) return;
    bf16 o[8];
    if (*flag) {
        const float* p = (const float*)in + i;
        float4 a = *(const float4*)p;
        float4 b = *(const float4*)(p + 4);
        o[0] = __float2bfloat16(a.x); o[1] = __float2bfloat16(a.y);
        o[2] = __float2bfloat16(a.z); o[3] = __float2bfloat16(a.w);
        o[4] = __float2bfloat16(b.x); o[5] = __float2bfloat16(b.y);
        o[6] = __float2bfloat16(b.z); o[7] = __float2bfloat16(b.w);
    } else {
        *(float4*)o = *(const float4*)((const bf16*)in + i);
    }
    *(float4*)&out[i] = *(float4*)o;
}

// ---------- emit canonical bf16 -> d_out in flag dtype (fallback tiers) ----
__global__ __launch_bounds__(256) void emit_out(
    const bf16* __restrict__ in, void* __restrict__ out, long n,
    const int* __restrict__ flag)
{
    long i = ((long)blockIdx.x * 256 + threadIdx.x) * 8;
    if (i >= n) return;
    bf16 v[8];
    *(float4*)v = *(const float4*)&in[i];
    if (*flag) {
        float* o = (float*)out + i;
        float4 a, b;
        a.x = __bfloat162float(v[0]); a.y = __bfloat162float(v[1]);
        a.z = __bfloat162float(v[2]); a.w = __bfloat162float(v[3]);
        b.x = __bfloat162float(v[4]); b.y = __bfloat162float(v[5]);
        b.z = __bfloat162float(v[6]); b.w = __bfloat162float(v[7]);
        *(float4*)o = a;
        *(float4*)(o + 4) = b;
    } else {
        *(float4*)((bf16*)out + i) = *(float4*)v;
    }
}

// ---------- transpose raw-dtype input -> bf16 output ----------
__global__ __launch_bounds__(256) void transpose_any(
    const void* __restrict__ inv, bf16* __restrict__ out,
    int ldin, int ldout, const int* __restrict__ flag)
{
    __shared__ bf16 tile[64][80];
    const int fp32 = *flag;
    const int c0 = blockIdx.x * 64;
    const int r0 = blockIdx.y * 64;
    const int tid = threadIdx.x;
#pragma unroll
    for (int it = 0; it < 2; ++it) {
        int ch = tid + it * 256;
        int r = ch >> 3, c = (ch & 7) * 8;
        long eidx = (long)(r0 + r) * ldin + (c0 + c);
        if (fp32) {
            const float* p = (const float*)inv + eidx;
            float4 a = *(const float4*)p;
            float4 b = *(const float4*)(p + 4);
            bf16 o[8];
            o[0] = __float2bfloat16(a.x); o[1] = __float2bfloat16(a.y);
            o[2] = __float2bfloat16(a.z); o[3] = __float2bfloat16(a.w);
            o[4] = __float2bfloat16(b.x); o[5] = __float2bfloat16(b.y);
            o[6] = __float2bfloat16(b.z); o[7] = __float2bfloat16(b.w);
            *(float4*)&tile[r][c] = *(float4*)o;
        } else {
            *(float4*)&tile[r][c] = *(const float4*)((const bf16*)inv + eidx);
        }
    }
    __syncthreads();
#pragma unroll
    for (int it = 0; it < 2; ++it) {
        int ch = tid + it * 256;
        int oc = ch >> 3, rb = (ch & 7) * 8;
        bf16 tmp[8];
#pragma unroll
        for (int i = 0; i < 8; ++i) tmp[i] = tile[rb + i][oc];
        *(float4*)&out[(long)(c0 + oc) * ldout + r0 + rb] = *(float4*)tmp;
    }
}

// ---------- pure-bf16 transpose (fallback tiers) ----------
__global__ __launch_bounds__(256) void transpose_bf16(
    const bf16* __restrict__ in, bf16* __restrict__ out,
    int ldin, int ldout,
    int nz1, long in_z1, long out_z1, long in_z2, long out_z2)
{
    __shared__ bf16 tile[64][80];
    const int z = blockIdx.z;
    const int z1 = z % nz1, z2 = z / nz1;
    in  += (long)z1 * in_z1 + (long)z2 * in_z2;
    out += (long)z1 * out_z1 + (long)z2 * out_z2;
    const int c0 = blockIdx.x * 64;
    const int r0 = blockIdx.y * 64;
    const int tid = threadIdx.x;
#pragma unroll
    for (int it = 0; it < 2; ++it) {
        int ch = tid + it * 256;
        int r = ch >> 3, c = (ch & 7) * 8;
        *(float4*)&tile[r][c] = *(const float4*)&in[(long)(r0 + r) * ldin + c0 + c];
    }
    __syncthreads();
#pragma unroll
    for (int it = 0; it < 2; ++it) {
        int ch = tid + it * 256;
        int oc = ch >> 3, rb = (ch & 7) * 8;
        bf16 tmp[8];
#pragma unroll
        for (int i = 0; i < 8; ++i) tmp[i] = tile[rb + i][oc];
        *(float4*)&out[(long)(c0 + oc) * ldout + r0 + rb] = *(float4*)tmp;
    }
}

// =====================================================================
// 256x256-tile 8-wave 8-phase GEMM. C = A * Bt^T.
// MODE 1 (QK, swapped A=K,B=Q): S[q][s]=exp(acc), 8B stores; accumulates
//   rowsum L[q] via cross-lane reduce + fp32 atomicAdd.
// MODE 4 (QKV): Q|K part via 4x4 shuffle transpose -> 8B row stores;
//   V part written transposed to Vt.
// SWZ 1: head-per-XCD for grid (8,8,8). SWZ 2: 6-ntile chunks, grid (48,8,1).
// =====================================================================
template <int MODE, int SWZ>
__global__ __launch_bounds__(512, 2) void gemm256(
    const bf16* __restrict__ A, const bf16* __restrict__ Bt,
    bf16* __restrict__ C, const bf16* __restrict__ bias,
    int lda, int ldb, int ldc,
    long az, long bz, long cz, int K, float scale, int qcols,
    bf16* __restrict__ Vt, int vcol0, float* __restrict__ Lsum)
{
    __shared__ bf16 AsL[2][2][256 * 32];
    __shared__ bf16 BsL[2][2][256 * 32];

    const int tid  = threadIdx.x;
    const int lane = tid & 63;
    const int wave = tid >> 6;
    const int wr = wave >> 2;        // 0..1  row half of C tile
    const int wc = wave & 3;         // 0..3  col quarter of C tile
    const int lm = lane & 15;
    const int cl = lane >> 4;        // fragment k-chunk 0..3

    int bxx = blockIdx.x, byy = blockIdx.y, bzz = blockIdx.z;
    if constexpr (SWZ == 1) {        // grid (8,8,8): head z = XCD
        int flat = bxx + (byy << 3) + (bzz << 6);
        int xcd = flat & 7, idx = flat >> 3;
        bzz = xcd; bxx = idx & 7; byy = idx >> 3;
    } else if constexpr (SWZ == 2) { // grid (48,8,1): 6 n-tiles per XCD
        int flat = bxx + byy * 48;
        int xcd = flat & 7, idx = flat >> 3;
        bxx = xcd * 6 + idx % 6; byy = idx / 6; bzz = 0;
    }
    const long zz = bzz;
    A  += zz * az;
    Bt += zz * bz;
    C  += zz * cz;
    float* Lz = (MODE == 1) ? (Lsum + zz * 2048) : nullptr;
    const int m0 = byy * 256;
    const int n0 = bxx * 256;

    // per-lane swizzled ds_read offsets within a [256][32] k-half block
    int offA[8], offB[4];
#pragma unroll
    for (int i = 0; i < 8; ++i) {
        int row = wr * 128 + i * 16 + lm;
        offA[i] = row * 32 + ((cl ^ ((row >> 1) & 3)) << 3);
    }
#pragma unroll
    for (int j = 0; j < 4; ++j) {
        int row = wc * 64 + j * 16 + lm;
        offB[j] = row * 32 + ((cl ^ ((row >> 1) & 3)) << 3);
    }

    const int sr = lane >> 2;        // staging row-in-16
    const int sc = lane & 3;         // staging chunk
    const int NT = K >> 6;           // 64-wide K tiles (NT even)

    floatx4 acc[8][4];
#pragma unroll
    for (int i = 0; i < 8; ++i)
#pragma unroll
        for (int j = 0; j < 4; ++j)
            acc[i][j] = (floatx4){0.f, 0.f, 0.f, 0.f};

    // stage one (operand, khalf) unit of tile t: 2 x global_load_lds
    auto stageU = [&](int which, int t, int kh) {
        if (t >= NT) return;
        const bf16* G = which ? Bt : A;
        const int ldg  = which ? ldb : lda;
        const int g0   = which ? n0 : m0;
        bf16* lb = which ? &BsL[t & 1][kh][0] : &AsL[t & 1][kh][0];
        const int kcol = t * 64 + kh * 32;
#pragma unroll
        for (int ii = 0; ii < 2; ++ii) {
            int row = ii * 128 + wave * 16 + sr;
            int cg  = sc ^ ((row >> 1) & 3);   // pre-swizzled global chunk
            gload_lds16(G + (long)(g0 + row) * ldg + kcol + cg * 8,
                        lb + row * 32 + sc * 8);
        }
    };

    bf16x8 af[8], bfv[2];
    auto dsA = [&](int b, int kh) {
        const bf16* p = &AsL[b][kh][0];
#pragma unroll
        for (int i = 0; i < 8; ++i) af[i] = *(const bf16x8*)(p + offA[i]);
    };
    auto dsB = [&](int b, int kh, int nh) {
        const bf16* p = &BsL[b][kh][0];
        bfv[0] = *(const bf16x8*)(p + offB[nh * 2]);
        bfv[1] = *(const bf16x8*)(p + offB[nh * 2 + 1]);
    };
    auto mfmaQ = [&](int nh) {
        __builtin_amdgcn_s_setprio(1);
#pragma unroll
        for (int i = 0; i < 8; ++i) {
            acc[i][nh * 2] = __builtin_amdgcn_mfma_f32_16x16x32_bf16(
                af[i], bfv[0], acc[i][nh * 2], 0, 0, 0);
            acc[i][nh * 2 + 1] = __builtin_amdgcn_mfma_f32_16x16x32_bf16(
                af[i], bfv[1], acc[i][nh * 2 + 1], 0, 0, 0);
        }
        __builtin_amdgcn_s_setprio(0);
    };

#define BAR    __builtin_amdgcn_s_barrier()
#define SBZ    __builtin_amdgcn_sched_barrier(0)
#define LGKM0  do { asm volatile("s_waitcnt lgkmcnt(0)" ::: "memory"); SBZ; } while (0)
#define VM(n)  do { asm volatile("s_waitcnt vmcnt(" #n ")" ::: "memory"); SBZ; } while (0)

    // ---- prologue: tile0 (all), tile1 k0 ----
    stageU(0, 0, 0); stageU(1, 0, 0); stageU(0, 0, 1); stageU(1, 0, 1);
    stageU(0, 1, 0); stageU(1, 1, 0);
    VM(4);
    BAR;

    for (int t0 = 0; t0 < NT; t0 += 2) {
        const bool last = (t0 + 2 >= NT);
        dsA(0, 0); dsB(0, 0, 0); stageU(0, t0 + 1, 1);
        BAR; LGKM0; mfmaQ(0); BAR;
        dsB(0, 0, 1); stageU(1, t0 + 1, 1);
        BAR; LGKM0; mfmaQ(1); BAR;
        dsA(0, 1); dsB(0, 1, 0); stageU(0, t0 + 2, 0);
        BAR; LGKM0; mfmaQ(0); BAR;
        dsB(0, 1, 1); stageU(1, t0 + 2, 0);
        BAR; LGKM0; mfmaQ(1);
        if (last) { VM(0); } else { VM(4); }
        BAR;
        dsA(1, 0); dsB(1, 0, 0); stageU(0, t0 + 2, 1);
        BAR; LGKM0; mfmaQ(0); BAR;
        dsB(1, 0, 1); stageU(1, t0 + 2, 1);
        BAR; LGKM0; mfmaQ(1); BAR;
        dsA(1, 1); dsB(1, 1, 0); stageU(0, t0 + 3, 0);
        BAR; LGKM0; mfmaQ(0); BAR;
        dsB(1, 1, 1); stageU(1, t0 + 3, 0);
        BAR; LGKM0; mfmaQ(1);
        if (!last) { VM(4); }
        BAR;
    }
#undef BAR
#undef SBZ
#undef LGKM0
#undef VM

    // ---- epilogue ----
    const int cr = (lane >> 4) * 4;
    if constexpr (MODE == 1) {
        // swapped operands: acc(row=s, col=q). Store S[q][s] = exp(acc):
        // lane holds 4 consecutive s -> 8B packet. Also rowsum -> atomic.
#pragma unroll
        for (int j = 0; j < 4; ++j) {
            long q = n0 + wc * 64 + j * 16 + lm;
            bf16* Cr = C + q * ldc + m0 + wr * 128;
            float rs = 0.f;
#pragma unroll
            for (int i = 0; i < 8; ++i) {
                bf16 pk[4];
#pragma unroll
                for (int r = 0; r < 4; ++r) {
                    float e = __expf(acc[i][j][r]);
                    rs += e;
                    pk[r] = __float2bfloat16(e);
                }
                *(uint64_t*)&Cr[i * 16 + cr] = *(const uint64_t*)pk;
            }
            rs += __shfl_xor(rs, 16);
            rs += __shfl_xor(rs, 32);
            if (cl == 0) atomicAdd(&Lz[q], rs);
        }
    } else {   // MODE 4
        if (n0 >= vcol0) {
            // V block: write transposed, packed 4 consecutive t per 8B store
#pragma unroll
            for (int j = 0; j < 4; ++j) {
                int col = n0 + wc * 64 + j * 16 + lm;
                float bv = __bfloat162float(bias[col]);
                int eg = col - vcol0;
                bf16* vt = Vt + ((long)(eg >> 9) * 512 + (eg & 511)) * 2048;
#pragma unroll
                for (int i = 0; i < 8; ++i) {
                    int t0v = m0 + wr * 128 + i * 16 + cr;
                    bf16 pk[4];
#pragma unroll
                    for (int r = 0; r < 4; ++r)
                        pk[r] = __float2bfloat16(acc[i][j][r] + bv);
                    *(uint64_t*)&vt[t0v] = *(const uint64_t*)pk;
                }
            }
        } else {
            // Q|K: bias+scale, then 4x4 shuffle transpose -> 8B row stores
            const int l4 = lane & 3;
            float bvj[4], scj[4];
#pragma unroll
            for (int j = 0; j < 4; ++j) {
                int col = n0 + wc * 64 + j * 16 + lm;
                bvj[j] = __bfloat162float(bias[col]);
                scj[j] = (col < qcols) ? scale : 1.0f;
            }
#pragma unroll
            for (int i = 0; i < 8; ++i) {
                int row = m0 + wr * 128 + i * 16 + cr + l4;
                bf16* Cr = C + (long)row * ldc + n0 + wc * 64 + (lm & ~3);
#pragma unroll
                for (int j = 0; j < 4; ++j) {
                    float x0 = (acc[i][j][0] + bvj[j]) * scj[j];
                    float x1 = (acc[i][j][1] + bvj[j]) * scj[j];
                    float x2 = (acc[i][j][2] + bvj[j]) * scj[j];
                    float x3 = (acc[i][j][3] + bvj[j]) * scj[j];
                    float u = __shfl_xor((l4 & 1) ? x0 : x1, 1);
                    float v = __shfl_xor((l4 & 1) ? x2 : x3, 1);
                    if (l4 & 1) { x0 = u; x2 = v; } else { x1 = u; x3 = v; }
                    u = __shfl_xor((l4 & 2) ? x0 : x2, 2);
                    v = __shfl_xor((l4 & 2) ? x1 : x3, 2);
                    if (l4 & 2) { x0 = u; x1 = v; } else { x2 = u; x3 = v; }
                    bf16 pk[4];
                    pk[0] = __float2bfloat16(x0); pk[1] = __float2bfloat16(x1);
                    pk[2] = __float2bfloat16(x2); pk[3] = __float2bfloat16(x3);
                    *(uint64_t*)&Cr[j * 16] = *(const uint64_t*)pk;
                }
            }
        }
    }
}

// =====================================================================
// PV kernel v3: 256x256-tile 8-wave 8-phase (same body as gemm256).
// A = Vt (rows=ch, ld=T), Bt = S (rows=q, ld=T), K = 2048.
// Grid (8 q-tiles, 2 ch-tiles, 8 heads) = 128 blocks; each S q-panel is
// read by only the 2 ch-siblings (ids 8 apart -> same XCD -> L2 hit);
// S effectively read once per XCD pair. O[q][ch] = acc / L[q] stored as
// 8B packets of 4 consecutive ch (MODE-1 store pattern, verified layout).
// =====================================================================
__global__ __launch_bounds__(512, 2) void gemm_pv3(
    const bf16* __restrict__ A, const bf16* __restrict__ Bt,
    bf16* __restrict__ C, const float* __restrict__ L,
    int lda, int ldb, int ldc, long az, long bz, long cz, int K)
{
    __shared__ bf16 AsL[2][2][256 * 32];
    __shared__ bf16 BsL[2][2][256 * 32];

    const int tid  = threadIdx.x;
    const int lane = tid & 63;
    const int wave = tid >> 6;
    const int wr = wave >> 2;
    const int wc = wave & 3;
    const int lm = lane & 15;
    const int cl = lane >> 4;

    const int bxx = blockIdx.x;      // q-tile 0..7
    const int byy = blockIdx.y;      // ch-tile 0..1
    const long zz = blockIdx.z;      // head
    A  += zz * az;
    Bt += zz * bz;
    C  += zz * cz;
    const float* Lz = L + zz * 2048;
    const int m0 = byy * 256;        // ch base
    const int n0 = bxx * 256;        // q base

    int offA[8], offB[4];
#pragma unroll
    for (int i = 0; i < 8; ++i) {
        int row = wr * 128 + i * 16 + lm;
        offA[i] = row * 32 + ((cl ^ ((row >> 1) & 3)) << 3);
    }
#pragma unroll
    for (int j = 0; j < 4; ++j) {
        int row = wc * 64 + j * 16 + lm;
        offB[j] = row * 32 + ((cl ^ ((row >> 1) & 3)) << 3);
    }

    const int sr = lane >> 2;
    const int sc = lane & 3;
    const int NT = K >> 6;           // 32, even

    floatx4 acc[8][4];
#pragma unroll
    for (int i = 0; i < 8; ++i)
#pragma unroll
        for (int j = 0; j < 4; ++j)
            acc[i][j] = (floatx4){0.f, 0.f, 0.f, 0.f};

    auto stageU = [&](int which, int t, int kh) {
        if (t >= NT) return;
        const bf16* G = which ? Bt : A;
        const int ldg  = which ? ldb : lda;
        const int g0   = which ? n0 : m0;
        bf16* lb = which ? &BsL[t & 1][kh][0] : &AsL[t & 1][kh][0];
        const int kcol = t * 64 + kh * 32;
#pragma unroll
        for (int ii = 0; ii < 2; ++ii) {
            int row = ii * 128 + wave * 16 + sr;
            int cg  = sc ^ ((row >> 1) & 3);
            gload_lds16(G + (long)(g0 + row) * ldg + kcol + cg * 8,
                        lb + row * 32 + sc * 8);
        }
    };

    bf16x8 af[8], bfv[2];
    auto dsA = [&](int b, int kh) {
        const bf16* p = &AsL[b][kh][0];
#pragma unroll
        for (int i = 0; i < 8; ++i) af[i] = *(const bf16x8*)(p + offA[i]);
    };
    auto dsB = [&](int b, int kh, int nh) {
        const bf16* p = &BsL[b][kh][0];
        bfv[0] = *(const bf16x8*)(p + offB[nh * 2]);
        bfv[1] = *(const bf16x8*)(p + offB[nh * 2 + 1]);
    };
    auto mfmaQ = [&](int nh) {
        __builtin_amdgcn_s_setprio(1);
#pragma unroll
        for (int i = 0; i < 8; ++i) {
            acc[i][nh * 2] = __builtin_amdgcn_mfma_f32_16x16x32_bf16(
                af[i], bfv[0], acc[i][nh * 2], 0, 0, 0);
            acc[i][nh * 2 + 1] = __builtin_amdgcn_mfma_f32_16x16x32_bf16(
                af[i], bfv[1], acc[i][nh * 2 + 1], 0, 0, 0);
        }
        __builtin_amdgcn_s_setprio(0);
    };

#define BAR    __builtin_amdgcn_s_barrier()
#define SBZ    __builtin_amdgcn_sched_barrier(0)
#define LGKM0  do { asm volatile("s_waitcnt lgkmcnt(0)" ::: "memory"); SBZ; } while (0)
#define VM(n)  do { asm volatile("s_waitcnt vmcnt(" #n ")" ::: "memory"); SBZ; } while (0)

    stageU(0, 0, 0); stageU(1, 0, 0); stageU(0, 0, 1); stageU(1, 0, 1);
    stageU(0, 1, 0); stageU(1, 1, 0);
    VM(4);
    BAR;

    for (int t0 = 0; t0 < NT; t0 += 2) {
        const bool last = (t0 + 2 >= NT);
        dsA(0, 0); dsB(0, 0, 0); stageU(0, t0 + 1, 1);
        BAR; LGKM0; mfmaQ(0); BAR;
        dsB(0, 0, 1); stageU(1, t0 + 1, 1);
        BAR; LGKM0; mfmaQ(1); BAR;
        dsA(0, 1); dsB(0, 1, 0); stageU(0, t0 + 2, 0);
        BAR; LGKM0; mfmaQ(0); BAR;
        dsB(0, 1, 1); stageU(1, t0 + 2, 0);
        BAR; LGKM0; mfmaQ(1);
        if (last) { VM(0); } else { VM(4); }
        BAR;
        dsA(1, 0); dsB(1, 0, 0); stageU(0, t0 + 2, 1);
        BAR; LGKM0; mfmaQ(0); BAR;
        dsB(1, 0, 1); stageU(1, t0 + 2, 1);
        BAR; LGKM0; mfmaQ(1); BAR;
        dsA(1, 1); dsB(1, 1, 0); stageU(0, t0 + 3, 0);
        BAR; LGKM0; mfmaQ(0); BAR;
        dsB(1, 1, 1); stageU(1, t0 + 3, 0);
        BAR; LGKM0; mfmaQ(1);
        if (!last) { VM(4); }
        BAR;
    }
#undef BAR
#undef SBZ
#undef LGKM0
#undef VM

    // epilogue: acc rows = ch, cols = q. O[q][ch] = acc / L[q];
    // lane holds 4 consecutive ch -> 8B packets.
    const int cr = (lane >> 4) * 4;
#pragma unroll
    for (int j = 0; j < 4; ++j) {
        long q = n0 + wc * 64 + j * 16 + lm;
        float inv = 1.0f / Lz[q];
        bf16* Cr = C + q * ldc + m0 + wr * 128;
#pragma unroll
        for (int i = 0; i < 8; ++i) {
            bf16 pk[4];
#pragma unroll
            for (int r = 0; r < 4; ++r)
                pk[r] = __float2bfloat16(acc[i][j][r] * inv);
            *(uint64_t*)&Cr[i * 16 + cr] = *(const uint64_t*)pk;
        }
    }
}

// =====================================================================
// 128(M)x256(N)-tile 8-wave 8-phase GEMM (out-proj split-K). 96KB LDS.
// MODE 6: P[t][ch] = acc partial, z = k-split (kbase = z*kper).
// SWZ 6: chunked remap, grid (32,4,2).
// =====================================================================
template <int MODE, int SWZ>
__global__ __launch_bounds__(512, 2) void gemm128n(
    const bf16* __restrict__ A, const bf16* __restrict__ Bt,
    bf16* __restrict__ C, const float* __restrict__ L,
    int lda, int ldb, int ldc,
    long az, long bz, long cz, int K, int kper)
{
    __shared__ bf16 AsL[2][2][128 * 32];
    __shared__ bf16 BsL[2][2][256 * 32];

    const int tid  = threadIdx.x;
    const int lane = tid & 63;
    const int wave = tid >> 6;
    const int wr = wave >> 2;        // 0..1  m-half (64 rows)
    const int wc = wave & 3;         // 0..3  n-quarter (64 cols)
    const int lm = lane & 15;
    const int cl = lane >> 4;

    int bxx = blockIdx.x, byy = blockIdx.y, bzz = blockIdx.z;
    if constexpr (SWZ == 5) {        // grid (8,4,8): head z = XCD
        int flat = bxx + (byy << 3) + (bzz << 5);
        int xcd = flat & 7, idx = flat >> 3;
        bzz = xcd; bxx = idx & 7; byy = idx >> 3;
    } else if constexpr (SWZ == 6) { // grid (32,4,2): chunked remap
        int flat = bxx + (byy << 5) + (bzz << 7);
        int nf = (flat & 7) * 32 + (flat >> 3);
        bzz = nf >> 7; int rr = nf & 127; byy = rr >> 5; bxx = rr & 31;
    }
    const long zz = bzz;
    A  += zz * az;
    Bt += zz * bz;
    C  += zz * cz;
    const float* Lz = (MODE == 5) ? (L + zz * 2048) : nullptr;
    const int kbase = (int)(zz * (long)kper);
    const int m0 = byy * 128;
    const int n0 = bxx * 256;

    int offA[4], offB[4];
#pragma unroll
    for (int i = 0; i < 4; ++i) {
        int row = wr * 64 + i * 16 + lm;
        offA[i] = row * 32 + ((cl ^ ((row >> 1) & 3)) << 3);
    }
#pragma unroll
    for (int j = 0; j < 4; ++j) {
        int row = wc * 64 + j * 16 + lm;
        offB[j] = row * 32 + ((cl ^ ((row >> 1) & 3)) << 3);
    }

    const int sr = lane >> 2;
    const int sc = lane & 3;
    const int NT = K >> 6;           // even

    floatx4 acc[4][4];
#pragma unroll
    for (int i = 0; i < 4; ++i)
#pragma unroll
        for (int j = 0; j < 4; ++j)
            acc[i][j] = (floatx4){0.f, 0.f, 0.f, 0.f};

    auto stageA = [&](int t, int kh) {   // 1 load/thread
        if (t >= NT) return;
        bf16* lb = &AsL[t & 1][kh][0];
        const int kcol = kbase + t * 64 + kh * 32;
        int row = wave * 16 + sr;
        int cg  = sc ^ ((row >> 1) & 3);
        gload_lds16(A + (long)(m0 + row) * lda + kcol + cg * 8,
                    lb + row * 32 + sc * 8);
    };
    auto stageB = [&](int t, int kh) {   // 2 loads/thread
        if (t >= NT) return;
        bf16* lb = &BsL[t & 1][kh][0];
        const int kcol = kbase + t * 64 + kh * 32;
#pragma unroll
        for (int ii = 0; ii < 2; ++ii) {
            int row = ii * 128 + wave * 16 + sr;
            int cg  = sc ^ ((row >> 1) & 3);
            gload_lds16(Bt + (long)(n0 + row) * ldb + kcol + cg * 8,
                        lb + row * 32 + sc * 8);
        }
    };

    bf16x8 af[4], bfv[2];
    auto dsA = [&](int b, int kh) {
        const bf16* p = &AsL[b][kh][0];
#pragma unroll
        for (int i = 0; i < 4; ++i) af[i] = *(const bf16x8*)(p + offA[i]);
    };
    auto dsB = [&](int b, int kh, int nh) {
        const bf16* p = &BsL[b][kh][0];
        bfv[0] = *(const bf16x8*)(p + offB[nh * 2]);
        bfv[1] = *(const bf16x8*)(p + offB[nh * 2 + 1]);
    };
    auto mfmaQ = [&](int nh) {
        __builtin_amdgcn_s_setprio(1);
#pragma unroll
        for (int i = 0; i < 4; ++i) {
            acc[i][nh * 2] = __builtin_amdgcn_mfma_f32_16x16x32_bf16(
                af[i], bfv[0], acc[i][nh * 2], 0, 0, 0);
            acc[i][nh * 2 + 1] = __builtin_amdgcn_mfma_f32_16x16x32_bf16(
                af[i], bfv[1], acc[i][nh * 2 + 1], 0, 0, 0);
        }
        __builtin_amdgcn_s_setprio(0);
    };

#define BAR    __builtin_amdgcn_s_barrier()
#define SBZ    __builtin_amdgcn_sched_barrier(0)
#define LGKM0  do { asm volatile("s_waitcnt lgkmcnt(0)" ::: "memory"); SBZ; } while (0)
#define VM(n)  do { asm volatile("s_waitcnt vmcnt(" #n ")" ::: "memory"); SBZ; } while (0)

    stageA(0, 0); stageB(0, 0); stageA(0, 1); stageB(0, 1);
    stageA(1, 0); stageB(1, 0);
    VM(3);
    BAR;

    for (int t0 = 0; t0 < NT; t0 += 2) {
        const bool last = (t0 + 2 >= NT);
        dsA(0, 0); dsB(0, 0, 0); stageA(t0 + 1, 1);
        BAR; LGKM0; mfmaQ(0); BAR;
        dsB(0, 0, 1); stageB(t0 + 1, 1);
        BAR; LGKM0; mfmaQ(1); BAR;
        dsA(0, 1); dsB(0, 1, 0); stageA(t0 + 2, 0);
        BAR; LGKM0; mfmaQ(0); BAR;
        dsB(0, 1, 1); stageB(t0 + 2, 0);
        BAR; LGKM0; mfmaQ(1);
        if (last) { VM(0); } else { VM(3); }
        BAR;
        dsA(1, 0); dsB(1, 0, 0); stageA(t0 + 2, 1);
        BAR; LGKM0; mfmaQ(0); BAR;
        dsB(1, 0, 1); stageB(t0 + 2, 1);
        BAR; LGKM0; mfmaQ(1); BAR;
        dsA(1, 1); dsB(1, 1, 0); stageA(t0 + 3, 0);
        BAR; LGKM0; mfmaQ(0); BAR;
        dsB(1, 1, 1); stageB(t0 + 3, 0);
        BAR; LGKM0; mfmaQ(1);
        if (!last) { VM(3); }
        BAR;
    }
#undef BAR
#undef SBZ
#undef LGKM0
#undef VM

    const int cr = cl * 4;
#pragma unroll
    for (int j = 0; j < 4; ++j) {
        int col = n0 + wc * 64 + j * 16 + lm;
        bf16* Cr = C + (long)col * ldc + m0 + wr * 64;
        float inv = 1.0f;
        if constexpr (MODE == 5) inv = 1.0f / Lz[col];
#pragma unroll
        for (int i = 0; i < 4; ++i) {
            bf16 pk[4];
#pragma unroll
            for (int r = 0; r < 4; ++r)
                pk[r] = __float2bfloat16(acc[i][j][r] * inv);
            *(uint64_t*)&Cr[i * 16 + cr] = *(const uint64_t*)pk;
        }
    }
}

// ---------- GEMM (bf16 in/out, fp32 acc), fallback tiers -----------------
template <int MODE, bool SWAP = false, int SWZ = 0>
__global__ __launch_bounds__(256) void gemm_bt(
    const bf16* __restrict__ A, const bf16* __restrict__ Bt,
    bf16* __restrict__ C, const bf16* __restrict__ bias,
    int lda, int ldb, int ldc,
    long az, long bz, long cz, int K, float scale, int qcols,
    bf16* __restrict__ Vt, int vcol0)
{
    __shared__ bf16 As[128 * 64];
    __shared__ bf16 Bs[128 * 64];

    const int tid  = threadIdx.x;
    const int lane = tid & 63;
    const int wave = tid >> 6;
    const int wx = wave & 1;
    const int wy = wave >> 1;

    int bxx = blockIdx.x, byy = blockIdx.y, bzz = blockIdx.z;
    const long zz = bzz;
    A  += zz * az;
    Bt += zz * bz;
    C  += zz * cz;
    const int bm = SWAP ? bxx : byy;
    const int bn = SWAP ? byy : bxx;
    const int m0 = bm * 128;
    const int n0 = bn * 128;

    const int lm = lane & 15;
    const int kq = (lane >> 4) * 8;

    floatx4 acc[4][4];
#pragma unroll
    for (int i = 0; i < 4; ++i)
#pragma unroll
        for (int j = 0; j < 4; ++j)
            acc[i][j] = (floatx4){0.f, 0.f, 0.f, 0.f};

    for (int kt = 0; kt < K; kt += 64) {
        __syncthreads();
#pragma unroll
        for (int it = 0; it < 4; ++it) {
            int ch = tid + it * 256;
            int r = ch >> 3;
            int c = (ch & 7) * 8;
            gload_lds16(A  + (long)(m0 + r) * lda + (kt + c), &As[ch * 8]);
            gload_lds16(Bt + (long)(n0 + r) * ldb + (kt + c), &Bs[ch * 8]);
        }
        __syncthreads();
#pragma unroll
        for (int kk = 0; kk < 64; kk += 32) {
            bf16x8 af[4], bfv[4];
#pragma unroll
            for (int i = 0; i < 4; ++i)
                af[i] = *(const bf16x8*)&As[(wy * 64 + i * 16 + lm) * 64 + kk + kq];
#pragma unroll
            for (int j = 0; j < 4; ++j)
                bfv[j] = *(const bf16x8*)&Bs[(wx * 64 + j * 16 + lm) * 64 + kk + kq];
#pragma unroll
            for (int i = 0; i < 4; ++i)
#pragma unroll
                for (int j = 0; j < 4; ++j)
                    acc[i][j] = __builtin_amdgcn_mfma_f32_16x16x32_bf16(
                        af[i], bfv[j], acc[i][j], 0, 0, 0);
        }
    }

    const int cr = (lane >> 4) * 4;
    if constexpr (MODE == 1) {
#pragma unroll
        for (int j = 0; j < 4; ++j) {
            int col = n0 + wx * 64 + j * 16 + lm;
#pragma unroll
            for (int i = 0; i < 4; ++i)
#pragma unroll
                for (int r = 0; r < 4; ++r) {
                    int row = m0 + wy * 64 + i * 16 + cr + r;
                    C[(long)row * ldc + col] = __float2bfloat16(__expf(acc[i][j][r]));
                }
        }
    } else {
#pragma unroll
        for (int j = 0; j < 4; ++j) {
            int col = n0 + wx * 64 + j * 16 + lm;
            float bv = (MODE == 0 && bias) ? __bfloat162float(bias[col]) : 0.f;
            float sc = (col < qcols) ? scale : 1.0f;
#pragma unroll
            for (int i = 0; i < 4; ++i) {
#pragma unroll
                for (int r = 0; r < 4; ++r) {
                    int row = m0 + wy * 64 + i * 16 + cr + r;
                    long idx = (long)row * ldc + col;
                    float v;
                    if (MODE == 2) v = acc[i][j][r] + __bfloat162float(C[idx]);
                    else           v = (acc[i][j][r] + bv) * sc;
                    C[idx] = __float2bfloat16(v);
                }
            }
        }
    }
}

// ---------- split-K GEMM, bf16 partials (fallback tiers) ------------------
template <bool SWAP = false>
__global__ __launch_bounds__(256) void gemm_bt_splitk(
    const bf16* __restrict__ A, const bf16* __restrict__ Bt,
    bf16* __restrict__ P, int lda, int ldb, int ldp,
    long az, long bz, long pz, long skStride, int nsk, int Kc)
{
    __shared__ bf16 As[128 * 64];
    __shared__ bf16 Bs[128 * 64];

    const int tid  = threadIdx.x;
    const int lane = tid & 63;
    const int wave = tid >> 6;
    const int wx = wave & 1;
    const int wy = wave >> 1;
    const int zz = blockIdx.z;
    const int ks = zz % nsk;
    const int zh = zz / nsk;
    A  += (long)zh * az;
    Bt += (long)zh * bz;
    bf16* Pz = P + (long)zh * pz + (long)ks * skStride;
    const int bm = SWAP ? blockIdx.x : blockIdx.y;
    const int bn = SWAP ? blockIdx.y : blockIdx.x;
    const int m0 = bm * 128;
    const int n0 = bn * 128;
    const int k0 = ks * Kc;

    const int lm = lane & 15;
    const int kq = (lane >> 4) * 8;

    floatx4 acc[4][4];
#pragma unroll
    for (int i = 0; i < 4; ++i)
#pragma unroll
        for (int j = 0; j < 4; ++j)
            acc[i][j] = (floatx4){0.f, 0.f, 0.f, 0.f};

    for (int kt = k0; kt < k0 + Kc; kt += 64) {
        __syncthreads();
#pragma unroll
        for (int it = 0; it < 4; ++it) {
            int ch = tid + it * 256;
            int r = ch >> 3;
            int c = (ch & 7) * 8;
            gload_lds16(A  + (long)(m0 + r) * lda + (kt + c), &As[ch * 8]);
            gload_lds16(Bt + (long)(n0 + r) * ldb + (kt + c), &Bs[ch * 8]);
        }
        __syncthreads();
#pragma unroll
        for (int kk = 0; kk < 64; kk += 32) {
            bf16x8 af[4], bfv[4];
#pragma unroll
            for (int i = 0; i < 4; ++i)
                af[i] = *(const bf16x8*)&As[(wy * 64 + i * 16 + lm) * 64 + kk + kq];
#pragma unroll
            for (int j = 0; j < 4; ++j)
                bfv[j] = *(const bf16x8*)&Bs[(wx * 64 + j * 16 + lm) * 64 + kk + kq];
#pragma unroll
            for (int i = 0; i < 4; ++i)
#pragma unroll
                for (int j = 0; j < 4; ++j)
                    acc[i][j] = __builtin_amdgcn_mfma_f32_16x16x32_bf16(
                        af[i], bfv[j], acc[i][j], 0, 0, 0);
        }
    }

    const int cr = (lane >> 4) * 4;
#pragma unroll
    for (int j = 0; j < 4; ++j) {
        int col = n0 + wx * 64 + j * 16 + lm;
#pragma unroll
        for (int i = 0; i < 4; ++i)
#pragma unroll
            for (int r = 0; r < 4; ++r) {
                int row = m0 + wy * 64 + i * 16 + cr + r;
                Pz[(long)row * ldp + col] = __float2bfloat16(acc[i][j][r]);
            }
    }
}

// ---------- reduce 2 bf16 split-K partials + bias -> d_out in flag dtype ----
__global__ __launch_bounds__(256) void reduce_emit(
    const bf16* __restrict__ P, const bf16* __restrict__ bias,
    void* __restrict__ out, long MN, int N,
    const int* __restrict__ flag)
{
    long i = ((long)blockIdx.x * 256 + threadIdx.x) * 8;
    if (i >= MN) return;
    bf16 bb[8], a[8], b[8];
    *(float4*)bb = *(const float4*)&bias[i & (N - 1)];
    *(float4*)a  = *(const float4*)&P[i];
    *(float4*)b  = *(const float4*)&P[MN + i];
    float s[8];
#pragma unroll
    for (int k = 0; k < 8; ++k)
        s[k] = __bfloat162float(bb[k]) + __bfloat162float(a[k]) + __bfloat162float(b[k]);
    if (*flag) {
        float* o = (float*)out + i;
        float4 lo = {s[0], s[1], s[2], s[3]};
        float4 hi = {s[4], s[5], s[6], s[7]};
        *(float4*)o = lo;
        *(float4*)(o + 4) = hi;
    } else {
        bf16 o[8];
#pragma unroll
        for (int k = 0; k < 8; ++k) o[k] = __float2bfloat16(s[k]);
        *(float4*)&((bf16*)out)[i] = *(float4*)o;
    }
}

// ---------- reduce bf16 split-K partials + bias -> bf16 (fallback) ----------
__global__ __launch_bounds__(256) void reduce_splitk(
    const bf16* __restrict__ P, const bf16* __restrict__ bias,
    bf16* __restrict__ Out, long MN, int N, int SK)
{
    long i = ((long)blockIdx.x * 256 + threadIdx.x) * 8;
    if (i >= MN) return;
    float s[8];
    if (bias) {
        bf16 bb[8];
        *(float4*)bb = *(const float4*)&bias[i & (N - 1)];
#pragma unroll
        for (int k = 0; k < 8; ++k) s[k] = __bfloat162float(bb[k]);
    } else {
#pragma unroll
        for (int k = 0; k < 8; ++k) s[k] = 0.f;
    }
    for (int z = 0; z < SK; ++z) {
        bf16 a[8];
        *(float4*)a = *(const float4*)&P[(long)z * MN + i];
#pragma unroll
        for (int k = 0; k < 8; ++k) s[k] += __bfloat162float(a[k]);
    }
    bf16 o[8];
#pragma unroll
    for (int k = 0; k < 8; ++k) o[k] = __float2bfloat16(s[k]);
    *(float4*)&Out[i] = *(float4*)o;
}

// ---------- in-place softmax over rows of 2048 bf16 (fallback tiers) -----
__global__ __launch_bounds__(256) void softmax_rows2048(bf16* __restrict__ S)
{
    __shared__ float red[8];
    const long row = blockIdx.x;
    bf16* p = S + row * 2048;
    const int tid = threadIdx.x;
    float4 raw = *(const float4*)&p[tid * 8];
    bf16 vb[8];
    *(float4*)vb = raw;
    float v[8];
#pragma unroll
    for (int i = 0; i < 8; ++i) v[i] = __bfloat162float(vb[i]);
    float m = v[0];
#pragma unroll
    for (int i = 1; i < 8; ++i) m = fmaxf(m, v[i]);
#pragma unroll
    for (int o = 32; o > 0; o >>= 1) m = fmaxf(m, __shfl_xor(m, o));
    if ((tid & 63) == 0) red[tid >> 6] = m;
    __syncthreads();
    m = fmaxf(fmaxf(red[0], red[1]), fmaxf(red[2], red[3]));
    float s = 0.f;
#pragma unroll
    for (int i = 0; i < 8; ++i) { v[i] = __expf(v[i] - m); s += v[i]; }
#pragma unroll
    for (int o = 32; o > 0; o >>= 1) s += __shfl_xor(s, o);
    if ((tid & 63) == 0) red[4 + (tid >> 6)] = s;
    __syncthreads();
    s = (red[4] + red[5]) + (red[6] + red[7]);
    float inv = 1.f / s;
#pragma unroll
    for (int i = 0; i < 8; ++i) vb[i] = __float2bfloat16(v[i] * inv);
    *(float4*)&p[tid * 8] = *(float4*)vb;
}

extern "C" void kernel_launch(void* const* d_in, const int* in_sizes, int n_in,
                              void* d_out, int out_size, void* d_ws, size_t ws_size,
                              hipStream_t stream)
{
    const int Bb = 4, T = 2048, E = 512, H = 8;
    const int HE = H * E;            // 4096
    const int N3 = 3 * HE;           // 12288
    const int N2 = 2 * HE;           // 8192 (Q|K row width)
    const int M  = Bb * T;           // 8192
    const long NX = (long)M * E;     // 4,194,304

    // ---- size-signature input assignment (order-robust) ----
    const void* xr = nullptr;
    const void* Wr[4] = {nullptr, nullptr, nullptr, nullptr};
    const void* br[3] = {nullptr, nullptr, nullptr};
    const void* bor = nullptr;
    int nw = 0, nb = 0;
    for (int i = 0; i < n_in; ++i) {
        int s = in_sizes[i];
        if      (s == (int)NX)      xr = d_in[i];
        else if (s == E * HE)       { if (nw < 4) Wr[nw++] = d_in[i]; }
        else if (s == HE)           { if (nb < 3) br[nb++] = d_in[i]; }
        else if (s == E)            bor = d_in[i];
    }
    if (!xr || nw < 4 || nb < 3 || !bor) {
        xr = d_in[0]; Wr[0] = d_in[1]; br[0] = d_in[2]; Wr[1] = d_in[3];
        br[1] = d_in[4]; Wr[2] = d_in[5]; br[2] = d_in[6]; Wr[3] = d_in[7];
        bor = d_in[8];
    }

    const float qscale = 0.04419417382415922f;  // 1/sqrt(512)
    const int   QC = 1 << 30;
    dim3 blk(256);

    // ---- workspace layout (bf16 elements) ----
    bf16* pool = (bf16*)d_ws;
    int*  flag = (int*)(void*)pool;
    bf16* xc   = pool + 8;
    bf16* bqc  = xc  + NX;
    bf16* bkc  = bqc + HE;
    bf16* bvc  = bkc + HE;
    bf16* boc  = bvc + HE;
    bf16* WqT  = boc + E;
    const size_t w2m = (size_t)E * HE;
    bf16* WkT  = WqT + w2m;
    bf16* WvT  = WkT + w2m;
    bf16* WoT  = WvT + w2m;
    bf16* Ofin = WoT + w2m;
    bf16* p0   = Ofin + NX;

    const size_t wsE    = ws_size / sizeof(bf16);
    const size_t fixedE = (size_t)(p0 - pool);
    const size_t wQK   = (size_t)T * N2;
    const size_t wQKV  = (size_t)T * N3;
    const size_t wBat  = (size_t)T * HE;
    const size_t wHd   = (size_t)T * E;
    const size_t sAll  = (size_t)H * T * T;
    const size_t sOne  = (size_t)T * T;
    const size_t wBig  = (size_t)M * HE;
    const size_t wL    = 32768;  // fp32 L[H][T] as bf16-el units
    const size_t needB2 = fixedE + wQK + wBat + sAll + wBig + wL;
    const size_t needB  = fixedE + wQKV + 2 * wBat + sAll;
    const size_t needC  = fixedE + 5 * wBat + sOne;
    const size_t needD  = fixedE + 5 * wHd  + sOne;
    if (wsE < needD) return;

    // ---- stage 0: dtype probe + canonicalize ----
    probe_dtype<<<dim3(1), blk, 0, stream>>>((const float*)xr, flag);
    convert_to_bf16<<<dim3((unsigned)((NX / 8 + 255) / 256)), blk, 0, stream>>>(
        xr, xc, NX, flag);
    convert_to_bf16<<<dim3(2), blk, 0, stream>>>(br[0], bqc, HE, flag);
    convert_to_bf16<<<dim3(2), blk, 0, stream>>>(br[1], bkc, HE, flag);
    convert_to_bf16<<<dim3(2), blk, 0, stream>>>(br[2], bvc, HE, flag);
    convert_to_bf16<<<dim3(1), blk, 0, stream>>>(bor, boc, E, flag);
    transpose_any<<<dim3(HE / 64, E / 64, 1), blk, 0, stream>>>(Wr[0], WqT, HE, E, flag);
    transpose_any<<<dim3(HE / 64, E / 64, 1), blk, 0, stream>>>(Wr[1], WkT, HE, E, flag);
    transpose_any<<<dim3(HE / 64, E / 64, 1), blk, 0, stream>>>(Wr[2], WvT, HE, E, flag);
    transpose_any<<<dim3(E / 64, HE / 64, 1), blk, 0, stream>>>(Wr[3], WoT, E, HE, flag);

    if (wsE >= needB2) {
        // ---- Tier B2: QKV (256²) -> zeroL -> QK (256², exp+L) ->
        //      PV (256² 8-phase, S read once) ; out-proj (128x256 split-K) ----
        bf16* QKb = p0;                  // [t, 8192] = Q|K; aliased for P later
        bf16* Vtb = QKb + wQK;           // [h,e,t]
        bf16* S   = Vtb + wBat;          // exp(scores) [h,t,s]
        bf16* Oatt = S + sAll;           // O_all [M, HE]
        float* Lbuf = (float*)(Oatt + wBig);   // fp32 [H][T]

        for (int b = 0; b < Bb; ++b) {
            const bf16* xb = xc + (size_t)b * T * E;
            gemm256<4, 2><<<dim3(N3 / 256, T / 256, 1), dim3(512), 0, stream>>>(
                xb, WqT, QKb, bqc, E, E, N2, 0, 0, 0, E, qscale, HE, Vtb, N2,
                nullptr);
            zero_f32<<<dim3(64), blk, 0, stream>>>(Lbuf, H * T);
            gemm256<1, 1><<<dim3(T / 256, T / 256, H), dim3(512), 0, stream>>>(
                QKb + HE, QKb, S, nullptr, N2, N2, T,
                (long)E, (long)E, (long)T * T, E, 1.f, QC, nullptr, 0, Lbuf);
            gemm_pv3<<<dim3(T / 256, E / 256, H), dim3(512), 0, stream>>>(
                Vtb, S, Oatt + (size_t)b * T * HE, Lbuf, T, T, HE,
                (long)E * T, (long)T * T, (long)E, T);
        }
        // out-proj: A=WoT (rows=ch), B=Oatt (rows=t), split-K=2 via z
        gemm128n<6, 6><<<dim3(M / 256, E / 128, 2), dim3(512), 0, stream>>>(
            WoT, Oatt, QKb, nullptr, HE, HE, E,
            0, 0, (long)M * E, HE / 2, HE / 2);
        reduce_emit<<<dim3((unsigned)((NX / 8 + 255) / 256)), blk, 0, stream>>>(
            QKb, boc, d_out, NX, E, flag);
        return;
    }

    if (wsE >= needB) {
        // ---- Tier B fallback: softmax path ----
        bf16* QKVb = p0;
        bf16* Vtb  = QKVb + wQKV;
        bf16* Oatt = Vtb + wBat;
        bf16* S    = Oatt + wBat;

        for (int b = 0; b < Bb; ++b) {
            const bf16* xb = xc + (size_t)b * T * E;
            gemm_bt<0><<<dim3(N3 / 128, T / 128, 1), blk, 0, stream>>>(
                xb, WqT, QKVb, bqc, E, E, N3, 0, 0, 0, E, qscale, HE, nullptr, 0);
            transpose_bf16<<<dim3(E / 64, T / 64, H), blk, 0, stream>>>(
                QKVb + 2 * HE, Vtb, N3, T, H, (long)E, (long)E * T, 0, 0);
            gemm_bt<0><<<dim3(T / 128, T / 128, H), blk, 0, stream>>>(
                QKVb, QKVb + HE, S, nullptr, N3, N3, T,
                (long)E, (long)E, (long)T * T, E, 1.f, QC, nullptr, 0);
            softmax_rows2048<<<dim3(H * T, 1, 1), blk, 0, stream>>>(S);
            gemm_bt<0><<<dim3(E / 128, T / 128, H), blk, 0, stream>>>(
                S, Vtb, Oatt, nullptr, T, T, HE,
                (long)T * T, (long)E * T, (long)E, T, 1.f, QC, nullptr, 0);
            gemm_bt_splitk<false><<<dim3(E / 128, T / 128, 8), blk, 0, stream>>>(
                Oatt, WoT, (bf16*)S, HE, HE, E, 0, 0, 0, (long)T * E, 8, HE / 8);
            reduce_splitk<<<dim3((unsigned)(((long)T * E / 8 + 255) / 256)), blk, 0, stream>>>(
                (bf16*)S, boc, Ofin + (size_t)b * T * E, (long)T * E, E, 8);
        }
    } else if (wsE >= needC) {
        // ---- Tier C fallback ----
        bf16* Qb  = p0;
        bf16* Kb  = Qb  + wBat;
        bf16* Vb  = Kb  + wBat;
        bf16* Vtb = Vb  + wBat;
        bf16* Ob  = Vtb + wBat;
        bf16* S   = Ob  + wBat;

        for (int b = 0; b < Bb; ++b) {
            const bf16* xb = xc + (size_t)b * T * E;
            gemm_bt<0><<<dim3(HE / 128, T / 128, 1), blk, 0, stream>>>(
                xb, WqT, Qb, bqc, E, E, HE, 0, 0, 0, E, qscale, QC, nullptr, 0);
            gemm_bt<0><<<dim3(HE / 128, T / 128, 1), blk, 0, stream>>>(
                xb, WkT, Kb, bkc, E, E, HE, 0, 0, 0, E, 1.f, QC, nullptr, 0);
            gemm_bt<0><<<dim3(HE / 128, T / 128, 1), blk, 0, stream>>>(
                xb, WvT, Vb, bvc, E, E, HE, 0, 0, 0, E, 1.f, QC, nullptr, 0);
            transpose_bf16<<<dim3(E / 64, T / 64, H), blk, 0, stream>>>(
                Vb, Vtb, HE, T, H, (long)E, (long)E * T, 0, 0);
            for (int h = 0; h < H; ++h) {
                gemm_bt<0><<<dim3(T / 128, T / 128, 1), blk, 0, stream>>>(
                    Qb + (size_t)h * E, Kb + (size_t)h * E, S, nullptr,
                    HE, HE, T, 0, 0, 0, E, 1.f, QC, nullptr, 0);
                softmax_rows2048<<<dim3(T, 1, 1), blk, 0, stream>>>(S);
                gemm_bt<0><<<dim3(E / 128, T / 128, 1), blk, 0, stream>>>(
                    S, Vtb + (size_t)h * E * T, Ob + (size_t)h * E, nullptr,
                    T, T, HE, 0, 0, 0, T, 1.f, QC, nullptr, 0);
            }
            gemm_bt<0><<<dim3(E / 128, T / 128, 1), blk, 0, stream>>>(
                Ob, WoT, Ofin + (size_t)b * T * E, boc,
                HE, HE, E, 0, 0, 0, HE, 1.f, QC, nullptr, 0);
        }
    } else {
        // ---- Tier D fallback ----
        bf16* Qh  = p0;
        bf16* Kh  = Qh  + wHd;
        bf16* Vh  = Kh  + wHd;
        bf16* Vth = Vh  + wHd;
        bf16* Oh  = Vth + wHd;
        bf16* S   = Oh  + wHd;

        for (int b = 0; b < Bb; ++b) {
            const bf16* xb = xc + (size_t)b * T * E;
            bf16* outb = Ofin + (size_t)b * T * E;
            for (int h = 0; h < H; ++h) {
                const size_t hw = (size_t)h * E * E;
                gemm_bt<0><<<dim3(E / 128, T / 128, 1), blk, 0, stream>>>(
                    xb, WqT + hw, Qh, bqc + (size_t)h * E, E, E, E,
                    0, 0, 0, E, qscale, QC, nullptr, 0);
                gemm_bt<0><<<dim3(E / 128, T / 128, 1), blk, 0, stream>>>(
                    xb, WkT + hw, Kh, bkc + (size_t)h * E, E, E, E,
                    0, 0, 0, E, 1.f, QC, nullptr, 0);
                gemm_bt<0><<<dim3(E / 128, T / 128, 1), blk, 0, stream>>>(
                    xb, WvT + hw, Vh, bvc + (size_t)h * E, E, E, E,
                    0, 0, 0, E, 1.f, QC, nullptr, 0);
                transpose_bf16<<<dim3(E / 64, T / 64, 1), blk, 0, stream>>>(
                    Vh, Vth, E, T, 1, 0, 0, 0, 0);
                gemm_bt<0><<<dim3(T / 128, T / 128, 1), blk, 0, stream>>>(
                    Qh, Kh, S, nullptr, E, E, T, 0, 0, 0, E, 1.f, QC, nullptr, 0);
                softmax_rows2048<<<dim3(T, 1, 1), blk, 0, stream>>>(S);
                gemm_bt<0><<<dim3(E / 128, T / 128, 1), blk, 0, stream>>>(
                    S, Vth, Oh, nullptr, T, T, E, 0, 0, 0, T, 1.f, QC, nullptr, 0);
                if (h == 0)
                    gemm_bt<0><<<dim3(E / 128, T / 128, 1), blk, 0, stream>>>(
                        Oh, WoT, outb, boc, E, HE, E, 0, 0, 0, E, 1.f, QC, nullptr, 0);
                else
                    gemm_bt<2><<<dim3(E / 128, T / 128, 1), blk, 0, stream>>>(
                        Oh, WoT + (size_t)h * E, outb, nullptr,
                        E, HE, E, 0, 0, 0, E, 1.f, QC, nullptr, 0);
            }
        }
    }

    // ---- emit in the probed dtype (fallback tiers only) ----
    emit_out<<<dim3((unsigned)((NX / 8 + 255) / 256)), blk, 0, stream>>>(
        Ofin, d_out, NX, flag);
}

// Round 9
// 899.475 us; speedup vs baseline: 1.0906x; 1.0721x over previous
//
#include <hip/hip_runtime.h>
#include <hip/hip_bf16.h>
#include <stdint.h>

typedef __hip_bfloat16 bf16;
typedef __bf16 bf16x8 __attribute__((ext_vector_type(8)));
typedef float floatx4 __attribute__((ext_vector_type(4)));

#define AS_LDS __attribute__((address_space(3)))
#define AS_GLB __attribute__((address_space(1)))

__device__ __forceinline__ void gload_lds16(const bf16* g, bf16* l) {
    __builtin_amdgcn_global_load_lds((const AS_GLB void*)g, (AS_LDS void*)l, 16, 0, 0);
}

// ---------- dtype probe: *flag = 1 if x is fp32, 0 if bf16 ----------
__global__ void probe_dtype(const float* __restrict__ x, int* __restrict__ flag) {
    __shared__ int cnt;
    if (threadIdx.x == 0) cnt = 0;
    __syncthreads();
    int ok = 0;
    for (int i = threadIdx.x; i < 4096; i += 256) {
        float v = x[i];
        if (v == v && fabsf(v) < 1.0e3f) ok++;
    }
    atomicAdd(&cnt, ok);
    __syncthreads();
    if (threadIdx.x == 0) *flag = (cnt > 2048) ? 1 : 0;
}

__global__ __launch_bounds__(256) void zero_f32(float* __restrict__ p, int n) {
    int i = blockIdx.x * 256 + threadIdx.x;
    if (i < n) p[i] = 0.f;
}

// ---------- convert raw (fp32 or bf16 per flag) -> canonical bf16 ----------
__global__ __launch_bounds__(256) void convert_to_bf16(
    const void* __restrict__ in, bf16* __restrict__ out, long n,
    const int* __restrict__ flag)
{
    long i = ((long)blockIdx.x * 256 + threadIdx.x) * 8;
    if (i >= n) return;
    bf16 o[8];
    if (*flag) {
        const float* p = (const float*)in + i;
        float4 a = *(const float4*)p;
        float4 b = *(const float4*)(p + 4);
        o[0] = __float2bfloat16(a.x); o[1] = __float2bfloat16(a.y);
        o[2] = __float2bfloat16(a.z); o[3] = __float2bfloat16(a.w);
        o[4] = __float2bfloat16(b.x); o[5] = __float2bfloat16(b.y);
        o[6] = __float2bfloat16(b.z); o[7] = __float2bfloat16(b.w);
    } else {
        *(float4*)o = *(const float4*)((const bf16*)in + i);
    }
    *(float4*)&out[i] = *(float4*)o;
}

// ---------- emit canonical bf16 -> d_out in flag dtype (fallback tiers) ----
__global__ __launch_bounds__(256) void emit_out(
    const bf16* __restrict__ in, void* __restrict__ out, long n,
    const int* __restrict__ flag)
{
    long i = ((long)blockIdx.x * 256 + threadIdx.x) * 8;
    if (i >= n) return;
    bf16 v[8];
    *(float4*)v = *(const float4*)&in[i];
    if (*flag) {
        float* o = (float*)out + i;
        float4 a, b;
        a.x = __bfloat162float(v[0]); a.y = __bfloat162float(v[1]);
        a.z = __bfloat162float(v[2]); a.w = __bfloat162float(v[3]);
        b.x = __bfloat162float(v[4]); b.y = __bfloat162float(v[5]);
        b.z = __bfloat162float(v[6]); b.w = __bfloat162float(v[7]);
        *(float4*)o = a;
        *(float4*)(o + 4) = b;
    } else {
        *(float4*)((bf16*)out + i) = *(float4*)v;
    }
}

// ---------- transpose raw-dtype input -> bf16 output ----------
__global__ __launch_bounds__(256) void transpose_any(
    const void* __restrict__ inv, bf16* __restrict__ out,
    int ldin, int ldout, const int* __restrict__ flag)
{
    __shared__ bf16 tile[64][80];
    const int fp32 = *flag;
    const int c0 = blockIdx.x * 64;
    const int r0 = blockIdx.y * 64;
    const int tid = threadIdx.x;
#pragma unroll
    for (int it = 0; it < 2; ++it) {
        int ch = tid + it * 256;
        int r = ch >> 3, c = (ch & 7) * 8;
        long eidx = (long)(r0 + r) * ldin + (c0 + c);
        if (fp32) {
            const float* p = (const float*)inv + eidx;
            float4 a = *(const float4*)p;
            float4 b = *(const float4*)(p + 4);
            bf16 o[8];
            o[0] = __float2bfloat16(a.x); o[1] = __float2bfloat16(a.y);
            o[2] = __float2bfloat16(a.z); o[3] = __float2bfloat16(a.w);
            o[4] = __float2bfloat16(b.x); o[5] = __float2bfloat16(b.y);
            o[6] = __float2bfloat16(b.z); o[7] = __float2bfloat16(b.w);
            *(float4*)&tile[r][c] = *(float4*)o;
        } else {
            *(float4*)&tile[r][c] = *(const float4*)((const bf16*)inv + eidx);
        }
    }
    __syncthreads();
#pragma unroll
    for (int it = 0; it < 2; ++it) {
        int ch = tid + it * 256;
        int oc = ch >> 3, rb = (ch & 7) * 8;
        bf16 tmp[8];
#pragma unroll
        for (int i = 0; i < 8; ++i) tmp[i] = tile[rb + i][oc];
        *(float4*)&out[(long)(c0 + oc) * ldout + r0 + rb] = *(float4*)tmp;
    }
}

// ---------- pure-bf16 transpose (fallback tiers) ----------
__global__ __launch_bounds__(256) void transpose_bf16(
    const bf16* __restrict__ in, bf16* __restrict__ out,
    int ldin, int ldout,
    int nz1, long in_z1, long out_z1, long in_z2, long out_z2)
{
    __shared__ bf16 tile[64][80];
    const int z = blockIdx.z;
    const int z1 = z % nz1, z2 = z / nz1;
    in  += (long)z1 * in_z1 + (long)z2 * in_z2;
    out += (long)z1 * out_z1 + (long)z2 * out_z2;
    const int c0 = blockIdx.x * 64;
    const int r0 = blockIdx.y * 64;
    const int tid = threadIdx.x;
#pragma unroll
    for (int it = 0; it < 2; ++it) {
        int ch = tid + it * 256;
        int r = ch >> 3, c = (ch & 7) * 8;
        *(float4*)&tile[r][c] = *(const float4*)&in[(long)(r0 + r) * ldin + c0 + c];
    }
    __syncthreads();
#pragma unroll
    for (int it = 0; it < 2; ++it) {
        int ch = tid + it * 256;
        int oc = ch >> 3, rb = (ch & 7) * 8;
        bf16 tmp[8];
#pragma unroll
        for (int i = 0; i < 8; ++i) tmp[i] = tile[rb + i][oc];
        *(float4*)&out[(long)(c0 + oc) * ldout + r0 + rb] = *(float4*)tmp;
    }
}

// =====================================================================
// 256x256-tile 8-wave 8-phase GEMM. C = A * Bt^T.
// MODE 1 (QK, swapped A=K,B=Q): S[q][s]=exp(acc), 8B stores; accumulates
//   rowsum L[q] via cross-lane reduce + fp32 atomicAdd.
// MODE 4 (QKV): Q|K part via 4x4 shuffle transpose -> 8B row stores;
//   V part written transposed to Vt.
// SWZ 1: head-per-XCD for grid (8,8,8). SWZ 2: 6-ntile chunks, grid (48,8,1).
// =====================================================================
template <int MODE, int SWZ>
__global__ __launch_bounds__(512, 2) void gemm256(
    const bf16* __restrict__ A, const bf16* __restrict__ Bt,
    bf16* __restrict__ C, const bf16* __restrict__ bias,
    int lda, int ldb, int ldc,
    long az, long bz, long cz, int K, float scale, int qcols,
    bf16* __restrict__ Vt, int vcol0, float* __restrict__ Lsum)
{
    __shared__ bf16 AsL[2][2][256 * 32];
    __shared__ bf16 BsL[2][2][256 * 32];

    const int tid  = threadIdx.x;
    const int lane = tid & 63;
    const int wave = tid >> 6;
    const int wr = wave >> 2;        // 0..1  row half of C tile
    const int wc = wave & 3;         // 0..3  col quarter of C tile
    const int lm = lane & 15;
    const int cl = lane >> 4;        // fragment k-chunk 0..3

    int bxx = blockIdx.x, byy = blockIdx.y, bzz = blockIdx.z;
    if constexpr (SWZ == 1) {        // grid (8,8,8): head z = XCD
        int flat = bxx + (byy << 3) + (bzz << 6);
        int xcd = flat & 7, idx = flat >> 3;
        bzz = xcd; bxx = idx & 7; byy = idx >> 3;
    } else if constexpr (SWZ == 2) { // grid (48,8,1): 6 n-tiles per XCD
        int flat = bxx + byy * 48;
        int xcd = flat & 7, idx = flat >> 3;
        bxx = xcd * 6 + idx % 6; byy = idx / 6; bzz = 0;
    }
    const long zz = bzz;
    A  += zz * az;
    Bt += zz * bz;
    C  += zz * cz;
    float* Lz = (MODE == 1) ? (Lsum + zz * 2048) : nullptr;
    const int m0 = byy * 256;
    const int n0 = bxx * 256;

    // per-lane swizzled ds_read offsets within a [256][32] k-half block
    int offA[8], offB[4];
#pragma unroll
    for (int i = 0; i < 8; ++i) {
        int row = wr * 128 + i * 16 + lm;
        offA[i] = row * 32 + ((cl ^ ((row >> 1) & 3)) << 3);
    }
#pragma unroll
    for (int j = 0; j < 4; ++j) {
        int row = wc * 64 + j * 16 + lm;
        offB[j] = row * 32 + ((cl ^ ((row >> 1) & 3)) << 3);
    }

    const int sr = lane >> 2;        // staging row-in-16
    const int sc = lane & 3;         // staging chunk
    const int NT = K >> 6;           // 64-wide K tiles (NT even)

    floatx4 acc[8][4];
#pragma unroll
    for (int i = 0; i < 8; ++i)
#pragma unroll
        for (int j = 0; j < 4; ++j)
            acc[i][j] = (floatx4){0.f, 0.f, 0.f, 0.f};

    // stage one (operand, khalf) unit of tile t: 2 x global_load_lds
    auto stageU = [&](int which, int t, int kh) {
        if (t >= NT) return;
        const bf16* G = which ? Bt : A;
        const int ldg  = which ? ldb : lda;
        const int g0   = which ? n0 : m0;
        bf16* lb = which ? &BsL[t & 1][kh][0] : &AsL[t & 1][kh][0];
        const int kcol = t * 64 + kh * 32;
#pragma unroll
        for (int ii = 0; ii < 2; ++ii) {
            int row = ii * 128 + wave * 16 + sr;
            int cg  = sc ^ ((row >> 1) & 3);   // pre-swizzled global chunk
            gload_lds16(G + (long)(g0 + row) * ldg + kcol + cg * 8,
                        lb + row * 32 + sc * 8);
        }
    };

    bf16x8 af[8], bfv[2];
    auto dsA = [&](int b, int kh) {
        const bf16* p = &AsL[b][kh][0];
#pragma unroll
        for (int i = 0; i < 8; ++i) af[i] = *(const bf16x8*)(p + offA[i]);
    };
    auto dsB = [&](int b, int kh, int nh) {
        const bf16* p = &BsL[b][kh][0];
        bfv[0] = *(const bf16x8*)(p + offB[nh * 2]);
        bfv[1] = *(const bf16x8*)(p + offB[nh * 2 + 1]);
    };
    auto mfmaQ = [&](int nh) {
        __builtin_amdgcn_s_setprio(1);
#pragma unroll
        for (int i = 0; i < 8; ++i) {
            acc[i][nh * 2] = __builtin_amdgcn_mfma_f32_16x16x32_bf16(
                af[i], bfv[0], acc[i][nh * 2], 0, 0, 0);
            acc[i][nh * 2 + 1] = __builtin_amdgcn_mfma_f32_16x16x32_bf16(
                af[i], bfv[1], acc[i][nh * 2 + 1], 0, 0, 0);
        }
        __builtin_amdgcn_s_setprio(0);
    };

#define BAR    __builtin_amdgcn_s_barrier()
#define SBZ    __builtin_amdgcn_sched_barrier(0)
#define LGKM0  do { asm volatile("s_waitcnt lgkmcnt(0)" ::: "memory"); SBZ; } while (0)
#define VM(n)  do { asm volatile("s_waitcnt vmcnt(" #n ")" ::: "memory"); SBZ; } while (0)

    // ---- prologue: tile0 (all), tile1 k0 ----
    stageU(0, 0, 0); stageU(1, 0, 0); stageU(0, 0, 1); stageU(1, 0, 1);
    stageU(0, 1, 0); stageU(1, 1, 0);
    VM(4);
    BAR;

    for (int t0 = 0; t0 < NT; t0 += 2) {
        const bool last = (t0 + 2 >= NT);
        dsA(0, 0); dsB(0, 0, 0); stageU(0, t0 + 1, 1);
        BAR; LGKM0; mfmaQ(0); BAR;
        dsB(0, 0, 1); stageU(1, t0 + 1, 1);
        BAR; LGKM0; mfmaQ(1); BAR;
        dsA(0, 1); dsB(0, 1, 0); stageU(0, t0 + 2, 0);
        BAR; LGKM0; mfmaQ(0); BAR;
        dsB(0, 1, 1); stageU(1, t0 + 2, 0);
        BAR; LGKM0; mfmaQ(1);
        if (last) { VM(0); } else { VM(4); }
        BAR;
        dsA(1, 0); dsB(1, 0, 0); stageU(0, t0 + 2, 1);
        BAR; LGKM0; mfmaQ(0); BAR;
        dsB(1, 0, 1); stageU(1, t0 + 2, 1);
        BAR; LGKM0; mfmaQ(1); BAR;
        dsA(1, 1); dsB(1, 1, 0); stageU(0, t0 + 3, 0);
        BAR; LGKM0; mfmaQ(0); BAR;
        dsB(1, 1, 1); stageU(1, t0 + 3, 0);
        BAR; LGKM0; mfmaQ(1);
        if (!last) { VM(4); }
        BAR;
    }
#undef BAR
#undef SBZ
#undef LGKM0
#undef VM

    // ---- epilogue ----
    const int cr = (lane >> 4) * 4;
    if constexpr (MODE == 1) {
        // swapped operands: acc(row=s, col=q). Store S[q][s] = exp(acc):
        // lane holds 4 consecutive s -> 8B packet. Also rowsum -> atomic.
#pragma unroll
        for (int j = 0; j < 4; ++j) {
            long q = n0 + wc * 64 + j * 16 + lm;
            bf16* Cr = C + q * ldc + m0 + wr * 128;
            float rs = 0.f;
#pragma unroll
            for (int i = 0; i < 8; ++i) {
                bf16 pk[4];
#pragma unroll
                for (int r = 0; r < 4; ++r) {
                    float e = __expf(acc[i][j][r]);
                    rs += e;
                    pk[r] = __float2bfloat16(e);
                }
                *(uint64_t*)&Cr[i * 16 + cr] = *(const uint64_t*)pk;
            }
            rs += __shfl_xor(rs, 16);
            rs += __shfl_xor(rs, 32);
            if (cl == 0) atomicAdd(&Lz[q], rs);
        }
    } else {   // MODE 4
        if (n0 >= vcol0) {
            // V block: write transposed, packed 4 consecutive t per 8B store
#pragma unroll
            for (int j = 0; j < 4; ++j) {
                int col = n0 + wc * 64 + j * 16 + lm;
                float bv = __bfloat162float(bias[col]);
                int eg = col - vcol0;
                bf16* vt = Vt + ((long)(eg >> 9) * 512 + (eg & 511)) * 2048;
#pragma unroll
                for (int i = 0; i < 8; ++i) {
                    int t0v = m0 + wr * 128 + i * 16 + cr;
                    bf16 pk[4];
#pragma unroll
                    for (int r = 0; r < 4; ++r)
                        pk[r] = __float2bfloat16(acc[i][j][r] + bv);
                    *(uint64_t*)&vt[t0v] = *(const uint64_t*)pk;
                }
            }
        } else {
            // Q|K: bias+scale, then 4x4 shuffle transpose -> 8B row stores
            const int l4 = lane & 3;
            float bvj[4], scj[4];
#pragma unroll
            for (int j = 0; j < 4; ++j) {
                int col = n0 + wc * 64 + j * 16 + lm;
                bvj[j] = __bfloat162float(bias[col]);
                scj[j] = (col < qcols) ? scale : 1.0f;
            }
#pragma unroll
            for (int i = 0; i < 8; ++i) {
                int row = m0 + wr * 128 + i * 16 + cr + l4;
                bf16* Cr = C + (long)row * ldc + n0 + wc * 64 + (lm & ~3);
#pragma unroll
                for (int j = 0; j < 4; ++j) {
                    float x0 = (acc[i][j][0] + bvj[j]) * scj[j];
                    float x1 = (acc[i][j][1] + bvj[j]) * scj[j];
                    float x2 = (acc[i][j][2] + bvj[j]) * scj[j];
                    float x3 = (acc[i][j][3] + bvj[j]) * scj[j];
                    float u = __shfl_xor((l4 & 1) ? x0 : x1, 1);
                    float v = __shfl_xor((l4 & 1) ? x2 : x3, 1);
                    if (l4 & 1) { x0 = u; x2 = v; } else { x1 = u; x3 = v; }
                    u = __shfl_xor((l4 & 2) ? x0 : x2, 2);
                    v = __shfl_xor((l4 & 2) ? x1 : x3, 2);
                    if (l4 & 2) { x0 = u; x1 = v; } else { x2 = u; x3 = v; }
                    bf16 pk[4];
                    pk[0] = __float2bfloat16(x0); pk[1] = __float2bfloat16(x1);
                    pk[2] = __float2bfloat16(x2); pk[3] = __float2bfloat16(x3);
                    *(uint64_t*)&Cr[j * 16] = *(const uint64_t*)pk;
                }
            }
        }
    }
}

// =====================================================================
// PV kernel (batch-paired): 256x256-tile 8-wave 8-phase, grid (256,1,1).
// Covers TWO batches in one dispatch -> full machine (fixes the 128-block
// MLP limit: 1.4 TB/s ceiling observed in round 8).
// flat = blockIdx.x: head = flat&7 (= XCD under round-robin), idx = flat>>3:
// q-tile = idx&7, ch-tile = (idx>>3)&1, batch-half i = idx>>4.
// A = Vt2 (+i*abz + h*az), Bt = S2 (+i*sbz + h*bz), C = O (+i*cbz + h*cz).
// O[q][ch] = acc / L[q]; 8B packets of 4 consecutive ch.
// =====================================================================
__global__ __launch_bounds__(512, 2) void gemm_pv3(
    const bf16* __restrict__ A, const bf16* __restrict__ Bt,
    bf16* __restrict__ C, const float* __restrict__ L,
    int lda, int ldb, int ldc,
    long az, long bz, long cz,
    long abz, long sbz, long cbz, int K)
{
    __shared__ bf16 AsL[2][2][256 * 32];
    __shared__ bf16 BsL[2][2][256 * 32];

    const int tid  = threadIdx.x;
    const int lane = tid & 63;
    const int wave = tid >> 6;
    const int wr = wave >> 2;
    const int wc = wave & 3;
    const int lm = lane & 15;
    const int cl = lane >> 4;

    const int flat = blockIdx.x;     // 0..255
    const int h   = flat & 7;        // head = XCD
    const int idx = flat >> 3;
    const int qb  = idx & 7;         // q-tile 0..7
    const int chb = (idx >> 3) & 1;  // ch-tile 0..1
    const int ib  = idx >> 4;        // batch-half 0..1
    A  += (long)ib * abz + (long)h * az;
    Bt += (long)ib * sbz + (long)h * bz;
    C  += (long)ib * cbz + (long)h * cz;
    const float* Lz = L + (long)ib * 16384 + (long)h * 2048;
    const int m0 = chb * 256;        // ch base
    const int n0 = qb * 256;         // q base

    int offA[8], offB[4];
#pragma unroll
    for (int i = 0; i < 8; ++i) {
        int row = wr * 128 + i * 16 + lm;
        offA[i] = row * 32 + ((cl ^ ((row >> 1) & 3)) << 3);
    }
#pragma unroll
    for (int j = 0; j < 4; ++j) {
        int row = wc * 64 + j * 16 + lm;
        offB[j] = row * 32 + ((cl ^ ((row >> 1) & 3)) << 3);
    }

    const int sr = lane >> 2;
    const int sc = lane & 3;
    const int NT = K >> 6;           // 32, even

    floatx4 acc[8][4];
#pragma unroll
    for (int i = 0; i < 8; ++i)
#pragma unroll
        for (int j = 0; j < 4; ++j)
            acc[i][j] = (floatx4){0.f, 0.f, 0.f, 0.f};

    auto stageU = [&](int which, int t, int kh) {
        if (t >= NT) return;
        const bf16* G = which ? Bt : A;
        const int ldg  = which ? ldb : lda;
        const int g0   = which ? n0 : m0;
        bf16* lb = which ? &BsL[t & 1][kh][0] : &AsL[t & 1][kh][0];
        const int kcol = t * 64 + kh * 32;
#pragma unroll
        for (int ii = 0; ii < 2; ++ii) {
            int row = ii * 128 + wave * 16 + sr;
            int cg  = sc ^ ((row >> 1) & 3);
            gload_lds16(G + (long)(g0 + row) * ldg + kcol + cg * 8,
                        lb + row * 32 + sc * 8);
        }
    };

    bf16x8 af[8], bfv[2];
    auto dsA = [&](int b, int kh) {
        const bf16* p = &AsL[b][kh][0];
#pragma unroll
        for (int i = 0; i < 8; ++i) af[i] = *(const bf16x8*)(p + offA[i]);
    };
    auto dsB = [&](int b, int kh, int nh) {
        const bf16* p = &BsL[b][kh][0];
        bfv[0] = *(const bf16x8*)(p + offB[nh * 2]);
        bfv[1] = *(const bf16x8*)(p + offB[nh * 2 + 1]);
    };
    auto mfmaQ = [&](int nh) {
        __builtin_amdgcn_s_setprio(1);
#pragma unroll
        for (int i = 0; i < 8; ++i) {
            acc[i][nh * 2] = __builtin_amdgcn_mfma_f32_16x16x32_bf16(
                af[i], bfv[0], acc[i][nh * 2], 0, 0, 0);
            acc[i][nh * 2 + 1] = __builtin_amdgcn_mfma_f32_16x16x32_bf16(
                af[i], bfv[1], acc[i][nh * 2 + 1], 0, 0, 0);
        }
        __builtin_amdgcn_s_setprio(0);
    };

#define BAR    __builtin_amdgcn_s_barrier()
#define SBZ    __builtin_amdgcn_sched_barrier(0)
#define LGKM0  do { asm volatile("s_waitcnt lgkmcnt(0)" ::: "memory"); SBZ; } while (0)
#define VM(n)  do { asm volatile("s_waitcnt vmcnt(" #n ")" ::: "memory"); SBZ; } while (0)

    stageU(0, 0, 0); stageU(1, 0, 0); stageU(0, 0, 1); stageU(1, 0, 1);
    stageU(0, 1, 0); stageU(1, 1, 0);
    VM(4);
    BAR;

    for (int t0 = 0; t0 < NT; t0 += 2) {
        const bool last = (t0 + 2 >= NT);
        dsA(0, 0); dsB(0, 0, 0); stageU(0, t0 + 1, 1);
        BAR; LGKM0; mfmaQ(0); BAR;
        dsB(0, 0, 1); stageU(1, t0 + 1, 1);
        BAR; LGKM0; mfmaQ(1); BAR;
        dsA(0, 1); dsB(0, 1, 0); stageU(0, t0 + 2, 0);
        BAR; LGKM0; mfmaQ(0); BAR;
        dsB(0, 1, 1); stageU(1, t0 + 2, 0);
        BAR; LGKM0; mfmaQ(1);
        if (last) { VM(0); } else { VM(4); }
        BAR;
        dsA(1, 0); dsB(1, 0, 0); stageU(0, t0 + 2, 1);
        BAR; LGKM0; mfmaQ(0); BAR;
        dsB(1, 0, 1); stageU(1, t0 + 2, 1);
        BAR; LGKM0; mfmaQ(1); BAR;
        dsA(1, 1); dsB(1, 1, 0); stageU(0, t0 + 3, 0);
        BAR; LGKM0; mfmaQ(0); BAR;
        dsB(1, 1, 1); stageU(1, t0 + 3, 0);
        BAR; LGKM0; mfmaQ(1);
        if (!last) { VM(4); }
        BAR;
    }
#undef BAR
#undef SBZ
#undef LGKM0
#undef VM

    // epilogue: acc rows = ch, cols = q. O[q][ch] = acc / L[q].
    const int cr = (lane >> 4) * 4;
#pragma unroll
    for (int j = 0; j < 4; ++j) {
        long q = n0 + wc * 64 + j * 16 + lm;
        float inv = 1.0f / Lz[q];
        bf16* Cr = C + q * ldc + m0 + wr * 128;
#pragma unroll
        for (int i = 0; i < 8; ++i) {
            bf16 pk[4];
#pragma unroll
            for (int r = 0; r < 4; ++r)
                pk[r] = __float2bfloat16(acc[i][j][r] * inv);
            *(uint64_t*)&Cr[i * 16 + cr] = *(const uint64_t*)pk;
        }
    }
}

// =====================================================================
// 128(M)x256(N)-tile 8-wave 8-phase GEMM. 96KB LDS.
// MODE 5 (PV fallback): O[q][ch] = acc / L[q].
// MODE 6 (out-proj split-K): P[t][ch] = acc partial, z = k-split.
// SWZ 5: head-per-XCD, grid (8,4,8). SWZ 6: chunked, grid (32,4,2).
// =====================================================================
template <int MODE, int SWZ>
__global__ __launch_bounds__(512, 2) void gemm128n(
    const bf16* __restrict__ A, const bf16* __restrict__ Bt,
    bf16* __restrict__ C, const float* __restrict__ L,
    int lda, int ldb, int ldc,
    long az, long bz, long cz, int K, int kper)
{
    __shared__ bf16 AsL[2][2][128 * 32];
    __shared__ bf16 BsL[2][2][256 * 32];

    const int tid  = threadIdx.x;
    const int lane = tid & 63;
    const int wave = tid >> 6;
    const int wr = wave >> 2;        // 0..1  m-half (64 rows)
    const int wc = wave & 3;         // 0..3  n-quarter (64 cols)
    const int lm = lane & 15;
    const int cl = lane >> 4;

    int bxx = blockIdx.x, byy = blockIdx.y, bzz = blockIdx.z;
    if constexpr (SWZ == 5) {        // grid (8,4,8): head z = XCD
        int flat = bxx + (byy << 3) + (bzz << 5);
        int xcd = flat & 7, idx = flat >> 3;
        bzz = xcd; bxx = idx & 7; byy = idx >> 3;
    } else if constexpr (SWZ == 6) { // grid (32,4,2): chunked remap
        int flat = bxx + (byy << 5) + (bzz << 7);
        int nf = (flat & 7) * 32 + (flat >> 3);
        bzz = nf >> 7; int rr = nf & 127; byy = rr >> 5; bxx = rr & 31;
    }
    const long zz = bzz;
    A  += zz * az;
    Bt += zz * bz;
    C  += zz * cz;
    const float* Lz = (MODE == 5) ? (L + zz * 2048) : nullptr;
    const int kbase = (int)(zz * (long)kper);
    const int m0 = byy * 128;
    const int n0 = bxx * 256;

    int offA[4], offB[4];
#pragma unroll
    for (int i = 0; i < 4; ++i) {
        int row = wr * 64 + i * 16 + lm;
        offA[i] = row * 32 + ((cl ^ ((row >> 1) & 3)) << 3);
    }
#pragma unroll
    for (int j = 0; j < 4; ++j) {
        int row = wc * 64 + j * 16 + lm;
        offB[j] = row * 32 + ((cl ^ ((row >> 1) & 3)) << 3);
    }

    const int sr = lane >> 2;
    const int sc = lane & 3;
    const int NT = K >> 6;           // even

    floatx4 acc[4][4];
#pragma unroll
    for (int i = 0; i < 4; ++i)
#pragma unroll
        for (int j = 0; j < 4; ++j)
            acc[i][j] = (floatx4){0.f, 0.f, 0.f, 0.f};

    auto stageA = [&](int t, int kh) {   // 1 load/thread
        if (t >= NT) return;
        bf16* lb = &AsL[t & 1][kh][0];
        const int kcol = kbase + t * 64 + kh * 32;
        int row = wave * 16 + sr;
        int cg  = sc ^ ((row >> 1) & 3);
        gload_lds16(A + (long)(m0 + row) * lda + kcol + cg * 8,
                    lb + row * 32 + sc * 8);
    };
    auto stageB = [&](int t, int kh) {   // 2 loads/thread
        if (t >= NT) return;
        bf16* lb = &BsL[t & 1][kh][0];
        const int kcol = kbase + t * 64 + kh * 32;
#pragma unroll
        for (int ii = 0; ii < 2; ++ii) {
            int row = ii * 128 + wave * 16 + sr;
            int cg  = sc ^ ((row >> 1) & 3);
            gload_lds16(Bt + (long)(n0 + row) * ldb + kcol + cg * 8,
                        lb + row * 32 + sc * 8);
        }
    };

    bf16x8 af[4], bfv[2];
    auto dsA = [&](int b, int kh) {
        const bf16* p = &AsL[b][kh][0];
#pragma unroll
        for (int i = 0; i < 4; ++i) af[i] = *(const bf16x8*)(p + offA[i]);
    };
    auto dsB = [&](int b, int kh, int nh) {
        const bf16* p = &BsL[b][kh][0];
        bfv[0] = *(const bf16x8*)(p + offB[nh * 2]);
        bfv[1] = *(const bf16x8*)(p + offB[nh * 2 + 1]);
    };
    auto mfmaQ = [&](int nh) {
        __builtin_amdgcn_s_setprio(1);
#pragma unroll
        for (int i = 0; i < 4; ++i) {
            acc[i][nh * 2] = __builtin_amdgcn_mfma_f32_16x16x32_bf16(
                af[i], bfv[0], acc[i][nh * 2], 0, 0, 0);
            acc[i][nh * 2 + 1] = __builtin_amdgcn_mfma_f32_16x16x32_bf16(
                af[i], bfv[1], acc[i][nh * 2 + 1], 0, 0, 0);
        }
        __builtin_amdgcn_s_setprio(0);
    };

#define BAR    __builtin_amdgcn_s_barrier()
#define SBZ    __builtin_amdgcn_sched_barrier(0)
#define LGKM0  do { asm volatile("s_waitcnt lgkmcnt(0)" ::: "memory"); SBZ; } while (0)
#define VM(n)  do { asm volatile("s_waitcnt vmcnt(" #n ")" ::: "memory"); SBZ; } while (0)

    stageA(0, 0); stageB(0, 0); stageA(0, 1); stageB(0, 1);
    stageA(1, 0); stageB(1, 0);
    VM(3);
    BAR;

    for (int t0 = 0; t0 < NT; t0 += 2) {
        const bool last = (t0 + 2 >= NT);
        dsA(0, 0); dsB(0, 0, 0); stageA(t0 + 1, 1);
        BAR; LGKM0; mfmaQ(0); BAR;
        dsB(0, 0, 1); stageB(t0 + 1, 1);
        BAR; LGKM0; mfmaQ(1); BAR;
        dsA(0, 1); dsB(0, 1, 0); stageA(t0 + 2, 0);
        BAR; LGKM0; mfmaQ(0); BAR;
        dsB(0, 1, 1); stageB(t0 + 2, 0);
        BAR; LGKM0; mfmaQ(1);
        if (last) { VM(0); } else { VM(3); }
        BAR;
        dsA(1, 0); dsB(1, 0, 0); stageA(t0 + 2, 1);
        BAR; LGKM0; mfmaQ(0); BAR;
        dsB(1, 0, 1); stageB(t0 + 2, 1);
        BAR; LGKM0; mfmaQ(1); BAR;
        dsA(1, 1); dsB(1, 1, 0); stageA(t0 + 3, 0);
        BAR; LGKM0; mfmaQ(0); BAR;
        dsB(1, 1, 1); stageB(t0 + 3, 0);
        BAR; LGKM0; mfmaQ(1);
        if (!last) { VM(3); }
        BAR;
    }
#undef BAR
#undef SBZ
#undef LGKM0
#undef VM

    const int cr = cl * 4;
#pragma unroll
    for (int j = 0; j < 4; ++j) {
        int col = n0 + wc * 64 + j * 16 + lm;
        bf16* Cr = C + (long)col * ldc + m0 + wr * 64;
        float inv = 1.0f;
        if constexpr (MODE == 5) inv = 1.0f / Lz[col];
#pragma unroll
        for (int i = 0; i < 4; ++i) {
            bf16 pk[4];
#pragma unroll
            for (int r = 0; r < 4; ++r)
                pk[r] = __float2bfloat16(acc[i][j][r] * inv);
            *(uint64_t*)&Cr[i * 16 + cr] = *(const uint64_t*)pk;
        }
    }
}

// ---------- GEMM (bf16 in/out, fp32 acc), fallback tiers -----------------
template <int MODE, bool SWAP = false>
__global__ __launch_bounds__(256) void gemm_bt(
    const bf16* __restrict__ A, const bf16* __restrict__ Bt,
    bf16* __restrict__ C, const bf16* __restrict__ bias,
    int lda, int ldb, int ldc,
    long az, long bz, long cz, int K, float scale, int qcols,
    bf16* __restrict__ Vt, int vcol0)
{
    __shared__ bf16 As[128 * 64];
    __shared__ bf16 Bs[128 * 64];

    const int tid  = threadIdx.x;
    const int lane = tid & 63;
    const int wave = tid >> 6;
    const int wx = wave & 1;
    const int wy = wave >> 1;

    const long zz = blockIdx.z;
    A  += zz * az;
    Bt += zz * bz;
    C  += zz * cz;
    const int bm = SWAP ? blockIdx.x : blockIdx.y;
    const int bn = SWAP ? blockIdx.y : blockIdx.x;
    const int m0 = bm * 128;
    const int n0 = bn * 128;

    const int lm = lane & 15;
    const int kq = (lane >> 4) * 8;

    floatx4 acc[4][4];
#pragma unroll
    for (int i = 0; i < 4; ++i)
#pragma unroll
        for (int j = 0; j < 4; ++j)
            acc[i][j] = (floatx4){0.f, 0.f, 0.f, 0.f};

    for (int kt = 0; kt < K; kt += 64) {
        __syncthreads();
#pragma unroll
        for (int it = 0; it < 4; ++it) {
            int ch = tid + it * 256;
            int r = ch >> 3;
            int c = (ch & 7) * 8;
            gload_lds16(A  + (long)(m0 + r) * lda + (kt + c), &As[ch * 8]);
            gload_lds16(Bt + (long)(n0 + r) * ldb + (kt + c), &Bs[ch * 8]);
        }
        __syncthreads();
#pragma unroll
        for (int kk = 0; kk < 64; kk += 32) {
            bf16x8 af[4], bfv[4];
#pragma unroll
            for (int i = 0; i < 4; ++i)
                af[i] = *(const bf16x8*)&As[(wy * 64 + i * 16 + lm) * 64 + kk + kq];
#pragma unroll
            for (int j = 0; j < 4; ++j)
                bfv[j] = *(const bf16x8*)&Bs[(wx * 64 + j * 16 + lm) * 64 + kk + kq];
#pragma unroll
            for (int i = 0; i < 4; ++i)
#pragma unroll
                for (int j = 0; j < 4; ++j)
                    acc[i][j] = __builtin_amdgcn_mfma_f32_16x16x32_bf16(
                        af[i], bfv[j], acc[i][j], 0, 0, 0);
        }
    }

    const int cr = (lane >> 4) * 4;
    if constexpr (MODE == 1) {
#pragma unroll
        for (int j = 0; j < 4; ++j) {
            int col = n0 + wx * 64 + j * 16 + lm;
#pragma unroll
            for (int i = 0; i < 4; ++i)
#pragma unroll
                for (int r = 0; r < 4; ++r) {
                    int row = m0 + wy * 64 + i * 16 + cr + r;
                    C[(long)row * ldc + col] = __float2bfloat16(__expf(acc[i][j][r]));
                }
        }
    } else {
#pragma unroll
        for (int j = 0; j < 4; ++j) {
            int col = n0 + wx * 64 + j * 16 + lm;
            float bv = (MODE == 0 && bias) ? __bfloat162float(bias[col]) : 0.f;
            float sc = (col < qcols) ? scale : 1.0f;
#pragma unroll
            for (int i = 0; i < 4; ++i) {
#pragma unroll
                for (int r = 0; r < 4; ++r) {
                    int row = m0 + wy * 64 + i * 16 + cr + r;
                    long idx = (long)row * ldc + col;
                    float v;
                    if (MODE == 2) v = acc[i][j][r] + __bfloat162float(C[idx]);
                    else           v = (acc[i][j][r] + bv) * sc;
                    C[idx] = __float2bfloat16(v);
                }
            }
        }
    }
}

// ---------- split-K GEMM, bf16 partials (fallback tiers) ------------------
template <bool SWAP = false>
__global__ __launch_bounds__(256) void gemm_bt_splitk(
    const bf16* __restrict__ A, const bf16* __restrict__ Bt,
    bf16* __restrict__ P, int lda, int ldb, int ldp,
    long az, long bz, long pz, long skStride, int nsk, int Kc)
{
    __shared__ bf16 As[128 * 64];
    __shared__ bf16 Bs[128 * 64];

    const int tid  = threadIdx.x;
    const int lane = tid & 63;
    const int wave = tid >> 6;
    const int wx = wave & 1;
    const int wy = wave >> 1;
    const int zz = blockIdx.z;
    const int ks = zz % nsk;
    const int zh = zz / nsk;
    A  += (long)zh * az;
    Bt += (long)zh * bz;
    bf16* Pz = P + (long)zh * pz + (long)ks * skStride;
    const int bm = SWAP ? blockIdx.x : blockIdx.y;
    const int bn = SWAP ? blockIdx.y : blockIdx.x;
    const int m0 = bm * 128;
    const int n0 = bn * 128;
    const int k0 = ks * Kc;

    const int lm = lane & 15;
    const int kq = (lane >> 4) * 8;

    floatx4 acc[4][4];
#pragma unroll
    for (int i = 0; i < 4; ++i)
#pragma unroll
        for (int j = 0; j < 4; ++j)
            acc[i][j] = (floatx4){0.f, 0.f, 0.f, 0.f};

    for (int kt = k0; kt < k0 + Kc; kt += 64) {
        __syncthreads();
#pragma unroll
        for (int it = 0; it < 4; ++it) {
            int ch = tid + it * 256;
            int r = ch >> 3;
            int c = (ch & 7) * 8;
            gload_lds16(A  + (long)(m0 + r) * lda + (kt + c), &As[ch * 8]);
            gload_lds16(Bt + (long)(n0 + r) * ldb + (kt + c), &Bs[ch * 8]);
        }
        __syncthreads();
#pragma unroll
        for (int kk = 0; kk < 64; kk += 32) {
            bf16x8 af[4], bfv[4];
#pragma unroll
            for (int i = 0; i < 4; ++i)
                af[i] = *(const bf16x8*)&As[(wy * 64 + i * 16 + lm) * 64 + kk + kq];
#pragma unroll
            for (int j = 0; j < 4; ++j)
                bfv[j] = *(const bf16x8*)&Bs[(wx * 64 + j * 16 + lm) * 64 + kk + kq];
#pragma unroll
            for (int i = 0; i < 4; ++i)
#pragma unroll
                for (int j = 0; j < 4; ++j)
                    acc[i][j] = __builtin_amdgcn_mfma_f32_16x16x32_bf16(
                        af[i], bfv[j], acc[i][j], 0, 0, 0);
        }
    }

    const int cr = (lane >> 4) * 4;
#pragma unroll
    for (int j = 0; j < 4; ++j) {
        int col = n0 + wx * 64 + j * 16 + lm;
#pragma unroll
        for (int i = 0; i < 4; ++i)
#pragma unroll
            for (int r = 0; r < 4; ++r) {
                int row = m0 + wy * 64 + i * 16 + cr + r;
                Pz[(long)row * ldp + col] = __float2bfloat16(acc[i][j][r]);
            }
    }
}

// ---------- reduce 2 bf16 split-K partials + bias -> d_out in flag dtype ----
__global__ __launch_bounds__(256) void reduce_emit(
    const bf16* __restrict__ P, const bf16* __restrict__ bias,
    void* __restrict__ out, long MN, int N,
    const int* __restrict__ flag)
{
    long i = ((long)blockIdx.x * 256 + threadIdx.x) * 8;
    if (i >= MN) return;
    bf16 bb[8], a[8], b[8];
    *(float4*)bb = *(const float4*)&bias[i & (N - 1)];
    *(float4*)a  = *(const float4*)&P[i];
    *(float4*)b  = *(const float4*)&P[MN + i];
    float s[8];
#pragma unroll
    for (int k = 0; k < 8; ++k)
        s[k] = __bfloat162float(bb[k]) + __bfloat162float(a[k]) + __bfloat162float(b[k]);
    if (*flag) {
        float* o = (float*)out + i;
        float4 lo = {s[0], s[1], s[2], s[3]};
        float4 hi = {s[4], s[5], s[6], s[7]};
        *(float4*)o = lo;
        *(float4*)(o + 4) = hi;
    } else {
        bf16 o[8];
#pragma unroll
        for (int k = 0; k < 8; ++k) o[k] = __float2bfloat16(s[k]);
        *(float4*)&((bf16*)out)[i] = *(float4*)o;
    }
}

// ---------- reduce bf16 split-K partials + bias -> bf16 (fallback) ----------
__global__ __launch_bounds__(256) void reduce_splitk(
    const bf16* __restrict__ P, const bf16* __restrict__ bias,
    bf16* __restrict__ Out, long MN, int N, int SK)
{
    long i = ((long)blockIdx.x * 256 + threadIdx.x) * 8;
    if (i >= MN) return;
    float s[8];
    if (bias) {
        bf16 bb[8];
        *(float4*)bb = *(const float4*)&bias[i & (N - 1)];
#pragma unroll
        for (int k = 0; k < 8; ++k) s[k] = __bfloat162float(bb[k]);
    } else {
#pragma unroll
        for (int k = 0; k < 8; ++k) s[k] = 0.f;
    }
    for (int z = 0; z < SK; ++z) {
        bf16 a[8];
        *(float4*)a = *(const float4*)&P[(long)z * MN + i];
#pragma unroll
        for (int k = 0; k < 8; ++k) s[k] += __bfloat162float(a[k]);
    }
    bf16 o[8];
#pragma unroll
    for (int k = 0; k < 8; ++k) o[k] = __float2bfloat16(s[k]);
    *(float4*)&Out[i] = *(float4*)o;
}

// ---------- in-place softmax over rows of 2048 bf16 (fallback tiers) -----
__global__ __launch_bounds__(256) void softmax_rows2048(bf16* __restrict__ S)
{
    __shared__ float red[8];
    const long row = blockIdx.x;
    bf16* p = S + row * 2048;
    const int tid = threadIdx.x;
    float4 raw = *(const float4*)&p[tid * 8];
    bf16 vb[8];
    *(float4*)vb = raw;
    float v[8];
#pragma unroll
    for (int i = 0; i < 8; ++i) v[i] = __bfloat162float(vb[i]);
    float m = v[0];
#pragma unroll
    for (int i = 1; i < 8; ++i) m = fmaxf(m, v[i]);
#pragma unroll
    for (int o = 32; o > 0; o >>= 1) m = fmaxf(m, __shfl_xor(m, o));
    if ((tid & 63) == 0) red[tid >> 6] = m;
    __syncthreads();
    m = fmaxf(fmaxf(red[0], red[1]), fmaxf(red[2], red[3]));
    float s = 0.f;
#pragma unroll
    for (int i = 0; i < 8; ++i) { v[i] = __expf(v[i] - m); s += v[i]; }
#pragma unroll
    for (int o = 32; o > 0; o >>= 1) s += __shfl_xor(s, o);
    if ((tid & 63) == 0) red[4 + (tid >> 6)] = s;
    __syncthreads();
    s = (red[4] + red[5]) + (red[6] + red[7]);
    float inv = 1.f / s;
#pragma unroll
    for (int i = 0; i < 8; ++i) vb[i] = __float2bfloat16(v[i] * inv);
    *(float4*)&p[tid * 8] = *(float4*)vb;
}

extern "C" void kernel_launch(void* const* d_in, const int* in_sizes, int n_in,
                              void* d_out, int out_size, void* d_ws, size_t ws_size,
                              hipStream_t stream)
{
    const int Bb = 4, T = 2048, E = 512, H = 8;
    const int HE = H * E;            // 4096
    const int N3 = 3 * HE;           // 12288
    const int N2 = 2 * HE;           // 8192 (Q|K row width)
    const int M  = Bb * T;           // 8192
    const long NX = (long)M * E;     // 4,194,304

    // ---- size-signature input assignment (order-robust) ----
    const void* xr = nullptr;
    const void* Wr[4] = {nullptr, nullptr, nullptr, nullptr};
    const void* br[3] = {nullptr, nullptr, nullptr};
    const void* bor = nullptr;
    int nw = 0, nb = 0;
    for (int i = 0; i < n_in; ++i) {
        int s = in_sizes[i];
        if      (s == (int)NX)      xr = d_in[i];
        else if (s == E * HE)       { if (nw < 4) Wr[nw++] = d_in[i]; }
        else if (s == HE)           { if (nb < 3) br[nb++] = d_in[i]; }
        else if (s == E)            bor = d_in[i];
    }
    if (!xr || nw < 4 || nb < 3 || !bor) {
        xr = d_in[0]; Wr[0] = d_in[1]; br[0] = d_in[2]; Wr[1] = d_in[3];
        br[1] = d_in[4]; Wr[2] = d_in[5]; br[2] = d_in[6]; Wr[3] = d_in[7];
        bor = d_in[8];
    }

    const float qscale = 0.04419417382415922f;  // 1/sqrt(512)
    const int   QC = 1 << 30;
    dim3 blk(256);

    // ---- workspace layout (bf16 elements) ----
    bf16* pool = (bf16*)d_ws;
    int*  flag = (int*)(void*)pool;
    bf16* xc   = pool + 8;
    bf16* bqc  = xc  + NX;
    bf16* bkc  = bqc + HE;
    bf16* bvc  = bkc + HE;
    bf16* boc  = bvc + HE;
    bf16* WqT  = boc + E;
    const size_t w2m = (size_t)E * HE;
    bf16* WkT  = WqT + w2m;
    bf16* WvT  = WkT + w2m;
    bf16* WoT  = WvT + w2m;
    bf16* Ofin = WoT + w2m;
    bf16* p0   = Ofin + NX;

    const size_t wsE    = ws_size / sizeof(bf16);
    const size_t fixedE = (size_t)(p0 - pool);
    const size_t wQK   = (size_t)T * N2;
    const size_t wQKV  = (size_t)T * N3;
    const size_t wBat  = (size_t)T * HE;
    const size_t wHd   = (size_t)T * E;
    const size_t sAll  = (size_t)H * T * T;
    const size_t sOne  = (size_t)T * T;
    const size_t wBig  = (size_t)M * HE;
    const size_t wL    = 32768;   // fp32 L[H][T] as bf16-el units
    const size_t wL2   = 65536;   // fp32 L[2][H][T] as bf16-el units
    const size_t needB3 = fixedE + wQK + 2 * wBat + 2 * sAll + wBig + wL2; // ~361MB
    const size_t needB2 = fixedE + wQK + wBat + sAll + wBig + wL;          // ~277MB
    const size_t needB  = fixedE + wQKV + 2 * wBat + sAll;
    const size_t needC  = fixedE + 5 * wBat + sOne;
    const size_t needD  = fixedE + 5 * wHd  + sOne;
    if (wsE < needD) return;

    // ---- stage 0: dtype probe + canonicalize ----
    probe_dtype<<<dim3(1), blk, 0, stream>>>((const float*)xr, flag);
    convert_to_bf16<<<dim3((unsigned)((NX / 8 + 255) / 256)), blk, 0, stream>>>(
        xr, xc, NX, flag);
    convert_to_bf16<<<dim3(2), blk, 0, stream>>>(br[0], bqc, HE, flag);
    convert_to_bf16<<<dim3(2), blk, 0, stream>>>(br[1], bkc, HE, flag);
    convert_to_bf16<<<dim3(2), blk, 0, stream>>>(br[2], bvc, HE, flag);
    convert_to_bf16<<<dim3(1), blk, 0, stream>>>(bor, boc, E, flag);
    transpose_any<<<dim3(HE / 64, E / 64, 1), blk, 0, stream>>>(Wr[0], WqT, HE, E, flag);
    transpose_any<<<dim3(HE / 64, E / 64, 1), blk, 0, stream>>>(Wr[1], WkT, HE, E, flag);
    transpose_any<<<dim3(HE / 64, E / 64, 1), blk, 0, stream>>>(Wr[2], WvT, HE, E, flag);
    transpose_any<<<dim3(E / 64, HE / 64, 1), blk, 0, stream>>>(Wr[3], WoT, E, HE, flag);

    if (wsE >= needB3) {
        // ---- Tier B3: batch-paired PV (full-machine 256 blocks) ----
        bf16* QKb  = p0;                    // [t, 8192] Q|K; reused per batch; P later
        bf16* Vtb2 = QKb + wQK;             // 2 x [h,e,t]
        bf16* S2   = Vtb2 + 2 * wBat;       // 2 x exp(scores) [h,t,s]
        bf16* Oatt = S2 + 2 * sAll;         // O_all [M, HE]
        float* Lb2 = (float*)(Oatt + wBig); // fp32 [2][H][T]

        for (int pb = 0; pb < Bb / 2; ++pb) {
            zero_f32<<<dim3(128), blk, 0, stream>>>(Lb2, 2 * H * T);
            for (int i = 0; i < 2; ++i) {
                int b = pb * 2 + i;
                const bf16* xb = xc + (size_t)b * T * E;
                gemm256<4, 2><<<dim3(N3 / 256, T / 256, 1), dim3(512), 0, stream>>>(
                    xb, WqT, QKb, bqc, E, E, N2, 0, 0, 0, E, qscale, HE,
                    Vtb2 + (size_t)i * wBat, N2, nullptr);
                gemm256<1, 1><<<dim3(T / 256, T / 256, H), dim3(512), 0, stream>>>(
                    QKb + HE, QKb, S2 + (size_t)i * sAll, nullptr, N2, N2, T,
                    (long)E, (long)E, (long)T * T, E, 1.f, QC, nullptr, 0,
                    Lb2 + (size_t)i * H * T);
            }
            // PV for both batches of the pair in one 256-block dispatch
            gemm_pv3<<<dim3(256, 1, 1), dim3(512), 0, stream>>>(
                Vtb2, S2, Oatt + (size_t)(pb * 2) * T * HE, Lb2,
                T, T, HE,
                (long)E * T, (long)T * T, (long)E,
                (long)wBat, (long)sAll, (long)T * HE, T);
        }
        // out-proj: A=WoT (rows=ch), B=Oatt (rows=t), split-K=2 via z
        gemm128n<6, 6><<<dim3(M / 256, E / 128, 2), dim3(512), 0, stream>>>(
            WoT, Oatt, QKb, nullptr, HE, HE, E,
            0, 0, (long)M * E, HE / 2, HE / 2);
        reduce_emit<<<dim3((unsigned)((NX / 8 + 255) / 256)), blk, 0, stream>>>(
            QKb, boc, d_out, NX, E, flag);
        return;
    }

    if (wsE >= needB2) {
        // ---- Tier B2 fallback: single-batch PV (gemm128n<5,5>) ----
        bf16* QKb = p0;
        bf16* Vtb = QKb + wQK;
        bf16* S   = Vtb + wBat;
        bf16* Oatt = S + sAll;
        float* Lbuf = (float*)(Oatt + wBig);

        for (int b = 0; b < Bb; ++b) {
            const bf16* xb = xc + (size_t)b * T * E;
            gemm256<4, 2><<<dim3(N3 / 256, T / 256, 1), dim3(512), 0, stream>>>(
                xb, WqT, QKb, bqc, E, E, N2, 0, 0, 0, E, qscale, HE, Vtb, N2,
                nullptr);
            zero_f32<<<dim3(64), blk, 0, stream>>>(Lbuf, H * T);
            gemm256<1, 1><<<dim3(T / 256, T / 256, H), dim3(512), 0, stream>>>(
                QKb + HE, QKb, S, nullptr, N2, N2, T,
                (long)E, (long)E, (long)T * T, E, 1.f, QC, nullptr, 0, Lbuf);
            gemm128n<5, 5><<<dim3(T / 256, E / 128, H), dim3(512), 0, stream>>>(
                Vtb, S, Oatt + (size_t)b * T * HE, Lbuf, T, T, HE,
                (long)E * T, (long)T * T, (long)E, T, 0);
        }
        gemm128n<6, 6><<<dim3(M / 256, E / 128, 2), dim3(512), 0, stream>>>(
            WoT, Oatt, QKb, nullptr, HE, HE, E,
            0, 0, (long)M * E, HE / 2, HE / 2);
        reduce_emit<<<dim3((unsigned)((NX / 8 + 255) / 256)), blk, 0, stream>>>(
            QKb, boc, d_out, NX, E, flag);
        return;
    }

    if (wsE >= needB) {
        // ---- Tier B fallback: softmax path ----
        bf16* QKVb = p0;
        bf16* Vtb  = QKVb + wQKV;
        bf16* Oatt = Vtb + wBat;
        bf16* S    = Oatt + wBat;

        for (int b = 0; b < Bb; ++b) {
            const bf16* xb = xc + (size_t)b * T * E;
            gemm_bt<0><<<dim3(N3 / 128, T / 128, 1), blk, 0, stream>>>(
                xb, WqT, QKVb, bqc, E, E, N3, 0, 0, 0, E, qscale, HE, nullptr, 0);
            transpose_bf16<<<dim3(E / 64, T / 64, H), blk, 0, stream>>>(
                QKVb + 2 * HE, Vtb, N3, T, H, (long)E, (long)E * T, 0, 0);
            gemm_bt<0><<<dim3(T / 128, T / 128, H), blk, 0, stream>>>(
                QKVb, QKVb + HE, S, nullptr, N3, N3, T,
                (long)E, (long)E, (long)T * T, E, 1.f, QC, nullptr, 0);
            softmax_rows2048<<<dim3(H * T, 1, 1), blk, 0, stream>>>(S);
            gemm_bt<0><<<dim3(E / 128, T / 128, H), blk, 0, stream>>>(
                S, Vtb, Oatt, nullptr, T, T, HE,
                (long)T * T, (long)E * T, (long)E, T, 1.f, QC, nullptr, 0);
            gemm_bt_splitk<false><<<dim3(E / 128, T / 128, 8), blk, 0, stream>>>(
                Oatt, WoT, (bf16*)S, HE, HE, E, 0, 0, 0, (long)T * E, 8, HE / 8);
            reduce_splitk<<<dim3((unsigned)(((long)T * E / 8 + 255) / 256)), blk, 0, stream>>>(
                (bf16*)S, boc, Ofin + (size_t)b * T * E, (long)T * E, E, 8);
        }
    } else if (wsE >= needC) {
        // ---- Tier C fallback ----
        bf16* Qb  = p0;
        bf16* Kb  = Qb  + wBat;
        bf16* Vb  = Kb  + wBat;
        bf16* Vtb = Vb  + wBat;
        bf16* Ob  = Vtb + wBat;
        bf16* S   = Ob  + wBat;

        for (int b = 0; b < Bb; ++b) {
            const bf16* xb = xc + (size_t)b * T * E;
            gemm_bt<0><<<dim3(HE / 128, T / 128, 1), blk, 0, stream>>>(
                xb, WqT, Qb, bqc, E, E, HE, 0, 0, 0, E, qscale, QC, nullptr, 0);
            gemm_bt<0><<<dim3(HE / 128, T / 128, 1), blk, 0, stream>>>(
                xb, WkT, Kb, bkc, E, E, HE, 0, 0, 0, E, 1.f, QC, nullptr, 0);
            gemm_bt<0><<<dim3(HE / 128, T / 128, 1), blk, 0, stream>>>(
                xb, WvT, Vb, bvc, E, E, HE, 0, 0, 0, E, 1.f, QC, nullptr, 0);
            transpose_bf16<<<dim3(E / 64, T / 64, H), blk, 0, stream>>>(
                Vb, Vtb, HE, T, H, (long)E, (long)E * T, 0, 0);
            for (int h = 0; h < H; ++h) {
                gemm_bt<0><<<dim3(T / 128, T / 128, 1), blk, 0, stream>>>(
                    Qb + (size_t)h * E, Kb + (size_t)h * E, S, nullptr,
                    HE, HE, T, 0, 0, 0, E, 1.f, QC, nullptr, 0);
                softmax_rows2048<<<dim3(T, 1, 1), blk, 0, stream>>>(S);
                gemm_bt<0><<<dim3(E / 128, T / 128, 1), blk, 0, stream>>>(
                    S, Vtb + (size_t)h * E * T, Ob + (size_t)h * E, nullptr,
                    T, T, HE, 0, 0, 0, T, 1.f, QC, nullptr, 0);
            }
            gemm_bt<0><<<dim3(E / 128, T / 128, 1), blk, 0, stream>>>(
                Ob, WoT, Ofin + (size_t)b * T * E, boc,
                HE, HE, E, 0, 0, 0, HE, 1.f, QC, nullptr, 0);
        }
    } else {
        // ---- Tier D fallback ----
        bf16* Qh  = p0;
        bf16* Kh  = Qh  + wHd;
        bf16* Vh  = Kh  + wHd;
        bf16* Vth = Vh  + wHd;
        bf16* Oh  = Vth + wHd;
        bf16* S   = Oh  + wHd;

        for (int b = 0; b < Bb; ++b) {
            const bf16* xb = xc + (size_t)b * T * E;
            bf16* outb = Ofin + (size_t)b * T * E;
            for (int h = 0; h < H; ++h) {
                const size_t hw = (size_t)h * E * E;
                gemm_bt<0><<<dim3(E / 128, T / 128, 1), blk, 0, stream>>>(
                    xb, WqT + hw, Qh, bqc + (size_t)h * E, E, E, E,
                    0, 0, 0, E, qscale, QC, nullptr, 0);
                gemm_bt<0><<<dim3(E / 128, T / 128, 1), blk, 0, stream>>>(
                    xb, WkT + hw, Kh, bkc + (size_t)h * E, E, E, E,
                    0, 0, 0, E, 1.f, QC, nullptr, 0);
                gemm_bt<0><<<dim3(E / 128, T / 128, 1), blk, 0, stream>>>(
                    xb, WvT + hw, Vh, bvc + (size_t)h * E, E, E, E,
                    0, 0, 0, E, 1.f, QC, nullptr, 0);
                transpose_bf16<<<dim3(E / 64, T / 64, 1), blk, 0, stream>>>(
                    Vh, Vth, E, T, 1, 0, 0, 0, 0);
                gemm_bt<0><<<dim3(T / 128, T / 128, 1), blk, 0, stream>>>(
                    Qh, Kh, S, nullptr, E, E, T, 0, 0, 0, E, 1.f, QC, nullptr, 0);
                softmax_rows2048<<<dim3(T, 1, 1), blk, 0, stream>>>(S);
                gemm_bt<0><<<dim3(E / 128, T / 128, 1), blk, 0, stream>>>(
                    S, Vth, Oh, nullptr, T, T, E, 0, 0, 0, T, 1.f, QC, nullptr, 0);
                if (h == 0)
                    gemm_bt<0><<<dim3(E / 128, T / 128, 1), blk, 0, stream>>>(
                        Oh, WoT, outb, boc, E, HE, E, 0, 0, 0, E, 1.f, QC, nullptr, 0);
                else
                    gemm_bt<2><<<dim3(E / 128, T / 128, 1), blk, 0, stream>>>(
                        Oh, WoT + (size_t)h * E, outb, nullptr,
                        E, HE, E, 0, 0, 0, E, 1.f, QC, nullptr, 0);
            }
        }
    }

    // ---- emit in the probed dtype (fallback tiers only) ----
    emit_out<<<dim3((unsigned)((NX / 8 + 255) / 256)), blk, 0, stream>>>(
        Ofin, d_out, NX, flag);
}

// Round 11
// 858.095 us; speedup vs baseline: 1.1432x; 1.0482x over previous
//
#include <hip/hip_runtime.h>
#include <hip/hip_bf16.h>
#include <stdint.h>

typedef __hip_bfloat16 bf16;
typedef __bf16 bf16x8 __attribute__((ext_vector_type(8)));
typedef float floatx4 __attribute__((ext_vector_type(4)));

#define AS_LDS __attribute__((address_space(3)))
#define AS_GLB __attribute__((address_space(1)))

__device__ __forceinline__ void gload_lds16(const bf16* g, bf16* l) {
    __builtin_amdgcn_global_load_lds((const AS_GLB void*)g, (AS_LDS void*)l, 16, 0, 0);
}

// ---------- dtype probe: *flag = 1 if x is fp32, 0 if bf16 ----------
__global__ void probe_dtype(const float* __restrict__ x, int* __restrict__ flag) {
    __shared__ int cnt;
    if (threadIdx.x == 0) cnt = 0;
    __syncthreads();
    int ok = 0;
    for (int i = threadIdx.x; i < 4096; i += 256) {
        float v = x[i];
        if (v == v && fabsf(v) < 1.0e3f) ok++;
    }
    atomicAdd(&cnt, ok);
    __syncthreads();
    if (threadIdx.x == 0) *flag = (cnt > 2048) ? 1 : 0;
}

__global__ __launch_bounds__(256) void zero_f32(float* __restrict__ p, int n) {
    int i = blockIdx.x * 256 + threadIdx.x;
    if (i < n) p[i] = 0.f;
}

// ---------- convert raw (fp32 or bf16 per flag) -> canonical bf16 ----------
__global__ __launch_bounds__(256) void convert_to_bf16(
    const void* __restrict__ in, bf16* __restrict__ out, long n,
    const int* __restrict__ flag)
{
    long i = ((long)blockIdx.x * 256 + threadIdx.x) * 8;
    if (i >= n) return;
    bf16 o[8];
    if (*flag) {
        const float* p = (const float*)in + i;
        float4 a = *(const float4*)p;
        float4 b = *(const float4*)(p + 4);
        o[0] = __float2bfloat16(a.x); o[1] = __float2bfloat16(a.y);
        o[2] = __float2bfloat16(a.z); o[3] = __float2bfloat16(a.w);
        o[4] = __float2bfloat16(b.x); o[5] = __float2bfloat16(b.y);
        o[6] = __float2bfloat16(b.z); o[7] = __float2bfloat16(b.w);
    } else {
        *(float4*)o = *(const float4*)((const bf16*)in + i);
    }
    *(float4*)&out[i] = *(float4*)o;
}

// ---------- emit canonical bf16 -> d_out in flag dtype (fallback tiers) ----
__global__ __launch_bounds__(256) void emit_out(
    const bf16* __restrict__ in, void* __restrict__ out, long n,
    const int* __restrict__ flag)
{
    long i = ((long)blockIdx.x * 256 + threadIdx.x) * 8;
    if (i >= n) return;
    bf16 v[8];
    *(float4*)v = *(const float4*)&in[i];
    if (*flag) {
        float* o = (float*)out + i;
        float4 a, b;
        a.x = __bfloat162float(v[0]); a.y = __bfloat162float(v[1]);
        a.z = __bfloat162float(v[2]); a.w = __bfloat162float(v[3]);
        b.x = __bfloat162float(v[4]); b.y = __bfloat162float(v[5]);
        b.z = __bfloat162float(v[6]); b.w = __bfloat162float(v[7]);
        *(float4*)o = a;
        *(float4*)(o + 4) = b;
    } else {
        *(float4*)((bf16*)out + i) = *(float4*)v;
    }
}

// ---------- transpose raw-dtype input -> bf16 output ----------
__global__ __launch_bounds__(256) void transpose_any(
    const void* __restrict__ inv, bf16* __restrict__ out,
    int ldin, int ldout, const int* __restrict__ flag)
{
    __shared__ bf16 tile[64][80];
    const int fp32 = *flag;
    const int c0 = blockIdx.x * 64;
    const int r0 = blockIdx.y * 64;
    const int tid = threadIdx.x;
#pragma unroll
    for (int it = 0; it < 2; ++it) {
        int ch = tid + it * 256;
        int r = ch >> 3, c = (ch & 7) * 8;
        long eidx = (long)(r0 + r) * ldin + (c0 + c);
        if (fp32) {
            const float* p = (const float*)inv + eidx;
            float4 a = *(const float4*)p;
            float4 b = *(const float4*)(p + 4);
            bf16 o[8];
            o[0] = __float2bfloat16(a.x); o[1] = __float2bfloat16(a.y);
            o[2] = __float2bfloat16(a.z); o[3] = __float2bfloat16(a.w);
            o[4] = __float2bfloat16(b.x); o[5] = __float2bfloat16(b.y);
            o[6] = __float2bfloat16(b.z); o[7] = __float2bfloat16(b.w);
            *(float4*)&tile[r][c] = *(float4*)o;
        } else {
            *(float4*)&tile[r][c] = *(const float4*)((const bf16*)inv + eidx);
        }
    }
    __syncthreads();
#pragma unroll
    for (int it = 0; it < 2; ++it) {
        int ch = tid + it * 256;
        int oc = ch >> 3, rb = (ch & 7) * 8;
        bf16 tmp[8];
#pragma unroll
        for (int i = 0; i < 8; ++i) tmp[i] = tile[rb + i][oc];
        *(float4*)&out[(long)(c0 + oc) * ldout + r0 + rb] = *(float4*)tmp;
    }
}

// ---------- pure-bf16 transpose (fallback tiers) ----------
__global__ __launch_bounds__(256) void transpose_bf16(
    const bf16* __restrict__ in, bf16* __restrict__ out,
    int ldin, int ldout,
    int nz1, long in_z1, long out_z1, long in_z2, long out_z2)
{
    __shared__ bf16 tile[64][80];
    const int z = blockIdx.z;
    const int z1 = z % nz1, z2 = z / nz1;
    in  += (long)z1 * in_z1 + (long)z2 * in_z2;
    out += (long)z1 * out_z1 + (long)z2 * out_z2;
    const int c0 = blockIdx.x * 64;
    const int r0 = blockIdx.y * 64;
    const int tid = threadIdx.x;
#pragma unroll
    for (int it = 0; it < 2; ++it) {
        int ch = tid + it * 256;
        int r = ch >> 3, c = (ch & 7) * 8;
        *(float4*)&tile[r][c] = *(const float4*)&in[(long)(r0 + r) * ldin + c0 + c];
    }
    __syncthreads();
#pragma unroll
    for (int it = 0; it < 2; ++it) {
        int ch = tid + it * 256;
        int oc = ch >> 3, rb = (ch & 7) * 8;
        bf16 tmp[8];
#pragma unroll
        for (int i = 0; i < 8; ++i) tmp[i] = tile[rb + i][oc];
        *(float4*)&out[(long)(c0 + oc) * ldout + r0 + rb] = *(float4*)tmp;
    }
}

// =====================================================================
// 256x256-tile 8-wave 8-phase GEMM. C = A * Bt^T.
// MODE 1 (QK, swapped A=K,B=Q): S[q][s]=exp(acc), 8B stores; accumulates
//   rowsum L[q] via cross-lane reduce + fp32 atomicAdd.
// MODE 4 (QKV): Q|K part via 4x4 shuffle transpose -> 8B row stores;
//   V part written transposed to Vt.
// SWZ 1: head-per-XCD for grid (8,8,8). SWZ 2: 6-ntile chunks, grid (48,8,1).
// =====================================================================
template <int MODE, int SWZ>
__global__ __launch_bounds__(512, 2) void gemm256(
    const bf16* __restrict__ A, const bf16* __restrict__ Bt,
    bf16* __restrict__ C, const bf16* __restrict__ bias,
    int lda, int ldb, int ldc,
    long az, long bz, long cz, int K, float scale, int qcols,
    bf16* __restrict__ Vt, int vcol0, float* __restrict__ Lsum)
{
    __shared__ bf16 AsL[2][2][256 * 32];
    __shared__ bf16 BsL[2][2][256 * 32];

    const int tid  = threadIdx.x;
    const int lane = tid & 63;
    const int wave = tid >> 6;
    const int wr = wave >> 2;        // 0..1  row half of C tile
    const int wc = wave & 3;         // 0..3  col quarter of C tile
    const int lm = lane & 15;
    const int cl = lane >> 4;        // fragment k-chunk 0..3

    int bxx = blockIdx.x, byy = blockIdx.y, bzz = blockIdx.z;
    if constexpr (SWZ == 1) {        // grid (8,8,8): head z = XCD
        int flat = bxx + (byy << 3) + (bzz << 6);
        int xcd = flat & 7, idx = flat >> 3;
        bzz = xcd; bxx = idx & 7; byy = idx >> 3;
    } else if constexpr (SWZ == 2) { // grid (48,8,1): 6 n-tiles per XCD
        int flat = bxx + byy * 48;
        int xcd = flat & 7, idx = flat >> 3;
        bxx = xcd * 6 + idx % 6; byy = idx / 6; bzz = 0;
    }
    const long zz = bzz;
    A  += zz * az;
    Bt += zz * bz;
    C  += zz * cz;
    float* Lz = (MODE == 1) ? (Lsum + zz * 2048) : nullptr;
    const int m0 = byy * 256;
    const int n0 = bxx * 256;

    // per-lane swizzled ds_read offsets within a [256][32] k-half block
    int offA[8], offB[4];
#pragma unroll
    for (int i = 0; i < 8; ++i) {
        int row = wr * 128 + i * 16 + lm;
        offA[i] = row * 32 + ((cl ^ ((row >> 1) & 3)) << 3);
    }
#pragma unroll
    for (int j = 0; j < 4; ++j) {
        int row = wc * 64 + j * 16 + lm;
        offB[j] = row * 32 + ((cl ^ ((row >> 1) & 3)) << 3);
    }

    const int sr = lane >> 2;        // staging row-in-16
    const int sc = lane & 3;         // staging chunk
    const int NT = K >> 6;           // 64-wide K tiles (NT even)

    floatx4 acc[8][4];
#pragma unroll
    for (int i = 0; i < 8; ++i)
#pragma unroll
        for (int j = 0; j < 4; ++j)
            acc[i][j] = (floatx4){0.f, 0.f, 0.f, 0.f};

    // stage one (operand, khalf) unit of tile t: 2 x global_load_lds
    auto stageU = [&](int which, int t, int kh) {
        if (t >= NT) return;
        const bf16* G = which ? Bt : A;
        const int ldg  = which ? ldb : lda;
        const int g0   = which ? n0 : m0;
        bf16* lb = which ? &BsL[t & 1][kh][0] : &AsL[t & 1][kh][0];
        const int kcol = t * 64 + kh * 32;
#pragma unroll
        for (int ii = 0; ii < 2; ++ii) {
            int row = ii * 128 + wave * 16 + sr;
            int cg  = sc ^ ((row >> 1) & 3);   // pre-swizzled global chunk
            gload_lds16(G + (long)(g0 + row) * ldg + kcol + cg * 8,
                        lb + row * 32 + sc * 8);
        }
    };

    bf16x8 af[8], bfv[2];
    auto dsA = [&](int b, int kh) {
        const bf16* p = &AsL[b][kh][0];
#pragma unroll
        for (int i = 0; i < 8; ++i) af[i] = *(const bf16x8*)(p + offA[i]);
    };
    auto dsB = [&](int b, int kh, int nh) {
        const bf16* p = &BsL[b][kh][0];
        bfv[0] = *(const bf16x8*)(p + offB[nh * 2]);
        bfv[1] = *(const bf16x8*)(p + offB[nh * 2 + 1]);
    };
    auto mfmaQ = [&](int nh) {
        __builtin_amdgcn_s_setprio(1);
#pragma unroll
        for (int i = 0; i < 8; ++i) {
            acc[i][nh * 2] = __builtin_amdgcn_mfma_f32_16x16x32_bf16(
                af[i], bfv[0], acc[i][nh * 2], 0, 0, 0);
            acc[i][nh * 2 + 1] = __builtin_amdgcn_mfma_f32_16x16x32_bf16(
                af[i], bfv[1], acc[i][nh * 2 + 1], 0, 0, 0);
        }
        __builtin_amdgcn_s_setprio(0);
    };

#define BAR    __builtin_amdgcn_s_barrier()
#define SBZ    __builtin_amdgcn_sched_barrier(0)
#define LGKM0  do { asm volatile("s_waitcnt lgkmcnt(0)" ::: "memory"); SBZ; } while (0)
#define VM(n)  do { asm volatile("s_waitcnt vmcnt(" #n ")" ::: "memory"); SBZ; } while (0)

    // ---- prologue: tile0 (all), tile1 k0 ----
    stageU(0, 0, 0); stageU(1, 0, 0); stageU(0, 0, 1); stageU(1, 0, 1);
    stageU(0, 1, 0); stageU(1, 1, 0);
    VM(4);
    BAR;

    for (int t0 = 0; t0 < NT; t0 += 2) {
        const bool last = (t0 + 2 >= NT);
        dsA(0, 0); dsB(0, 0, 0); stageU(0, t0 + 1, 1);
        BAR; LGKM0; mfmaQ(0); BAR;
        dsB(0, 0, 1); stageU(1, t0 + 1, 1);
        BAR; LGKM0; mfmaQ(1); BAR;
        dsA(0, 1); dsB(0, 1, 0); stageU(0, t0 + 2, 0);
        BAR; LGKM0; mfmaQ(0); BAR;
        dsB(0, 1, 1); stageU(1, t0 + 2, 0);
        BAR; LGKM0; mfmaQ(1);
        if (last) { VM(0); } else { VM(4); }
        BAR;
        dsA(1, 0); dsB(1, 0, 0); stageU(0, t0 + 2, 1);
        BAR; LGKM0; mfmaQ(0); BAR;
        dsB(1, 0, 1); stageU(1, t0 + 2, 1);
        BAR; LGKM0; mfmaQ(1); BAR;
        dsA(1, 1); dsB(1, 1, 0); stageU(0, t0 + 3, 0);
        BAR; LGKM0; mfmaQ(0); BAR;
        dsB(1, 1, 1); stageU(1, t0 + 3, 0);
        BAR; LGKM0; mfmaQ(1);
        if (!last) { VM(4); }
        BAR;
    }
#undef BAR
#undef SBZ
#undef LGKM0
#undef VM

    // ---- epilogue ----
    const int cr = (lane >> 4) * 4;
    if constexpr (MODE == 1) {
        // swapped operands: acc(row=s, col=q). Store S[q][s] = exp(acc):
        // lane holds 4 consecutive s -> 8B packet. Also rowsum -> atomic.
#pragma unroll
        for (int j = 0; j < 4; ++j) {
            long q = n0 + wc * 64 + j * 16 + lm;
            bf16* Cr = C + q * ldc + m0 + wr * 128;
            float rs = 0.f;
#pragma unroll
            for (int i = 0; i < 8; ++i) {
                bf16 pk[4];
#pragma unroll
                for (int r = 0; r < 4; ++r) {
                    float e = __expf(acc[i][j][r]);
                    rs += e;
                    pk[r] = __float2bfloat16(e);
                }
                *(uint64_t*)&Cr[i * 16 + cr] = *(const uint64_t*)pk;
            }
            rs += __shfl_xor(rs, 16);
            rs += __shfl_xor(rs, 32);
            if (cl == 0) atomicAdd(&Lz[q], rs);
        }
    } else {   // MODE 4
        if (n0 >= vcol0) {
            // V block: write transposed, packed 4 consecutive t per 8B store
#pragma unroll
            for (int j = 0; j < 4; ++j) {
                int col = n0 + wc * 64 + j * 16 + lm;
                float bv = __bfloat162float(bias[col]);
                int eg = col - vcol0;
                bf16* vt = Vt + ((long)(eg >> 9) * 512 + (eg & 511)) * 2048;
#pragma unroll
                for (int i = 0; i < 8; ++i) {
                    int t0v = m0 + wr * 128 + i * 16 + cr;
                    bf16 pk[4];
#pragma unroll
                    for (int r = 0; r < 4; ++r)
                        pk[r] = __float2bfloat16(acc[i][j][r] + bv);
                    *(uint64_t*)&vt[t0v] = *(const uint64_t*)pk;
                }
            }
        } else {
            // Q|K: bias+scale, then 4x4 shuffle transpose -> 8B row stores
            const int l4 = lane & 3;
            float bvj[4], scj[4];
#pragma unroll
            for (int j = 0; j < 4; ++j) {
                int col = n0 + wc * 64 + j * 16 + lm;
                bvj[j] = __bfloat162float(bias[col]);
                scj[j] = (col < qcols) ? scale : 1.0f;
            }
#pragma unroll
            for (int i = 0; i < 8; ++i) {
                int row = m0 + wr * 128 + i * 16 + cr + l4;
                bf16* Cr = C + (long)row * ldc + n0 + wc * 64 + (lm & ~3);
#pragma unroll
                for (int j = 0; j < 4; ++j) {
                    float x0 = (acc[i][j][0] + bvj[j]) * scj[j];
                    float x1 = (acc[i][j][1] + bvj[j]) * scj[j];
                    float x2 = (acc[i][j][2] + bvj[j]) * scj[j];
                    float x3 = (acc[i][j][3] + bvj[j]) * scj[j];
                    float u = __shfl_xor((l4 & 1) ? x0 : x1, 1);
                    float v = __shfl_xor((l4 & 1) ? x2 : x3, 1);
                    if (l4 & 1) { x0 = u; x2 = v; } else { x1 = u; x3 = v; }
                    u = __shfl_xor((l4 & 2) ? x0 : x2, 2);
                    v = __shfl_xor((l4 & 2) ? x1 : x3, 2);
                    if (l4 & 2) { x0 = u; x1 = v; } else { x2 = u; x3 = v; }
                    bf16 pk[4];
                    pk[0] = __float2bfloat16(x0); pk[1] = __float2bfloat16(x1);
                    pk[2] = __float2bfloat16(x2); pk[3] = __float2bfloat16(x3);
                    *(uint64_t*)&Cr[j * 16] = *(const uint64_t*)pk;
                }
            }
        }
    }
}

// =====================================================================
// PV kernel (batch-paired): 256x256-tile 8-wave 8-phase, grid (256,1,1).
// Covers TWO batches in one dispatch -> full machine (fixes the 128-block
// MLP limit: 1.4 TB/s ceiling observed in round 8).
// flat = blockIdx.x: head = flat&7 (= XCD under round-robin), idx = flat>>3:
// q-tile = idx&7, ch-tile = (idx>>3)&1, batch-half i = idx>>4.
// A = Vt2 (+i*abz + h*az), Bt = S2 (+i*sbz + h*bz), C = O (+i*cbz + h*cz).
// O[q][ch] = acc / L[q]; 8B packets of 4 consecutive ch.
// =====================================================================
__global__ __launch_bounds__(512, 2) void gemm_pv3(
    const bf16* __restrict__ A, const bf16* __restrict__ Bt,
    bf16* __restrict__ C, const float* __restrict__ L,
    int lda, int ldb, int ldc,
    long az, long bz, long cz,
    long abz, long sbz, long cbz, int K)
{
    __shared__ bf16 AsL[2][2][256 * 32];
    __shared__ bf16 BsL[2][2][256 * 32];

    const int tid  = threadIdx.x;
    const int lane = tid & 63;
    const int wave = tid >> 6;
    const int wr = wave >> 2;
    const int wc = wave & 3;
    const int lm = lane & 15;
    const int cl = lane >> 4;

    const int flat = blockIdx.x;     // 0..255
    const int h   = flat & 7;        // head = XCD
    const int idx = flat >> 3;
    const int qb  = idx & 7;         // q-tile 0..7
    const int chb = (idx >> 3) & 1;  // ch-tile 0..1
    const int ib  = idx >> 4;        // batch-half 0..1
    A  += (long)ib * abz + (long)h * az;
    Bt += (long)ib * sbz + (long)h * bz;
    C  += (long)ib * cbz + (long)h * cz;
    const float* Lz = L + (long)ib * 16384 + (long)h * 2048;
    const int m0 = chb * 256;        // ch base
    const int n0 = qb * 256;         // q base

    int offA[8], offB[4];
#pragma unroll
    for (int i = 0; i < 8; ++i) {
        int row = wr * 128 + i * 16 + lm;
        offA[i] = row * 32 + ((cl ^ ((row >> 1) & 3)) << 3);
    }
#pragma unroll
    for (int j = 0; j < 4; ++j) {
        int row = wc * 64 + j * 16 + lm;
        offB[j] = row * 32 + ((cl ^ ((row >> 1) & 3)) << 3);
    }

    const int sr = lane >> 2;
    const int sc = lane & 3;
    const int NT = K >> 6;           // 32, even

    floatx4 acc[8][4];
#pragma unroll
    for (int i = 0; i < 8; ++i)
#pragma unroll
        for (int j = 0; j < 4; ++j)
            acc[i][j] = (floatx4){0.f, 0.f, 0.f, 0.f};

    auto stageU = [&](int which, int t, int kh) {
        if (t >= NT) return;
        const bf16* G = which ? Bt : A;
        const int ldg  = which ? ldb : lda;
        const int g0   = which ? n0 : m0;
        bf16* lb = which ? &BsL[t & 1][kh][0] : &AsL[t & 1][kh][0];
        const int kcol = t * 64 + kh * 32;
#pragma unroll
        for (int ii = 0; ii < 2; ++ii) {
            int row = ii * 128 + wave * 16 + sr;
            int cg  = sc ^ ((row >> 1) & 3);
            gload_lds16(G + (long)(g0 + row) * ldg + kcol + cg * 8,
                        lb + row * 32 + sc * 8);
        }
    };

    bf16x8 af[8], bfv[2];
    auto dsA = [&](int b, int kh) {
        const bf16* p = &AsL[b][kh][0];
#pragma unroll
        for (int i = 0; i < 8; ++i) af[i] = *(const bf16x8*)(p + offA[i]);
    };
    auto dsB = [&](int b, int kh, int nh) {
        const bf16* p = &BsL[b][kh][0];
        bfv[0] = *(const bf16x8*)(p + offB[nh * 2]);
        bfv[1] = *(const bf16x8*)(p + offB[nh * 2 + 1]);
    };
    auto mfmaQ = [&](int nh) {
        __builtin_amdgcn_s_setprio(1);
#pragma unroll
        for (int i = 0; i < 8; ++i) {
            acc[i][nh * 2] = __builtin_amdgcn_mfma_f32_16x16x32_bf16(
                af[i], bfv[0], acc[i][nh * 2], 0, 0, 0);
            acc[i][nh * 2 + 1] = __builtin_amdgcn_mfma_f32_16x16x32_bf16(
                af[i], bfv[1], acc[i][nh * 2 + 1], 0, 0, 0);
        }
        __builtin_amdgcn_s_setprio(0);
    };

#define BAR    __builtin_amdgcn_s_barrier()
#define SBZ    __builtin_amdgcn_sched_barrier(0)
#define LGKM0  do { asm volatile("s_waitcnt lgkmcnt(0)" ::: "memory"); SBZ; } while (0)
#define VM(n)  do { asm volatile("s_waitcnt vmcnt(" #n ")" ::: "memory"); SBZ; } while (0)

    stageU(0, 0, 0); stageU(1, 0, 0); stageU(0, 0, 1); stageU(1, 0, 1);
    stageU(0, 1, 0); stageU(1, 1, 0);
    VM(4);
    BAR;

    for (int t0 = 0; t0 < NT; t0 += 2) {
        const bool last = (t0 + 2 >= NT);
        dsA(0, 0); dsB(0, 0, 0); stageU(0, t0 + 1, 1);
        BAR; LGKM0; mfmaQ(0); BAR;
        dsB(0, 0, 1); stageU(1, t0 + 1, 1);
        BAR; LGKM0; mfmaQ(1); BAR;
        dsA(0, 1); dsB(0, 1, 0); stageU(0, t0 + 2, 0);
        BAR; LGKM0; mfmaQ(0); BAR;
        dsB(0, 1, 1); stageU(1, t0 + 2, 0);
        BAR; LGKM0; mfmaQ(1);
        if (last) { VM(0); } else { VM(4); }
        BAR;
        dsA(1, 0); dsB(1, 0, 0); stageU(0, t0 + 2, 1);
        BAR; LGKM0; mfmaQ(0); BAR;
        dsB(1, 0, 1); stageU(1, t0 + 2, 1);
        BAR; LGKM0; mfmaQ(1); BAR;
        dsA(1, 1); dsB(1, 1, 0); stageU(0, t0 + 3, 0);
        BAR; LGKM0; mfmaQ(0); BAR;
        dsB(1, 1, 1); stageU(1, t0 + 3, 0);
        BAR; LGKM0; mfmaQ(1);
        if (!last) { VM(4); }
        BAR;
    }
#undef BAR
#undef SBZ
#undef LGKM0
#undef VM

    // epilogue: acc rows = ch, cols = q. O[q][ch] = acc / L[q].
    const int cr = (lane >> 4) * 4;
#pragma unroll
    for (int j = 0; j < 4; ++j) {
        long q = n0 + wc * 64 + j * 16 + lm;
        float inv = 1.0f / Lz[q];
        bf16* Cr = C + q * ldc + m0 + wr * 128;
#pragma unroll
        for (int i = 0; i < 8; ++i) {
            bf16 pk[4];
#pragma unroll
            for (int r = 0; r < 4; ++r)
                pk[r] = __float2bfloat16(acc[i][j][r] * inv);
            *(uint64_t*)&Cr[i * 16 + cr] = *(const uint64_t*)pk;
        }
    }
}

// =====================================================================
// 128(M)x256(N)-tile 8-wave 8-phase GEMM. 96KB LDS.
// MODE 5 (PV fallback): O[q][ch] = acc / L[q].
// MODE 6 (out-proj split-K): P[t][ch] = acc partial, z = k-split.
// SWZ 5: head-per-XCD, grid (8,4,8). SWZ 6: chunked, grid (32,4,2).
// SWZ 7: chunked, grid (16,4,2) (per-pair out-proj).
// =====================================================================
template <int MODE, int SWZ>
__global__ __launch_bounds__(512, 2) void gemm128n(
    const bf16* __restrict__ A, const bf16* __restrict__ Bt,
    bf16* __restrict__ C, const float* __restrict__ L,
    int lda, int ldb, int ldc,
    long az, long bz, long cz, int K, int kper)
{
    __shared__ bf16 AsL[2][2][128 * 32];
    __shared__ bf16 BsL[2][2][256 * 32];

    const int tid  = threadIdx.x;
    const int lane = tid & 63;
    const int wave = tid >> 6;
    const int wr = wave >> 2;        // 0..1  m-half (64 rows)
    const int wc = wave & 3;         // 0..3  n-quarter (64 cols)
    const int lm = lane & 15;
    const int cl = lane >> 4;

    int bxx = blockIdx.x, byy = blockIdx.y, bzz = blockIdx.z;
    if constexpr (SWZ == 5) {        // grid (8,4,8): head z = XCD
        int flat = bxx + (byy << 3) + (bzz << 5);
        int xcd = flat & 7, idx = flat >> 3;
        bzz = xcd; bxx = idx & 7; byy = idx >> 3;
    } else if constexpr (SWZ == 6) { // grid (32,4,2): chunked remap
        int flat = bxx + (byy << 5) + (bzz << 7);
        int nf = (flat & 7) * 32 + (flat >> 3);
        bzz = nf >> 7; int rr = nf & 127; byy = rr >> 5; bxx = rr & 31;
    } else if constexpr (SWZ == 7) { // grid (16,4,2): chunked remap
        int flat = bxx + (byy << 4) + (bzz << 6);
        int nf = (flat & 7) * 16 + (flat >> 3);
        bzz = nf >> 6; int rr = nf & 63; byy = rr >> 4; bxx = rr & 15;
    }
    const long zz = bzz;
    A  += zz * az;
    Bt += zz * bz;
    C  += zz * cz;
    const float* Lz = (MODE == 5) ? (L + zz * 2048) : nullptr;
    const int kbase = (int)(zz * (long)kper);
    const int m0 = byy * 128;
    const int n0 = bxx * 256;

    int offA[4], offB[4];
#pragma unroll
    for (int i = 0; i < 4; ++i) {
        int row = wr * 64 + i * 16 + lm;
        offA[i] = row * 32 + ((cl ^ ((row >> 1) & 3)) << 3);
    }
#pragma unroll
    for (int j = 0; j < 4; ++j) {
        int row = wc * 64 + j * 16 + lm;
        offB[j] = row * 32 + ((cl ^ ((row >> 1) & 3)) << 3);
    }

    const int sr = lane >> 2;
    const int sc = lane & 3;
    const int NT = K >> 6;           // even

    floatx4 acc[4][4];
#pragma unroll
    for (int i = 0; i < 4; ++i)
#pragma unroll
        for (int j = 0; j < 4; ++j)
            acc[i][j] = (floatx4){0.f, 0.f, 0.f, 0.f};

    auto stageA = [&](int t, int kh) {   // 1 load/thread
        if (t >= NT) return;
        bf16* lb = &AsL[t & 1][kh][0];
        const int kcol = kbase + t * 64 + kh * 32;
        int row = wave * 16 + sr;
        int cg  = sc ^ ((row >> 1) & 3);
        gload_lds16(A + (long)(m0 + row) * lda + kcol + cg * 8,
                    lb + row * 32 + sc * 8);
    };
    auto stageB = [&](int t, int kh) {   // 2 loads/thread
        if (t >= NT) return;
        bf16* lb = &BsL[t & 1][kh][0];
        const int kcol = kbase + t * 64 + kh * 32;
#pragma unroll
        for (int ii = 0; ii < 2; ++ii) {
            int row = ii * 128 + wave * 16 + sr;
            int cg  = sc ^ ((row >> 1) & 3);
            gload_lds16(Bt + (long)(n0 + row) * ldb + kcol + cg * 8,
                        lb + row * 32 + sc * 8);
        }
    };

    bf16x8 af[4], bfv[2];
    auto dsA = [&](int b, int kh) {
        const bf16* p = &AsL[b][kh][0];
#pragma unroll
        for (int i = 0; i < 4; ++i) af[i] = *(const bf16x8*)(p + offA[i]);
    };
    auto dsB = [&](int b, int kh, int nh) {
        const bf16* p = &BsL[b][kh][0];
        bfv[0] = *(const bf16x8*)(p + offB[nh * 2]);
        bfv[1] = *(const bf16x8*)(p + offB[nh * 2 + 1]);
    };
    auto mfmaQ = [&](int nh) {
        __builtin_amdgcn_s_setprio(1);
#pragma unroll
        for (int i = 0; i < 4; ++i) {
            acc[i][nh * 2] = __builtin_amdgcn_mfma_f32_16x16x32_bf16(
                af[i], bfv[0], acc[i][nh * 2], 0, 0, 0);
            acc[i][nh * 2 + 1] = __builtin_amdgcn_mfma_f32_16x16x32_bf16(
                af[i], bfv[1], acc[i][nh * 2 + 1], 0, 0, 0);
        }
        __builtin_amdgcn_s_setprio(0);
    };

#define BAR    __builtin_amdgcn_s_barrier()
#define SBZ    __builtin_amdgcn_sched_barrier(0)
#define LGKM0  do { asm volatile("s_waitcnt lgkmcnt(0)" ::: "memory"); SBZ; } while (0)
#define VM(n)  do { asm volatile("s_waitcnt vmcnt(" #n ")" ::: "memory"); SBZ; } while (0)

    stageA(0, 0); stageB(0, 0); stageA(0, 1); stageB(0, 1);
    stageA(1, 0); stageB(1, 0);
    VM(3);
    BAR;

    for (int t0 = 0; t0 < NT; t0 += 2) {
        const bool last = (t0 + 2 >= NT);
        dsA(0, 0); dsB(0, 0, 0); stageA(t0 + 1, 1);
        BAR; LGKM0; mfmaQ(0); BAR;
        dsB(0, 0, 1); stageB(t0 + 1, 1);
        BAR; LGKM0; mfmaQ(1); BAR;
        dsA(0, 1); dsB(0, 1, 0); stageA(t0 + 2, 0);
        BAR; LGKM0; mfmaQ(0); BAR;
        dsB(0, 1, 1); stageB(t0 + 2, 0);
        BAR; LGKM0; mfmaQ(1);
        if (last) { VM(0); } else { VM(3); }
        BAR;
        dsA(1, 0); dsB(1, 0, 0); stageA(t0 + 2, 1);
        BAR; LGKM0; mfmaQ(0); BAR;
        dsB(1, 0, 1); stageB(t0 + 2, 1);
        BAR; LGKM0; mfmaQ(1); BAR;
        dsA(1, 1); dsB(1, 1, 0); stageA(t0 + 3, 0);
        BAR; LGKM0; mfmaQ(0); BAR;
        dsB(1, 1, 1); stageB(t0 + 3, 0);
        BAR; LGKM0; mfmaQ(1);
        if (!last) { VM(3); }
        BAR;
    }
#undef BAR
#undef SBZ
#undef LGKM0
#undef VM

    const int cr = cl * 4;
#pragma unroll
    for (int j = 0; j < 4; ++j) {
        int col = n0 + wc * 64 + j * 16 + lm;
        bf16* Cr = C + (long)col * ldc + m0 + wr * 64;
        float inv = 1.0f;
        if constexpr (MODE == 5) inv = 1.0f / Lz[col];
#pragma unroll
        for (int i = 0; i < 4; ++i) {
            bf16 pk[4];
#pragma unroll
            for (int r = 0; r < 4; ++r)
                pk[r] = __float2bfloat16(acc[i][j][r] * inv);
            *(uint64_t*)&Cr[i * 16 + cr] = *(const uint64_t*)pk;
        }
    }
}

// ---------- GEMM (bf16 in/out, fp32 acc), fallback tiers -----------------
template <int MODE, bool SWAP = false>
__global__ __launch_bounds__(256) void gemm_bt(
    const bf16* __restrict__ A, const bf16* __restrict__ Bt,
    bf16* __restrict__ C, const bf16* __restrict__ bias,
    int lda, int ldb, int ldc,
    long az, long bz, long cz, int K, float scale, int qcols,
    bf16* __restrict__ Vt, int vcol0)
{
    __shared__ bf16 As[128 * 64];
    __shared__ bf16 Bs[128 * 64];

    const int tid  = threadIdx.x;
    const int lane = tid & 63;
    const int wave = tid >> 6;
    const int wx = wave & 1;
    const int wy = wave >> 1;

    const long zz = blockIdx.z;
    A  += zz * az;
    Bt += zz * bz;
    C  += zz * cz;
    const int bm = SWAP ? blockIdx.x : blockIdx.y;
    const int bn = SWAP ? blockIdx.y : blockIdx.x;
    const int m0 = bm * 128;
    const int n0 = bn * 128;

    const int lm = lane & 15;
    const int kq = (lane >> 4) * 8;

    floatx4 acc[4][4];
#pragma unroll
    for (int i = 0; i < 4; ++i)
#pragma unroll
        for (int j = 0; j < 4; ++j)
            acc[i][j] = (floatx4){0.f, 0.f, 0.f, 0.f};

    for (int kt = 0; kt < K; kt += 64) {
        __syncthreads();
#pragma unroll
        for (int it = 0; it < 4; ++it) {
            int ch = tid + it * 256;
            int r = ch >> 3;
            int c = (ch & 7) * 8;
            gload_lds16(A  + (long)(m0 + r) * lda + (kt + c), &As[ch * 8]);
            gload_lds16(Bt + (long)(n0 + r) * ldb + (kt + c), &Bs[ch * 8]);
        }
        __syncthreads();
#pragma unroll
        for (int kk = 0; kk < 64; kk += 32) {
            bf16x8 af[4], bfv[4];
#pragma unroll
            for (int i = 0; i < 4; ++i)
                af[i] = *(const bf16x8*)&As[(wy * 64 + i * 16 + lm) * 64 + kk + kq];
#pragma unroll
            for (int j = 0; j < 4; ++j)
                bfv[j] = *(const bf16x8*)&Bs[(wx * 64 + j * 16 + lm) * 64 + kk + kq];
#pragma unroll
            for (int i = 0; i < 4; ++i)
#pragma unroll
                for (int j = 0; j < 4; ++j)
                    acc[i][j] = __builtin_amdgcn_mfma_f32_16x16x32_bf16(
                        af[i], bfv[j], acc[i][j], 0, 0, 0);
        }
    }

    const int cr = (lane >> 4) * 4;
    if constexpr (MODE == 1) {
#pragma unroll
        for (int j = 0; j < 4; ++j) {
            int col = n0 + wx * 64 + j * 16 + lm;
#pragma unroll
            for (int i = 0; i < 4; ++i)
#pragma unroll
                for (int r = 0; r < 4; ++r) {
                    int row = m0 + wy * 64 + i * 16 + cr + r;
                    C[(long)row * ldc + col] = __float2bfloat16(__expf(acc[i][j][r]));
                }
        }
    } else {
#pragma unroll
        for (int j = 0; j < 4; ++j) {
            int col = n0 + wx * 64 + j * 16 + lm;
            float bv = (MODE == 0 && bias) ? __bfloat162float(bias[col]) : 0.f;
            float sc = (col < qcols) ? scale : 1.0f;
#pragma unroll
            for (int i = 0; i < 4; ++i) {
#pragma unroll
                for (int r = 0; r < 4; ++r) {
                    int row = m0 + wy * 64 + i * 16 + cr + r;
                    long idx = (long)row * ldc + col;
                    float v;
                    if (MODE == 2) v = acc[i][j][r] + __bfloat162float(C[idx]);
                    else           v = (acc[i][j][r] + bv) * sc;
                    C[idx] = __float2bfloat16(v);
                }
            }
        }
    }
}

// ---------- split-K GEMM, bf16 partials (fallback tiers) ------------------
template <bool SWAP = false>
__global__ __launch_bounds__(256) void gemm_bt_splitk(
    const bf16* __restrict__ A, const bf16* __restrict__ Bt,
    bf16* __restrict__ P, int lda, int ldb, int ldp,
    long az, long bz, long pz, long skStride, int nsk, int Kc)
{
    __shared__ bf16 As[128 * 64];
    __shared__ bf16 Bs[128 * 64];

    const int tid  = threadIdx.x;
    const int lane = tid & 63;
    const int wave = tid >> 6;
    const int wx = wave & 1;
    const int wy = wave >> 1;
    const int zz = blockIdx.z;
    const int ks = zz % nsk;
    const int zh = zz / nsk;
    A  += (long)zh * az;
    Bt += (long)zh * bz;
    bf16* Pz = P + (long)zh * pz + (long)ks * skStride;
    const int bm = SWAP ? blockIdx.x : blockIdx.y;
    const int bn = SWAP ? blockIdx.y : blockIdx.x;
    const int m0 = bm * 128;
    const int n0 = bn * 128;
    const int k0 = ks * Kc;

    const int lm = lane & 15;
    const int kq = (lane >> 4) * 8;

    floatx4 acc[4][4];
#pragma unroll
    for (int i = 0; i < 4; ++i)
#pragma unroll
        for (int j = 0; j < 4; ++j)
            acc[i][j] = (floatx4){0.f, 0.f, 0.f, 0.f};

    for (int kt = k0; kt < k0 + Kc; kt += 64) {
        __syncthreads();
#pragma unroll
        for (int it = 0; it < 4; ++it) {
            int ch = tid + it * 256;
            int r = ch >> 3;
            int c = (ch & 7) * 8;
            gload_lds16(A  + (long)(m0 + r) * lda + (kt + c), &As[ch * 8]);
            gload_lds16(Bt + (long)(n0 + r) * ldb + (kt + c), &Bs[ch * 8]);
        }
        __syncthreads();
#pragma unroll
        for (int kk = 0; kk < 64; kk += 32) {
            bf16x8 af[4], bfv[4];
#pragma unroll
            for (int i = 0; i < 4; ++i)
                af[i] = *(const bf16x8*)&As[(wy * 64 + i * 16 + lm) * 64 + kk + kq];
#pragma unroll
            for (int j = 0; j < 4; ++j)
                bfv[j] = *(const bf16x8*)&Bs[(wx * 64 + j * 16 + lm) * 64 + kk + kq];
#pragma unroll
            for (int i = 0; i < 4; ++i)
#pragma unroll
                for (int j = 0; j < 4; ++j)
                    acc[i][j] = __builtin_amdgcn_mfma_f32_16x16x32_bf16(
                        af[i], bfv[j], acc[i][j], 0, 0, 0);
        }
    }

    const int cr = (lane >> 4) * 4;
#pragma unroll
    for (int j = 0; j < 4; ++j) {
        int col = n0 + wx * 64 + j * 16 + lm;
#pragma unroll
        for (int i = 0; i < 4; ++i)
#pragma unroll
            for (int r = 0; r < 4; ++r) {
                int row = m0 + wy * 64 + i * 16 + cr + r;
                Pz[(long)row * ldp + col] = __float2bfloat16(acc[i][j][r]);
            }
    }
}

// ---------- reduce 2 bf16 split-K partials + bias -> d_out in flag dtype ----
__global__ __launch_bounds__(256) void reduce_emit(
    const bf16* __restrict__ P, const bf16* __restrict__ bias,
    void* __restrict__ out, long MN, int N,
    const int* __restrict__ flag, long oofs)
{
    long i = ((long)blockIdx.x * 256 + threadIdx.x) * 8;
    if (i >= MN) return;
    bf16 bb[8], a[8], b[8];
    *(float4*)bb = *(const float4*)&bias[i & (N - 1)];
    *(float4*)a  = *(const float4*)&P[i];
    *(float4*)b  = *(const float4*)&P[MN + i];
    float s[8];
#pragma unroll
    for (int k = 0; k < 8; ++k)
        s[k] = __bfloat162float(bb[k]) + __bfloat162float(a[k]) + __bfloat162float(b[k]);
    if (*flag) {
        float* o = (float*)out + oofs + i;
        float4 lo = {s[0], s[1], s[2], s[3]};
        float4 hi = {s[4], s[5], s[6], s[7]};
        *(float4*)o = lo;
        *(float4*)(o + 4) = hi;
    } else {
        bf16 o[8];
#pragma unroll
        for (int k = 0; k < 8; ++k) o[k] = __float2bfloat16(s[k]);
        *(float4*)&((bf16*)out)[oofs + i] = *(float4*)o;
    }
}

// ---------- reduce bf16 split-K partials + bias -> bf16 (fallback) ----------
__global__ __launch_bounds__(256) void reduce_splitk(
    const bf16* __restrict__ P, const bf16* __restrict__ bias,
    bf16* __restrict__ Out, long MN, int N, int SK)
{
    long i = ((long)blockIdx.x * 256 + threadIdx.x) * 8;
    if (i >= MN) return;
    float s[8];
    if (bias) {
        bf16 bb[8];
        *(float4*)bb = *(const float4*)&bias[i & (N - 1)];
#pragma unroll
        for (int k = 0; k < 8; ++k) s[k] = __bfloat162float(bb[k]);
    } else {
#pragma unroll
        for (int k = 0; k < 8; ++k) s[k] = 0.f;
    }
    for (int z = 0; z < SK; ++z) {
        bf16 a[8];
        *(float4*)a = *(const float4*)&P[(long)z * MN + i];
#pragma unroll
        for (int k = 0; k < 8; ++k) s[k] += __bfloat162float(a[k]);
    }
    bf16 o[8];
#pragma unroll
    for (int k = 0; k < 8; ++k) o[k] = __float2bfloat16(s[k]);
    *(float4*)&Out[i] = *(float4*)o;
}

// ---------- in-place softmax over rows of 2048 bf16 (fallback tiers) -----
__global__ __launch_bounds__(256) void softmax_rows2048(bf16* __restrict__ S)
{
    __shared__ float red[8];
    const long row = blockIdx.x;
    bf16* p = S + row * 2048;
    const int tid = threadIdx.x;
    float4 raw = *(const float4*)&p[tid * 8];
    bf16 vb[8];
    *(float4*)vb = raw;
    float v[8];
#pragma unroll
    for (int i = 0; i < 8; ++i) v[i] = __bfloat162float(vb[i]);
    float m = v[0];
#pragma unroll
    for (int i = 1; i < 8; ++i) m = fmaxf(m, v[i]);
#pragma unroll
    for (int o = 32; o > 0; o >>= 1) m = fmaxf(m, __shfl_xor(m, o));
    if ((tid & 63) == 0) red[tid >> 6] = m;
    __syncthreads();
    m = fmaxf(fmaxf(red[0], red[1]), fmaxf(red[2], red[3]));
    float s = 0.f;
#pragma unroll
    for (int i = 0; i < 8; ++i) { v[i] = __expf(v[i] - m); s += v[i]; }
#pragma unroll
    for (int o = 32; o > 0; o >>= 1) s += __shfl_xor(s, o);
    if ((tid & 63) == 0) red[4 + (tid >> 6)] = s;
    __syncthreads();
    s = (red[4] + red[5]) + (red[6] + red[7]);
    float inv = 1.f / s;
#pragma unroll
    for (int i = 0; i < 8; ++i) vb[i] = __float2bfloat16(v[i] * inv);
    *(float4*)&p[tid * 8] = *(float4*)vb;
}

extern "C" void kernel_launch(void* const* d_in, const int* in_sizes, int n_in,
                              void* d_out, int out_size, void* d_ws, size_t ws_size,
                              hipStream_t stream)
{
    const int Bb = 4, T = 2048, E = 512, H = 8;
    const int HE = H * E;            // 4096
    const int N3 = 3 * HE;           // 12288
    const int N2 = 2 * HE;           // 8192 (Q|K row width)
    const int M  = Bb * T;           // 8192
    const long NX = (long)M * E;     // 4,194,304

    // ---- size-signature input assignment (order-robust) ----
    const void* xr = nullptr;
    const void* Wr[4] = {nullptr, nullptr, nullptr, nullptr};
    const void* br[3] = {nullptr, nullptr, nullptr};
    const void* bor = nullptr;
    int nw = 0, nb = 0;
    for (int i = 0; i < n_in; ++i) {
        int s = in_sizes[i];
        if      (s == (int)NX)      xr = d_in[i];
        else if (s == E * HE)       { if (nw < 4) Wr[nw++] = d_in[i]; }
        else if (s == HE)           { if (nb < 3) br[nb++] = d_in[i]; }
        else if (s == E)            bor = d_in[i];
    }
    if (!xr || nw < 4 || nb < 3 || !bor) {
        xr = d_in[0]; Wr[0] = d_in[1]; br[0] = d_in[2]; Wr[1] = d_in[3];
        br[1] = d_in[4]; Wr[2] = d_in[5]; br[2] = d_in[6]; Wr[3] = d_in[7];
        bor = d_in[8];
    }

    const float qscale = 0.04419417382415922f;  // 1/sqrt(512)
    const int   QC = 1 << 30;
    dim3 blk(256);

    // ---- workspace layout (bf16 elements) ----
    bf16* pool = (bf16*)d_ws;
    int*  flag = (int*)(void*)pool;
    bf16* xc   = pool + 8;
    bf16* bqc  = xc  + NX;
    bf16* bkc  = bqc + HE;
    bf16* bvc  = bkc + HE;
    bf16* boc  = bvc + HE;
    bf16* WqT  = boc + E;
    const size_t w2m = (size_t)E * HE;
    bf16* WkT  = WqT + w2m;
    bf16* WvT  = WkT + w2m;
    bf16* WoT  = WvT + w2m;
    bf16* Ofin = WoT + w2m;
    bf16* p0   = Ofin + NX;

    const size_t wsE    = ws_size / sizeof(bf16);
    const size_t fixedE = (size_t)(p0 - pool);
    const size_t preE   = (size_t)(Ofin - pool);   // fixed region w/o Ofin
    const size_t wQK   = (size_t)T * N2;
    const size_t wQKV  = (size_t)T * N3;
    const size_t wBat  = (size_t)T * HE;
    const size_t wHd   = (size_t)T * E;
    const size_t sAll  = (size_t)H * T * T;
    const size_t sOne  = (size_t)T * T;
    const size_t wBig  = (size_t)M * HE;
    const size_t wL    = 32768;   // fp32 L[H][T] as bf16-el units
    const size_t wL2   = 65536;   // fp32 L[2][H][T] as bf16-el units
    // Tier B3p (batch-paired PV, per-pair out-proj, Ofin region reused):
    //   preE + QKb + Vt2 + S2 + Opair + L2  ~= 248.1 MiB
    const size_t needB3p = preE + wQK + 2 * wBat + 2 * sAll + 2 * wBat + wL2;
    const size_t needB2 = fixedE + wQK + wBat + sAll + wBig + wL;  // ~208 MiB
    const size_t needB  = fixedE + wQKV + 2 * wBat + sAll;
    const size_t needC  = fixedE + 5 * wBat + sOne;
    const size_t needD  = fixedE + 5 * wHd  + sOne;
    if (wsE < needD) return;

    // ---- stage 0: dtype probe + canonicalize ----
    probe_dtype<<<dim3(1), blk, 0, stream>>>((const float*)xr, flag);
    convert_to_bf16<<<dim3((unsigned)((NX / 8 + 255) / 256)), blk, 0, stream>>>(
        xr, xc, NX, flag);
    convert_to_bf16<<<dim3(2), blk, 0, stream>>>(br[0], bqc, HE, flag);
    convert_to_bf16<<<dim3(2), blk, 0, stream>>>(br[1], bkc, HE, flag);
    convert_to_bf16<<<dim3(2), blk, 0, stream>>>(br[2], bvc, HE, flag);
    convert_to_bf16<<<dim3(1), blk, 0, stream>>>(bor, boc, E, flag);
    transpose_any<<<dim3(HE / 64, E / 64, 1), blk, 0, stream>>>(Wr[0], WqT, HE, E, flag);
    transpose_any<<<dim3(HE / 64, E / 64, 1), blk, 0, stream>>>(Wr[1], WkT, HE, E, flag);
    transpose_any<<<dim3(HE / 64, E / 64, 1), blk, 0, stream>>>(Wr[2], WvT, HE, E, flag);
    transpose_any<<<dim3(E / 64, HE / 64, 1), blk, 0, stream>>>(Wr[3], WoT, E, HE, flag);

    if (wsE >= needB3p) {
        // ---- Tier B3p: batch-paired PV (256 blocks, full machine);
        //      per-pair out-proj + emit; Ofin region reused as tier base ----
        bf16* QKb  = Ofin;                   // [t, 8192] Q|K (per batch)
        bf16* Vtb2 = QKb + wQK;              // 2 x [h,e,t]
        bf16* S2   = Vtb2 + 2 * wBat;        // 2 x exp(scores) [h,t,s]
        bf16* Opair = S2 + 2 * sAll;         // pair O [2T, HE]
        float* Lb2 = (float*)(Opair + 2 * wBat); // fp32 [2][H][T]
        bf16* Ppair = S2;                    // split-K P [2][4096, E] (S2 dead)
        const long MpE = (long)2 * T * E;    // pair out elements (4096*512)

        for (int pb = 0; pb < Bb / 2; ++pb) {
            zero_f32<<<dim3(128), blk, 0, stream>>>(Lb2, 2 * H * T);
            for (int i = 0; i < 2; ++i) {
                int b = pb * 2 + i;
                const bf16* xb = xc + (size_t)b * T * E;
                gemm256<4, 2><<<dim3(N3 / 256, T / 256, 1), dim3(512), 0, stream>>>(
                    xb, WqT, QKb, bqc, E, E, N2, 0, 0, 0, E, qscale, HE,
                    Vtb2 + (size_t)i * wBat, N2, nullptr);
                gemm256<1, 1><<<dim3(T / 256, T / 256, H), dim3(512), 0, stream>>>(
                    QKb + HE, QKb, S2 + (size_t)i * sAll, nullptr, N2, N2, T,
                    (long)E, (long)E, (long)T * T, E, 1.f, QC, nullptr, 0,
                    Lb2 + (size_t)i * H * T);
            }
            // PV for both batches of the pair in one 256-block dispatch
            gemm_pv3<<<dim3(256, 1, 1), dim3(512), 0, stream>>>(
                Vtb2, S2, Opair, Lb2, T, T, HE,
                (long)E * T, (long)T * T, (long)E,
                (long)wBat, (long)sAll, (long)T * HE, T);
            // per-pair out-proj: split-K=2 via z; P lives in dead S2 region
            gemm128n<6, 7><<<dim3(2 * T / 256, E / 128, 2), dim3(512), 0, stream>>>(
                WoT, Opair, Ppair, nullptr, HE, HE, E,
                0, 0, MpE, HE / 2, HE / 2);
            reduce_emit<<<dim3((unsigned)((MpE / 8 + 255) / 256)), blk, 0, stream>>>(
                Ppair, boc, d_out, MpE, E, flag, (long)pb * MpE);
        }
        return;
    }

    if (wsE >= needB2) {
        // ---- Tier B2 fallback: single-batch PV (gemm128n<5,5>) ----
        bf16* QKb = p0;
        bf16* Vtb = QKb + wQK;
        bf16* S   = Vtb + wBat;
        bf16* Oatt = S + sAll;
        float* Lbuf = (float*)(Oatt + wBig);

        for (int b = 0; b < Bb; ++b) {
            const bf16* xb = xc + (size_t)b * T * E;
            gemm256<4, 2><<<dim3(N3 / 256, T / 256, 1), dim3(512), 0, stream>>>(
                xb, WqT, QKb, bqc, E, E, N2, 0, 0, 0, E, qscale, HE, Vtb, N2,
                nullptr);
            zero_f32<<<dim3(64), blk, 0, stream>>>(Lbuf, H * T);
            gemm256<1, 1><<<dim3(T / 256, T / 256, H), dim3(512), 0, stream>>>(
                QKb + HE, QKb, S, nullptr, N2, N2, T,
                (long)E, (long)E, (long)T * T, E, 1.f, QC, nullptr, 0, Lbuf);
            gemm128n<5, 5><<<dim3(T / 256, E / 128, H), dim3(512), 0, stream>>>(
                Vtb, S, Oatt + (size_t)b * T * HE, Lbuf, T, T, HE,
                (long)E * T, (long)T * T, (long)E, T, 0);
        }
        gemm128n<6, 6><<<dim3(M / 256, E / 128, 2), dim3(512), 0, stream>>>(
            WoT, Oatt, QKb, nullptr, HE, HE, E,
            0, 0, (long)M * E, HE / 2, HE / 2);
        reduce_emit<<<dim3((unsigned)((NX / 8 + 255) / 256)), blk, 0, stream>>>(
            QKb, boc, d_out, NX, E, flag, 0);
        return;
    }

    if (wsE >= needB) {
        // ---- Tier B fallback: softmax path ----
        bf16* QKVb = p0;
        bf16* Vtb  = QKVb + wQKV;
        bf16* Oatt = Vtb + wBat;
        bf16* S    = Oatt + wBat;

        for (int b = 0; b < Bb; ++b) {
            const bf16* xb = xc + (size_t)b * T * E;
            gemm_bt<0><<<dim3(N3 / 128, T / 128, 1), blk, 0, stream>>>(
                xb, WqT, QKVb, bqc, E, E, N3, 0, 0, 0, E, qscale, HE, nullptr, 0);
            transpose_bf16<<<dim3(E / 64, T / 64, H), blk, 0, stream>>>(
                QKVb + 2 * HE, Vtb, N3, T, H, (long)E, (long)E * T, 0, 0);
            gemm_bt<0><<<dim3(T / 128, T / 128, H), blk, 0, stream>>>(
                QKVb, QKVb + HE, S, nullptr, N3, N3, T,
                (long)E, (long)E, (long)T * T, E, 1.f, QC, nullptr, 0);
            softmax_rows2048<<<dim3(H * T, 1, 1), blk, 0, stream>>>(S);
            gemm_bt<0><<<dim3(E / 128, T / 128, H), blk, 0, stream>>>(
                S, Vtb, Oatt, nullptr, T, T, HE,
                (long)T * T, (long)E * T, (long)E, T, 1.f, QC, nullptr, 0);
            gemm_bt_splitk<false><<<dim3(E / 128, T / 128, 8), blk, 0, stream>>>(
                Oatt, WoT, (bf16*)S, HE, HE, E, 0, 0, 0, (long)T * E, 8, HE / 8);
            reduce_splitk<<<dim3((unsigned)(((long)T * E / 8 + 255) / 256)), blk, 0, stream>>>(
                (bf16*)S, boc, Ofin + (size_t)b * T * E, (long)T * E, E, 8);
        }
    } else if (wsE >= needC) {
        // ---- Tier C fallback ----
        bf16* Qb  = p0;
        bf16* Kb  = Qb  + wBat;
        bf16* Vb  = Kb  + wBat;
        bf16* Vtb = Vb  + wBat;
        bf16* Ob  = Vtb + wBat;
        bf16* S   = Ob  + wBat;

        for (int b = 0; b < Bb; ++b) {
            const bf16* xb = xc + (size_t)b * T * E;
            gemm_bt<0><<<dim3(HE / 128, T / 128, 1), blk, 0, stream>>>(
                xb, WqT, Qb, bqc, E, E, HE, 0, 0, 0, E, qscale, QC, nullptr, 0);
            gemm_bt<0><<<dim3(HE / 128, T / 128, 1), blk, 0, stream>>>(
                xb, WkT, Kb, bkc, E, E, HE, 0, 0, 0, E, 1.f, QC, nullptr, 0);
            gemm_bt<0><<<dim3(HE / 128, T / 128, 1), blk, 0, stream>>>(
                xb, WvT, Vb, bvc, E, E, HE, 0, 0, 0, E, 1.f, QC, nullptr, 0);
            transpose_bf16<<<dim3(E / 64, T / 64, H), blk, 0, stream>>>(
                Vb, Vtb, HE, T, H, (long)E, (long)E * T, 0, 0);
            for (int h = 0; h < H; ++h) {
                gemm_bt<0><<<dim3(T / 128, T / 128, 1), blk, 0, stream>>>(
                    Qb + (size_t)h * E, Kb + (size_t)h * E, S, nullptr,
                    HE, HE, T, 0, 0, 0, E, 1.f, QC, nullptr, 0);
                softmax_rows2048<<<dim3(T, 1, 1), blk, 0, stream>>>(S);
                gemm_bt<0><<<dim3(E / 128, T / 128, 1), blk, 0, stream>>>(
                    S, Vtb + (size_t)h * E * T, Ob + (size_t)h * E, nullptr,
                    T, T, HE, 0, 0, 0, T, 1.f, QC, nullptr, 0);
            }
            gemm_bt<0><<<dim3(E / 128, T / 128, 1), blk, 0, stream>>>(
                Ob, WoT, Ofin + (size_t)b * T * E, boc,
                HE, HE, E, 0, 0, 0, HE, 1.f, QC, nullptr, 0);
        }
    } else {
        // ---- Tier D fallback ----
        bf16* Qh  = p0;
        bf16* Kh  = Qh  + wHd;
        bf16* Vh  = Kh  + wHd;
        bf16* Vth = Vh  + wHd;
        bf16* Oh  = Vth + wHd;
        bf16* S   = Oh  + wHd;

        for (int b = 0; b < Bb; ++b) {
            const bf16* xb = xc + (size_t)b * T * E;
            bf16* outb = Ofin + (size_t)b * T * E;
            for (int h = 0; h < H; ++h) {
                const size_t hw = (size_t)h * E * E;
                gemm_bt<0><<<dim3(E / 128, T / 128, 1), blk, 0, stream>>>(
                    xb, WqT + hw, Qh, bqc + (size_t)h * E, E, E, E,
                    0, 0, 0, E, qscale, QC, nullptr, 0);
                gemm_bt<0><<<dim3(E / 128, T / 128, 1), blk, 0, stream>>>(
                    xb, WkT + hw, Kh, bkc + (size_t)h * E, E, E, E,
                    0, 0, 0, E, 1.f, QC, nullptr, 0);
                gemm_bt<0><<<dim3(E / 128, T / 128, 1), blk, 0, stream>>>(
                    xb, WvT + hw, Vh, bvc + (size_t)h * E, E, E, E,
                    0, 0, 0, E, 1.f, QC, nullptr, 0);
                transpose_bf16<<<dim3(E / 64, T / 64, 1), blk, 0, stream>>>(
                    Vh, Vth, E, T, 1, 0, 0, 0, 0);
                gemm_bt<0><<<dim3(T / 128, T / 128, 1), blk, 0, stream>>>(
                    Qh, Kh, S, nullptr, E, E, T, 0, 0, 0, E, 1.f, QC, nullptr, 0);
                softmax_rows2048<<<dim3(T, 1, 1), blk, 0, stream>>>(S);
                gemm_bt<0><<<dim3(E / 128, T / 128, 1), blk, 0, stream>>>(
                    S, Vth, Oh, nullptr, T, T, E, 0, 0, 0, T, 1.f, QC, nullptr, 0);
                if (h == 0)
                    gemm_bt<0><<<dim3(E / 128, T / 128, 1), blk, 0, stream>>>(
                        Oh, WoT, outb, boc, E, HE, E, 0, 0, 0, E, 1.f, QC, nullptr, 0);
                else
                    gemm_bt<2><<<dim3(E / 128, T / 128, 1), blk, 0, stream>>>(
                        Oh, WoT + (size_t)h * E, outb, nullptr,
                        E, HE, E, 0, 0, 0, E, 1.f, QC, nullptr, 0);
            }
        }
    }

    // ---- emit in the probed dtype (fallback tiers only) ----
    emit_out<<<dim3((unsigned)((NX / 8 + 255) / 256)), blk, 0, stream>>>(
        Ofin, d_out, NX, flag);
}

// Round 12
// 809.963 us; speedup vs baseline: 1.2112x; 1.0594x over previous
//
#include <hip/hip_runtime.h>
#include <hip/hip_bf16.h>
#include <stdint.h>

typedef __hip_bfloat16 bf16;
typedef __bf16 bf16x8 __attribute__((ext_vector_type(8)));
typedef float floatx4 __attribute__((ext_vector_type(4)));

#define AS_LDS __attribute__((address_space(3)))
#define AS_GLB __attribute__((address_space(1)))

__device__ __forceinline__ void gload_lds16(const bf16* g, bf16* l) {
    __builtin_amdgcn_global_load_lds((const AS_GLB void*)g, (AS_LDS void*)l, 16, 0, 0);
}

// ---------- dtype probe: *flag = 1 if x is fp32, 0 if bf16 ----------
__global__ void probe_dtype(const float* __restrict__ x, int* __restrict__ flag) {
    __shared__ int cnt;
    if (threadIdx.x == 0) cnt = 0;
    __syncthreads();
    int ok = 0;
    for (int i = threadIdx.x; i < 4096; i += 256) {
        float v = x[i];
        if (v == v && fabsf(v) < 1.0e3f) ok++;
    }
    atomicAdd(&cnt, ok);
    __syncthreads();
    if (threadIdx.x == 0) *flag = (cnt > 2048) ? 1 : 0;
}

__global__ __launch_bounds__(256) void zero_f32(float* __restrict__ p, int n) {
    int i = blockIdx.x * 256 + threadIdx.x;
    if (i < n) p[i] = 0.f;
}

// ---------- convert raw (fp32 or bf16 per flag) -> canonical bf16 ----------
__global__ __launch_bounds__(256) void convert_to_bf16(
    const void* __restrict__ in, bf16* __restrict__ out, long n,
    const int* __restrict__ flag)
{
    long i = ((long)blockIdx.x * 256 + threadIdx.x) * 8;
    if (i >= n) return;
    bf16 o[8];
    if (*flag) {
        const float* p = (const float*)in + i;
        float4 a = *(const float4*)p;
        float4 b = *(const float4*)(p + 4);
        o[0] = __float2bfloat16(a.x); o[1] = __float2bfloat16(a.y);
        o[2] = __float2bfloat16(a.z); o[3] = __float2bfloat16(a.w);
        o[4] = __float2bfloat16(b.x); o[5] = __float2bfloat16(b.y);
        o[6] = __float2bfloat16(b.z); o[7] = __float2bfloat16(b.w);
    } else {
        *(float4*)o = *(const float4*)((const bf16*)in + i);
    }
    *(float4*)&out[i] = *(float4*)o;
}

// ---------- emit canonical bf16 -> d_out in flag dtype (fallback tiers) ----
__global__ __launch_bounds__(256) void emit_out(
    const bf16* __restrict__ in, void* __restrict__ out, long n,
    const int* __restrict__ flag)
{
    long i = ((long)blockIdx.x * 256 + threadIdx.x) * 8;
    if (i >= n) return;
    bf16 v[8];
    *(float4*)v = *(const float4*)&in[i];
    if (*flag) {
        float* o = (float*)out + i;
        float4 a, b;
        a.x = __bfloat162float(v[0]); a.y = __bfloat162float(v[1]);
        a.z = __bfloat162float(v[2]); a.w = __bfloat162float(v[3]);
        b.x = __bfloat162float(v[4]); b.y = __bfloat162float(v[5]);
        b.z = __bfloat162float(v[6]); b.w = __bfloat162float(v[7]);
        *(float4*)o = a;
        *(float4*)(o + 4) = b;
    } else {
        *(float4*)((bf16*)out + i) = *(float4*)v;
    }
}

// ---------- transpose raw-dtype input -> bf16 output ----------
__global__ __launch_bounds__(256) void transpose_any(
    const void* __restrict__ inv, bf16* __restrict__ out,
    int ldin, int ldout, const int* __restrict__ flag)
{
    __shared__ bf16 tile[64][80];
    const int fp32 = *flag;
    const int c0 = blockIdx.x * 64;
    const int r0 = blockIdx.y * 64;
    const int tid = threadIdx.x;
#pragma unroll
    for (int it = 0; it < 2; ++it) {
        int ch = tid + it * 256;
        int r = ch >> 3, c = (ch & 7) * 8;
        long eidx = (long)(r0 + r) * ldin + (c0 + c);
        if (fp32) {
            const float* p = (const float*)inv + eidx;
            float4 a = *(const float4*)p;
            float4 b = *(const float4*)(p + 4);
            bf16 o[8];
            o[0] = __float2bfloat16(a.x); o[1] = __float2bfloat16(a.y);
            o[2] = __float2bfloat16(a.z); o[3] = __float2bfloat16(a.w);
            o[4] = __float2bfloat16(b.x); o[5] = __float2bfloat16(b.y);
            o[6] = __float2bfloat16(b.z); o[7] = __float2bfloat16(b.w);
            *(float4*)&tile[r][c] = *(float4*)o;
        } else {
            *(float4*)&tile[r][c] = *(const float4*)((const bf16*)inv + eidx);
        }
    }
    __syncthreads();
#pragma unroll
    for (int it = 0; it < 2; ++it) {
        int ch = tid + it * 256;
        int oc = ch >> 3, rb = (ch & 7) * 8;
        bf16 tmp[8];
#pragma unroll
        for (int i = 0; i < 8; ++i) tmp[i] = tile[rb + i][oc];
        *(float4*)&out[(long)(c0 + oc) * ldout + r0 + rb] = *(float4*)tmp;
    }
}

// ---------- pure-bf16 transpose (fallback tiers) ----------
__global__ __launch_bounds__(256) void transpose_bf16(
    const bf16* __restrict__ in, bf16* __restrict__ out,
    int ldin, int ldout,
    int nz1, long in_z1, long out_z1, long in_z2, long out_z2)
{
    __shared__ bf16 tile[64][80];
    const int z = blockIdx.z;
    const int z1 = z % nz1, z2 = z / nz1;
    in  += (long)z1 * in_z1 + (long)z2 * in_z2;
    out += (long)z1 * out_z1 + (long)z2 * out_z2;
    const int c0 = blockIdx.x * 64;
    const int r0 = blockIdx.y * 64;
    const int tid = threadIdx.x;
#pragma unroll
    for (int it = 0; it < 2; ++it) {
        int ch = tid + it * 256;
        int r = ch >> 3, c = (ch & 7) * 8;
        *(float4*)&tile[r][c] = *(const float4*)&in[(long)(r0 + r) * ldin + c0 + c];
    }
    __syncthreads();
#pragma unroll
    for (int it = 0; it < 2; ++it) {
        int ch = tid + it * 256;
        int oc = ch >> 3, rb = (ch & 7) * 8;
        bf16 tmp[8];
#pragma unroll
        for (int i = 0; i < 8; ++i) tmp[i] = tile[rb + i][oc];
        *(float4*)&out[(long)(c0 + oc) * ldout + r0 + rb] = *(float4*)tmp;
    }
}

// =====================================================================
// 256x256-tile 8-wave 8-phase GEMM. C = A * Bt^T.
// MODE 1 (QK, swapped A=K,B=Q): S[q][s]=exp(acc), 8B stores; accumulates
//   rowsum L[q] via cross-lane reduce + fp32 atomicAdd.
// MODE 4 (QKV, single batch or batch-PAIR): Q|K part via 4x4 shuffle
//   transpose -> 8B row stores; V part written transposed to
//   Vt + (m0>>11)*vbz with t local to the batch (m0&2047). For a
//   single-batch launch m0<2048 so the extra terms vanish.
// SWZ 1: head-per-XCD for grid (8,8,8). SWZ 2: 6-ntile chunks,
//   grid (48,NY,1), NY<=16 (flat = bxx + byy*48; bijective for NY*48 wgs).
// =====================================================================
template <int MODE, int SWZ>
__global__ __launch_bounds__(512, 2) void gemm256(
    const bf16* __restrict__ A, const bf16* __restrict__ Bt,
    bf16* __restrict__ C, const bf16* __restrict__ bias,
    int lda, int ldb, int ldc,
    long az, long bz, long cz, int K, float scale, int qcols,
    bf16* __restrict__ Vt, int vcol0, float* __restrict__ Lsum, long vbz)
{
    __shared__ bf16 AsL[2][2][256 * 32];
    __shared__ bf16 BsL[2][2][256 * 32];

    const int tid  = threadIdx.x;
    const int lane = tid & 63;
    const int wave = tid >> 6;
    const int wr = wave >> 2;        // 0..1  row half of C tile
    const int wc = wave & 3;         // 0..3  col quarter of C tile
    const int lm = lane & 15;
    const int cl = lane >> 4;        // fragment k-chunk 0..3

    int bxx = blockIdx.x, byy = blockIdx.y, bzz = blockIdx.z;
    if constexpr (SWZ == 1) {        // grid (8,8,8): head z = XCD
        int flat = bxx + (byy << 3) + (bzz << 6);
        int xcd = flat & 7, idx = flat >> 3;
        bzz = xcd; bxx = idx & 7; byy = idx >> 3;
    } else if constexpr (SWZ == 2) { // grid (48,NY,1): 6 n-tiles per XCD
        int flat = bxx + byy * 48;
        int xcd = flat & 7, idx = flat >> 3;
        bxx = xcd * 6 + idx % 6; byy = idx / 6; bzz = 0;
    }
    const long zz = bzz;
    A  += zz * az;
    Bt += zz * bz;
    C  += zz * cz;
    float* Lz = (MODE == 1) ? (Lsum + zz * 2048) : nullptr;
    const int m0 = byy * 256;
    const int n0 = bxx * 256;

    // per-lane swizzled ds_read offsets within a [256][32] k-half block
    int offA[8], offB[4];
#pragma unroll
    for (int i = 0; i < 8; ++i) {
        int row = wr * 128 + i * 16 + lm;
        offA[i] = row * 32 + ((cl ^ ((row >> 1) & 3)) << 3);
    }
#pragma unroll
    for (int j = 0; j < 4; ++j) {
        int row = wc * 64 + j * 16 + lm;
        offB[j] = row * 32 + ((cl ^ ((row >> 1) & 3)) << 3);
    }

    const int sr = lane >> 2;        // staging row-in-16
    const int sc = lane & 3;         // staging chunk
    const int NT = K >> 6;           // 64-wide K tiles (NT even)

    floatx4 acc[8][4];
#pragma unroll
    for (int i = 0; i < 8; ++i)
#pragma unroll
        for (int j = 0; j < 4; ++j)
            acc[i][j] = (floatx4){0.f, 0.f, 0.f, 0.f};

    // stage one (operand, khalf) unit of tile t: 2 x global_load_lds
    auto stageU = [&](int which, int t, int kh) {
        if (t >= NT) return;
        const bf16* G = which ? Bt : A;
        const int ldg  = which ? ldb : lda;
        const int g0   = which ? n0 : m0;
        bf16* lb = which ? &BsL[t & 1][kh][0] : &AsL[t & 1][kh][0];
        const int kcol = t * 64 + kh * 32;
#pragma unroll
        for (int ii = 0; ii < 2; ++ii) {
            int row = ii * 128 + wave * 16 + sr;
            int cg  = sc ^ ((row >> 1) & 3);   // pre-swizzled global chunk
            gload_lds16(G + (long)(g0 + row) * ldg + kcol + cg * 8,
                        lb + row * 32 + sc * 8);
        }
    };

    bf16x8 af[8], bfv[2];
    auto dsA = [&](int b, int kh) {
        const bf16* p = &AsL[b][kh][0];
#pragma unroll
        for (int i = 0; i < 8; ++i) af[i] = *(const bf16x8*)(p + offA[i]);
    };
    auto dsB = [&](int b, int kh, int nh) {
        const bf16* p = &BsL[b][kh][0];
        bfv[0] = *(const bf16x8*)(p + offB[nh * 2]);
        bfv[1] = *(const bf16x8*)(p + offB[nh * 2 + 1]);
    };
    auto mfmaQ = [&](int nh) {
        __builtin_amdgcn_s_setprio(1);
#pragma unroll
        for (int i = 0; i < 8; ++i) {
            acc[i][nh * 2] = __builtin_amdgcn_mfma_f32_16x16x32_bf16(
                af[i], bfv[0], acc[i][nh * 2], 0, 0, 0);
            acc[i][nh * 2 + 1] = __builtin_amdgcn_mfma_f32_16x16x32_bf16(
                af[i], bfv[1], acc[i][nh * 2 + 1], 0, 0, 0);
        }
        __builtin_amdgcn_s_setprio(0);
    };

#define BAR    __builtin_amdgcn_s_barrier()
#define SBZ    __builtin_amdgcn_sched_barrier(0)
#define LGKM0  do { asm volatile("s_waitcnt lgkmcnt(0)" ::: "memory"); SBZ; } while (0)
#define VM(n)  do { asm volatile("s_waitcnt vmcnt(" #n ")" ::: "memory"); SBZ; } while (0)

    // ---- prologue: tile0 (all), tile1 k0 ----
    stageU(0, 0, 0); stageU(1, 0, 0); stageU(0, 0, 1); stageU(1, 0, 1);
    stageU(0, 1, 0); stageU(1, 1, 0);
    VM(4);
    BAR;

    for (int t0 = 0; t0 < NT; t0 += 2) {
        const bool last = (t0 + 2 >= NT);
        dsA(0, 0); dsB(0, 0, 0); stageU(0, t0 + 1, 1);
        BAR; LGKM0; mfmaQ(0); BAR;
        dsB(0, 0, 1); stageU(1, t0 + 1, 1);
        BAR; LGKM0; mfmaQ(1); BAR;
        dsA(0, 1); dsB(0, 1, 0); stageU(0, t0 + 2, 0);
        BAR; LGKM0; mfmaQ(0); BAR;
        dsB(0, 1, 1); stageU(1, t0 + 2, 0);
        BAR; LGKM0; mfmaQ(1);
        if (last) { VM(0); } else { VM(4); }
        BAR;
        dsA(1, 0); dsB(1, 0, 0); stageU(0, t0 + 2, 1);
        BAR; LGKM0; mfmaQ(0); BAR;
        dsB(1, 0, 1); stageU(1, t0 + 2, 1);
        BAR; LGKM0; mfmaQ(1); BAR;
        dsA(1, 1); dsB(1, 1, 0); stageU(0, t0 + 3, 0);
        BAR; LGKM0; mfmaQ(0); BAR;
        dsB(1, 1, 1); stageU(1, t0 + 3, 0);
        BAR; LGKM0; mfmaQ(1);
        if (!last) { VM(4); }
        BAR;
    }
#undef BAR
#undef SBZ
#undef LGKM0
#undef VM

    // ---- epilogue ----
    const int cr = (lane >> 4) * 4;
    if constexpr (MODE == 1) {
        // swapped operands: acc(row=s, col=q). Store S[q][s] = exp(acc):
        // lane holds 4 consecutive s -> 8B packet. Also rowsum -> atomic.
#pragma unroll
        for (int j = 0; j < 4; ++j) {
            long q = n0 + wc * 64 + j * 16 + lm;
            bf16* Cr = C + q * ldc + m0 + wr * 128;
            float rs = 0.f;
#pragma unroll
            for (int i = 0; i < 8; ++i) {
                bf16 pk[4];
#pragma unroll
                for (int r = 0; r < 4; ++r) {
                    float e = __expf(acc[i][j][r]);
                    rs += e;
                    pk[r] = __float2bfloat16(e);
                }
                *(uint64_t*)&Cr[i * 16 + cr] = *(const uint64_t*)pk;
            }
            rs += __shfl_xor(rs, 16);
            rs += __shfl_xor(rs, 32);
            if (cl == 0) atomicAdd(&Lz[q], rs);
        }
    } else {   // MODE 4
        if (n0 >= vcol0) {
            // V block: write transposed; batch from m0 (pair launches)
            const int ib = m0 >> 11;
            const int tl0 = (m0 & 2047) + wr * 128;
#pragma unroll
            for (int j = 0; j < 4; ++j) {
                int col = n0 + wc * 64 + j * 16 + lm;
                float bv = __bfloat162float(bias[col]);
                int eg = col - vcol0;
                bf16* vt = Vt + (long)ib * vbz
                         + ((long)(eg >> 9) * 512 + (eg & 511)) * 2048;
#pragma unroll
                for (int i = 0; i < 8; ++i) {
                    int t0v = tl0 + i * 16 + cr;
                    bf16 pk[4];
#pragma unroll
                    for (int r = 0; r < 4; ++r)
                        pk[r] = __float2bfloat16(acc[i][j][r] + bv);
                    *(uint64_t*)&vt[t0v] = *(const uint64_t*)pk;
                }
            }
        } else {
            // Q|K: bias+scale, then 4x4 shuffle transpose -> 8B row stores
            const int l4 = lane & 3;
            float bvj[4], scj[4];
#pragma unroll
            for (int j = 0; j < 4; ++j) {
                int col = n0 + wc * 64 + j * 16 + lm;
                bvj[j] = __bfloat162float(bias[col]);
                scj[j] = (col < qcols) ? scale : 1.0f;
            }
#pragma unroll
            for (int i = 0; i < 8; ++i) {
                int row = m0 + wr * 128 + i * 16 + cr + l4;
                bf16* Cr = C + (long)row * ldc + n0 + wc * 64 + (lm & ~3);
#pragma unroll
                for (int j = 0; j < 4; ++j) {
                    float x0 = (acc[i][j][0] + bvj[j]) * scj[j];
                    float x1 = (acc[i][j][1] + bvj[j]) * scj[j];
                    float x2 = (acc[i][j][2] + bvj[j]) * scj[j];
                    float x3 = (acc[i][j][3] + bvj[j]) * scj[j];
                    float u = __shfl_xor((l4 & 1) ? x0 : x1, 1);
                    float v = __shfl_xor((l4 & 1) ? x2 : x3, 1);
                    if (l4 & 1) { x0 = u; x2 = v; } else { x1 = u; x3 = v; }
                    u = __shfl_xor((l4 & 2) ? x0 : x2, 2);
                    v = __shfl_xor((l4 & 2) ? x1 : x3, 2);
                    if (l4 & 2) { x0 = u; x1 = v; } else { x2 = u; x3 = v; }
                    bf16 pk[4];
                    pk[0] = __float2bfloat16(x0); pk[1] = __float2bfloat16(x1);
                    pk[2] = __float2bfloat16(x2); pk[3] = __float2bfloat16(x3);
                    *(uint64_t*)&Cr[j * 16] = *(const uint64_t*)pk;
                }
            }
        }
    }
}

// =====================================================================
// PV kernel (batch-paired): 256x256-tile 8-wave 8-phase, grid (256,1,1).
// flat = blockIdx.x: head = flat&7 (= XCD), idx = flat>>3:
// q-tile = idx&7, ch-tile = (idx>>3)&1, batch-half i = idx>>4.
// O[q][ch] = acc / L[q]; 8B packets of 4 consecutive ch.
// =====================================================================
__global__ __launch_bounds__(512, 2) void gemm_pv3(
    const bf16* __restrict__ A, const bf16* __restrict__ Bt,
    bf16* __restrict__ C, const float* __restrict__ L,
    int lda, int ldb, int ldc,
    long az, long bz, long cz,
    long abz, long sbz, long cbz, int K)
{
    __shared__ bf16 AsL[2][2][256 * 32];
    __shared__ bf16 BsL[2][2][256 * 32];

    const int tid  = threadIdx.x;
    const int lane = tid & 63;
    const int wave = tid >> 6;
    const int wr = wave >> 2;
    const int wc = wave & 3;
    const int lm = lane & 15;
    const int cl = lane >> 4;

    const int flat = blockIdx.x;     // 0..255
    const int h   = flat & 7;        // head = XCD
    const int idx = flat >> 3;
    const int qb  = idx & 7;         // q-tile 0..7
    const int chb = (idx >> 3) & 1;  // ch-tile 0..1
    const int ib  = idx >> 4;        // batch-half 0..1
    A  += (long)ib * abz + (long)h * az;
    Bt += (long)ib * sbz + (long)h * bz;
    C  += (long)ib * cbz + (long)h * cz;
    const float* Lz = L + (long)ib * 16384 + (long)h * 2048;
    const int m0 = chb * 256;        // ch base
    const int n0 = qb * 256;         // q base

    int offA[8], offB[4];
#pragma unroll
    for (int i = 0; i < 8; ++i) {
        int row = wr * 128 + i * 16 + lm;
        offA[i] = row * 32 + ((cl ^ ((row >> 1) & 3)) << 3);
    }
#pragma unroll
    for (int j = 0; j < 4; ++j) {
        int row = wc * 64 + j * 16 + lm;
        offB[j] = row * 32 + ((cl ^ ((row >> 1) & 3)) << 3);
    }

    const int sr = lane >> 2;
    const int sc = lane & 3;
    const int NT = K >> 6;           // 32, even

    floatx4 acc[8][4];
#pragma unroll
    for (int i = 0; i < 8; ++i)
#pragma unroll
        for (int j = 0; j < 4; ++j)
            acc[i][j] = (floatx4){0.f, 0.f, 0.f, 0.f};

    auto stageU = [&](int which, int t, int kh) {
        if (t >= NT) return;
        const bf16* G = which ? Bt : A;
        const int ldg  = which ? ldb : lda;
        const int g0   = which ? n0 : m0;
        bf16* lb = which ? &BsL[t & 1][kh][0] : &AsL[t & 1][kh][0];
        const int kcol = t * 64 + kh * 32;
#pragma unroll
        for (int ii = 0; ii < 2; ++ii) {
            int row = ii * 128 + wave * 16 + sr;
            int cg  = sc ^ ((row >> 1) & 3);
            gload_lds16(G + (long)(g0 + row) * ldg + kcol + cg * 8,
                        lb + row * 32 + sc * 8);
        }
    };

    bf16x8 af[8], bfv[2];
    auto dsA = [&](int b, int kh) {
        const bf16* p = &AsL[b][kh][0];
#pragma unroll
        for (int i = 0; i < 8; ++i) af[i] = *(const bf16x8*)(p + offA[i]);
    };
    auto dsB = [&](int b, int kh, int nh) {
        const bf16* p = &BsL[b][kh][0];
        bfv[0] = *(const bf16x8*)(p + offB[nh * 2]);
        bfv[1] = *(const bf16x8*)(p + offB[nh * 2 + 1]);
    };
    auto mfmaQ = [&](int nh) {
        __builtin_amdgcn_s_setprio(1);
#pragma unroll
        for (int i = 0; i < 8; ++i) {
            acc[i][nh * 2] = __builtin_amdgcn_mfma_f32_16x16x32_bf16(
                af[i], bfv[0], acc[i][nh * 2], 0, 0, 0);
            acc[i][nh * 2 + 1] = __builtin_amdgcn_mfma_f32_16x16x32_bf16(
                af[i], bfv[1], acc[i][nh * 2 + 1], 0, 0, 0);
        }
        __builtin_amdgcn_s_setprio(0);
    };

#define BAR    __builtin_amdgcn_s_barrier()
#define SBZ    __builtin_amdgcn_sched_barrier(0)
#define LGKM0  do { asm volatile("s_waitcnt lgkmcnt(0)" ::: "memory"); SBZ; } while (0)
#define VM(n)  do { asm volatile("s_waitcnt vmcnt(" #n ")" ::: "memory"); SBZ; } while (0)

    stageU(0, 0, 0); stageU(1, 0, 0); stageU(0, 0, 1); stageU(1, 0, 1);
    stageU(0, 1, 0); stageU(1, 1, 0);
    VM(4);
    BAR;

    for (int t0 = 0; t0 < NT; t0 += 2) {
        const bool last = (t0 + 2 >= NT);
        dsA(0, 0); dsB(0, 0, 0); stageU(0, t0 + 1, 1);
        BAR; LGKM0; mfmaQ(0); BAR;
        dsB(0, 0, 1); stageU(1, t0 + 1, 1);
        BAR; LGKM0; mfmaQ(1); BAR;
        dsA(0, 1); dsB(0, 1, 0); stageU(0, t0 + 2, 0);
        BAR; LGKM0; mfmaQ(0); BAR;
        dsB(0, 1, 1); stageU(1, t0 + 2, 0);
        BAR; LGKM0; mfmaQ(1);
        if (last) { VM(0); } else { VM(4); }
        BAR;
        dsA(1, 0); dsB(1, 0, 0); stageU(0, t0 + 2, 1);
        BAR; LGKM0; mfmaQ(0); BAR;
        dsB(1, 0, 1); stageU(1, t0 + 2, 1);
        BAR; LGKM0; mfmaQ(1); BAR;
        dsA(1, 1); dsB(1, 1, 0); stageU(0, t0 + 3, 0);
        BAR; LGKM0; mfmaQ(0); BAR;
        dsB(1, 1, 1); stageU(1, t0 + 3, 0);
        BAR; LGKM0; mfmaQ(1);
        if (!last) { VM(4); }
        BAR;
    }
#undef BAR
#undef SBZ
#undef LGKM0
#undef VM

    // epilogue: acc rows = ch, cols = q. O[q][ch] = acc / L[q].
    const int cr = (lane >> 4) * 4;
#pragma unroll
    for (int j = 0; j < 4; ++j) {
        long q = n0 + wc * 64 + j * 16 + lm;
        float inv = 1.0f / Lz[q];
        bf16* Cr = C + q * ldc + m0 + wr * 128;
#pragma unroll
        for (int i = 0; i < 8; ++i) {
            bf16 pk[4];
#pragma unroll
            for (int r = 0; r < 4; ++r)
                pk[r] = __float2bfloat16(acc[i][j][r] * inv);
            *(uint64_t*)&Cr[i * 16 + cr] = *(const uint64_t*)pk;
        }
    }
}

// =====================================================================
// 128(M)x256(N)-tile 8-wave 8-phase GEMM. 96KB LDS.
// MODE 5 (PV fallback): O[q][ch] = acc / L[q].
// MODE 6 (out-proj split-K): P[t][ch] = acc partial, z = k-split.
// SWZ 5: head-per-XCD, grid (8,4,8). SWZ 6: chunked, grid (32,4,2).
// SWZ 7: chunked, grid (16,4,2) (per-pair out-proj).
// =====================================================================
template <int MODE, int SWZ>
__global__ __launch_bounds__(512, 2) void gemm128n(
    const bf16* __restrict__ A, const bf16* __restrict__ Bt,
    bf16* __restrict__ C, const float* __restrict__ L,
    int lda, int ldb, int ldc,
    long az, long bz, long cz, int K, int kper)
{
    __shared__ bf16 AsL[2][2][128 * 32];
    __shared__ bf16 BsL[2][2][256 * 32];

    const int tid  = threadIdx.x;
    const int lane = tid & 63;
    const int wave = tid >> 6;
    const int wr = wave >> 2;        // 0..1  m-half (64 rows)
    const int wc = wave & 3;         // 0..3  n-quarter (64 cols)
    const int lm = lane & 15;
    const int cl = lane >> 4;

    int bxx = blockIdx.x, byy = blockIdx.y, bzz = blockIdx.z;
    if constexpr (SWZ == 5) {        // grid (8,4,8): head z = XCD
        int flat = bxx + (byy << 3) + (bzz << 5);
        int xcd = flat & 7, idx = flat >> 3;
        bzz = xcd; bxx = idx & 7; byy = idx >> 3;
    } else if constexpr (SWZ == 6) { // grid (32,4,2): chunked remap
        int flat = bxx + (byy << 5) + (bzz << 7);
        int nf = (flat & 7) * 32 + (flat >> 3);
        bzz = nf >> 7; int rr = nf & 127; byy = rr >> 5; bxx = rr & 31;
    } else if constexpr (SWZ == 7) { // grid (16,4,2): chunked remap
        int flat = bxx + (byy << 4) + (bzz << 6);
        int nf = (flat & 7) * 16 + (flat >> 3);
        bzz = nf >> 6; int rr = nf & 63; byy = rr >> 4; bxx = rr & 15;
    }
    const long zz = bzz;
    A  += zz * az;
    Bt += zz * bz;
    C  += zz * cz;
    const float* Lz = (MODE == 5) ? (L + zz * 2048) : nullptr;
    const int kbase = (int)(zz * (long)kper);
    const int m0 = byy * 128;
    const int n0 = bxx * 256;

    int offA[4], offB[4];
#pragma unroll
    for (int i = 0; i < 4; ++i) {
        int row = wr * 64 + i * 16 + lm;
        offA[i] = row * 32 + ((cl ^ ((row >> 1) & 3)) << 3);
    }
#pragma unroll
    for (int j = 0; j < 4; ++j) {
        int row = wc * 64 + j * 16 + lm;
        offB[j] = row * 32 + ((cl ^ ((row >> 1) & 3)) << 3);
    }

    const int sr = lane >> 2;
    const int sc = lane & 3;
    const int NT = K >> 6;           // even

    floatx4 acc[4][4];
#pragma unroll
    for (int i = 0; i < 4; ++i)
#pragma unroll
        for (int j = 0; j < 4; ++j)
            acc[i][j] = (floatx4){0.f, 0.f, 0.f, 0.f};

    auto stageA = [&](int t, int kh) {   // 1 load/thread
        if (t >= NT) return;
        bf16* lb = &AsL[t & 1][kh][0];
        const int kcol = kbase + t * 64 + kh * 32;
        int row = wave * 16 + sr;
        int cg  = sc ^ ((row >> 1) & 3);
        gload_lds16(A + (long)(m0 + row) * lda + kcol + cg * 8,
                    lb + row * 32 + sc * 8);
    };
    auto stageB = [&](int t, int kh) {   // 2 loads/thread
        if (t >= NT) return;
        bf16* lb = &BsL[t & 1][kh][0];
        const int kcol = kbase + t * 64 + kh * 32;
#pragma unroll
        for (int ii = 0; ii < 2; ++ii) {
            int row = ii * 128 + wave * 16 + sr;
            int cg  = sc ^ ((row >> 1) & 3);
            gload_lds16(Bt + (long)(n0 + row) * ldb + kcol + cg * 8,
                        lb + row * 32 + sc * 8);
        }
    };

    bf16x8 af[4], bfv[2];
    auto dsA = [&](int b, int kh) {
        const bf16* p = &AsL[b][kh][0];
#pragma unroll
        for (int i = 0; i < 4; ++i) af[i] = *(const bf16x8*)(p + offA[i]);
    };
    auto dsB = [&](int b, int kh, int nh) {
        const bf16* p = &BsL[b][kh][0];
        bfv[0] = *(const bf16x8*)(p + offB[nh * 2]);
        bfv[1] = *(const bf16x8*)(p + offB[nh * 2 + 1]);
    };
    auto mfmaQ = [&](int nh) {
        __builtin_amdgcn_s_setprio(1);
#pragma unroll
        for (int i = 0; i < 4; ++i) {
            acc[i][nh * 2] = __builtin_amdgcn_mfma_f32_16x16x32_bf16(
                af[i], bfv[0], acc[i][nh * 2], 0, 0, 0);
            acc[i][nh * 2 + 1] = __builtin_amdgcn_mfma_f32_16x16x32_bf16(
                af[i], bfv[1], acc[i][nh * 2 + 1], 0, 0, 0);
        }
        __builtin_amdgcn_s_setprio(0);
    };

#define BAR    __builtin_amdgcn_s_barrier()
#define SBZ    __builtin_amdgcn_sched_barrier(0)
#define LGKM0  do { asm volatile("s_waitcnt lgkmcnt(0)" ::: "memory"); SBZ; } while (0)
#define VM(n)  do { asm volatile("s_waitcnt vmcnt(" #n ")" ::: "memory"); SBZ; } while (0)

    stageA(0, 0); stageB(0, 0); stageA(0, 1); stageB(0, 1);
    stageA(1, 0); stageB(1, 0);
    VM(3);
    BAR;

    for (int t0 = 0; t0 < NT; t0 += 2) {
        const bool last = (t0 + 2 >= NT);
        dsA(0, 0); dsB(0, 0, 0); stageA(t0 + 1, 1);
        BAR; LGKM0; mfmaQ(0); BAR;
        dsB(0, 0, 1); stageB(t0 + 1, 1);
        BAR; LGKM0; mfmaQ(1); BAR;
        dsA(0, 1); dsB(0, 1, 0); stageA(t0 + 2, 0);
        BAR; LGKM0; mfmaQ(0); BAR;
        dsB(0, 1, 1); stageB(t0 + 2, 0);
        BAR; LGKM0; mfmaQ(1);
        if (last) { VM(0); } else { VM(3); }
        BAR;
        dsA(1, 0); dsB(1, 0, 0); stageA(t0 + 2, 1);
        BAR; LGKM0; mfmaQ(0); BAR;
        dsB(1, 0, 1); stageB(t0 + 2, 1);
        BAR; LGKM0; mfmaQ(1); BAR;
        dsA(1, 1); dsB(1, 1, 0); stageA(t0 + 3, 0);
        BAR; LGKM0; mfmaQ(0); BAR;
        dsB(1, 1, 1); stageB(t0 + 3, 0);
        BAR; LGKM0; mfmaQ(1);
        if (!last) { VM(3); }
        BAR;
    }
#undef BAR
#undef SBZ
#undef LGKM0
#undef VM

    const int cr = cl * 4;
#pragma unroll
    for (int j = 0; j < 4; ++j) {
        int col = n0 + wc * 64 + j * 16 + lm;
        bf16* Cr = C + (long)col * ldc + m0 + wr * 64;
        float inv = 1.0f;
        if constexpr (MODE == 5) inv = 1.0f / Lz[col];
#pragma unroll
        for (int i = 0; i < 4; ++i) {
            bf16 pk[4];
#pragma unroll
            for (int r = 0; r < 4; ++r)
                pk[r] = __float2bfloat16(acc[i][j][r] * inv);
            *(uint64_t*)&Cr[i * 16 + cr] = *(const uint64_t*)pk;
        }
    }
}

// ---------- GEMM (bf16 in/out, fp32 acc), fallback tiers -----------------
template <int MODE, bool SWAP = false>
__global__ __launch_bounds__(256) void gemm_bt(
    const bf16* __restrict__ A, const bf16* __restrict__ Bt,
    bf16* __restrict__ C, const bf16* __restrict__ bias,
    int lda, int ldb, int ldc,
    long az, long bz, long cz, int K, float scale, int qcols,
    bf16* __restrict__ Vt, int vcol0)
{
    __shared__ bf16 As[128 * 64];
    __shared__ bf16 Bs[128 * 64];

    const int tid  = threadIdx.x;
    const int lane = tid & 63;
    const int wave = tid >> 6;
    const int wx = wave & 1;
    const int wy = wave >> 1;

    const long zz = blockIdx.z;
    A  += zz * az;
    Bt += zz * bz;
    C  += zz * cz;
    const int bm = SWAP ? blockIdx.x : blockIdx.y;
    const int bn = SWAP ? blockIdx.y : blockIdx.x;
    const int m0 = bm * 128;
    const int n0 = bn * 128;

    const int lm = lane & 15;
    const int kq = (lane >> 4) * 8;

    floatx4 acc[4][4];
#pragma unroll
    for (int i = 0; i < 4; ++i)
#pragma unroll
        for (int j = 0; j < 4; ++j)
            acc[i][j] = (floatx4){0.f, 0.f, 0.f, 0.f};

    for (int kt = 0; kt < K; kt += 64) {
        __syncthreads();
#pragma unroll
        for (int it = 0; it < 4; ++it) {
            int ch = tid + it * 256;
            int r = ch >> 3;
            int c = (ch & 7) * 8;
            gload_lds16(A  + (long)(m0 + r) * lda + (kt + c), &As[ch * 8]);
            gload_lds16(Bt + (long)(n0 + r) * ldb + (kt + c), &Bs[ch * 8]);
        }
        __syncthreads();
#pragma unroll
        for (int kk = 0; kk < 64; kk += 32) {
            bf16x8 af[4], bfv[4];
#pragma unroll
            for (int i = 0; i < 4; ++i)
                af[i] = *(const bf16x8*)&As[(wy * 64 + i * 16 + lm) * 64 + kk + kq];
#pragma unroll
            for (int j = 0; j < 4; ++j)
                bfv[j] = *(const bf16x8*)&Bs[(wx * 64 + j * 16 + lm) * 64 + kk + kq];
#pragma unroll
            for (int i = 0; i < 4; ++i)
#pragma unroll
                for (int j = 0; j < 4; ++j)
                    acc[i][j] = __builtin_amdgcn_mfma_f32_16x16x32_bf16(
                        af[i], bfv[j], acc[i][j], 0, 0, 0);
        }
    }

    const int cr = (lane >> 4) * 4;
    if constexpr (MODE == 1) {
#pragma unroll
        for (int j = 0; j < 4; ++j) {
            int col = n0 + wx * 64 + j * 16 + lm;
#pragma unroll
            for (int i = 0; i < 4; ++i)
#pragma unroll
                for (int r = 0; r < 4; ++r) {
                    int row = m0 + wy * 64 + i * 16 + cr + r;
                    C[(long)row * ldc + col] = __float2bfloat16(__expf(acc[i][j][r]));
                }
        }
    } else {
#pragma unroll
        for (int j = 0; j < 4; ++j) {
            int col = n0 + wx * 64 + j * 16 + lm;
            float bv = (MODE == 0 && bias) ? __bfloat162float(bias[col]) : 0.f;
            float sc = (col < qcols) ? scale : 1.0f;
#pragma unroll
            for (int i = 0; i < 4; ++i) {
#pragma unroll
                for (int r = 0; r < 4; ++r) {
                    int row = m0 + wy * 64 + i * 16 + cr + r;
                    long idx = (long)row * ldc + col;
                    float v;
                    if (MODE == 2) v = acc[i][j][r] + __bfloat162float(C[idx]);
                    else           v = (acc[i][j][r] + bv) * sc;
                    C[idx] = __float2bfloat16(v);
                }
            }
        }
    }
}

// ---------- split-K GEMM, bf16 partials (fallback tiers) ------------------
template <bool SWAP = false>
__global__ __launch_bounds__(256) void gemm_bt_splitk(
    const bf16* __restrict__ A, const bf16* __restrict__ Bt,
    bf16* __restrict__ P, int lda, int ldb, int ldp,
    long az, long bz, long pz, long skStride, int nsk, int Kc)
{
    __shared__ bf16 As[128 * 64];
    __shared__ bf16 Bs[128 * 64];

    const int tid  = threadIdx.x;
    const int lane = tid & 63;
    const int wave = tid >> 6;
    const int wx = wave & 1;
    const int wy = wave >> 1;
    const int zz = blockIdx.z;
    const int ks = zz % nsk;
    const int zh = zz / nsk;
    A  += (long)zh * az;
    Bt += (long)zh * bz;
    bf16* Pz = P + (long)zh * pz + (long)ks * skStride;
    const int bm = SWAP ? blockIdx.x : blockIdx.y;
    const int bn = SWAP ? blockIdx.y : blockIdx.x;
    const int m0 = bm * 128;
    const int n0 = bn * 128;
    const int k0 = ks * Kc;

    const int lm = lane & 15;
    const int kq = (lane >> 4) * 8;

    floatx4 acc[4][4];
#pragma unroll
    for (int i = 0; i < 4; ++i)
#pragma unroll
        for (int j = 0; j < 4; ++j)
            acc[i][j] = (floatx4){0.f, 0.f, 0.f, 0.f};

    for (int kt = k0; kt < k0 + Kc; kt += 64) {
        __syncthreads();
#pragma unroll
        for (int it = 0; it < 4; ++it) {
            int ch = tid + it * 256;
            int r = ch >> 3;
            int c = (ch & 7) * 8;
            gload_lds16(A  + (long)(m0 + r) * lda + (kt + c), &As[ch * 8]);
            gload_lds16(Bt + (long)(n0 + r) * ldb + (kt + c), &Bs[ch * 8]);
        }
        __syncthreads();
#pragma unroll
        for (int kk = 0; kk < 64; kk += 32) {
            bf16x8 af[4], bfv[4];
#pragma unroll
            for (int i = 0; i < 4; ++i)
                af[i] = *(const bf16x8*)&As[(wy * 64 + i * 16 + lm) * 64 + kk + kq];
#pragma unroll
            for (int j = 0; j < 4; ++j)
                bfv[j] = *(const bf16x8*)&Bs[(wx * 64 + j * 16 + lm) * 64 + kk + kq];
#pragma unroll
            for (int i = 0; i < 4; ++i)
#pragma unroll
                for (int j = 0; j < 4; ++j)
                    acc[i][j] = __builtin_amdgcn_mfma_f32_16x16x32_bf16(
                        af[i], bfv[j], acc[i][j], 0, 0, 0);
        }
    }

    const int cr = (lane >> 4) * 4;
#pragma unroll
    for (int j = 0; j < 4; ++j) {
        int col = n0 + wx * 64 + j * 16 + lm;
#pragma unroll
        for (int i = 0; i < 4; ++i)
#pragma unroll
            for (int r = 0; r < 4; ++r) {
                int row = m0 + wy * 64 + i * 16 + cr + r;
                Pz[(long)row * ldp + col] = __float2bfloat16(acc[i][j][r]);
            }
    }
}

// ---------- reduce 2 bf16 split-K partials + bias -> d_out in flag dtype ----
__global__ __launch_bounds__(256) void reduce_emit(
    const bf16* __restrict__ P, const bf16* __restrict__ bias,
    void* __restrict__ out, long MN, int N,
    const int* __restrict__ flag, long oofs)
{
    long i = ((long)blockIdx.x * 256 + threadIdx.x) * 8;
    if (i >= MN) return;
    bf16 bb[8], a[8], b[8];
    *(float4*)bb = *(const float4*)&bias[i & (N - 1)];
    *(float4*)a  = *(const float4*)&P[i];
    *(float4*)b  = *(const float4*)&P[MN + i];
    float s[8];
#pragma unroll
    for (int k = 0; k < 8; ++k)
        s[k] = __bfloat162float(bb[k]) + __bfloat162float(a[k]) + __bfloat162float(b[k]);
    if (*flag) {
        float* o = (float*)out + oofs + i;
        float4 lo = {s[0], s[1], s[2], s[3]};
        float4 hi = {s[4], s[5], s[6], s[7]};
        *(float4*)o = lo;
        *(float4*)(o + 4) = hi;
    } else {
        bf16 o[8];
#pragma unroll
        for (int k = 0; k < 8; ++k) o[k] = __float2bfloat16(s[k]);
        *(float4*)&((bf16*)out)[oofs + i] = *(float4*)o;
    }
}

// ---------- reduce bf16 split-K partials + bias -> bf16 (fallback) ----------
__global__ __launch_bounds__(256) void reduce_splitk(
    const bf16* __restrict__ P, const bf16* __restrict__ bias,
    bf16* __restrict__ Out, long MN, int N, int SK)
{
    long i = ((long)blockIdx.x * 256 + threadIdx.x) * 8;
    if (i >= MN) return;
    float s[8];
    if (bias) {
        bf16 bb[8];
        *(float4*)bb = *(const float4*)&bias[i & (N - 1)];
#pragma unroll
        for (int k = 0; k < 8; ++k) s[k] = __bfloat162float(bb[k]);
    } else {
#pragma unroll
        for (int k = 0; k < 8; ++k) s[k] = 0.f;
    }
    for (int z = 0; z < SK; ++z) {
        bf16 a[8];
        *(float4*)a = *(const float4*)&P[(long)z * MN + i];
#pragma unroll
        for (int k = 0; k < 8; ++k) s[k] += __bfloat162float(a[k]);
    }
    bf16 o[8];
#pragma unroll
    for (int k = 0; k < 8; ++k) o[k] = __float2bfloat16(s[k]);
    *(float4*)&Out[i] = *(float4*)o;
}

// ---------- in-place softmax over rows of 2048 bf16 (fallback tiers) -----
__global__ __launch_bounds__(256) void softmax_rows2048(bf16* __restrict__ S)
{
    __shared__ float red[8];
    const long row = blockIdx.x;
    bf16* p = S + row * 2048;
    const int tid = threadIdx.x;
    float4 raw = *(const float4*)&p[tid * 8];
    bf16 vb[8];
    *(float4*)vb = raw;
    float v[8];
#pragma unroll
    for (int i = 0; i < 8; ++i) v[i] = __bfloat162float(vb[i]);
    float m = v[0];
#pragma unroll
    for (int i = 1; i < 8; ++i) m = fmaxf(m, v[i]);
#pragma unroll
    for (int o = 32; o > 0; o >>= 1) m = fmaxf(m, __shfl_xor(m, o));
    if ((tid & 63) == 0) red[tid >> 6] = m;
    __syncthreads();
    m = fmaxf(fmaxf(red[0], red[1]), fmaxf(red[2], red[3]));
    float s = 0.f;
#pragma unroll
    for (int i = 0; i < 8; ++i) { v[i] = __expf(v[i] - m); s += v[i]; }
#pragma unroll
    for (int o = 32; o > 0; o >>= 1) s += __shfl_xor(s, o);
    if ((tid & 63) == 0) red[4 + (tid >> 6)] = s;
    __syncthreads();
    s = (red[4] + red[5]) + (red[6] + red[7]);
    float inv = 1.f / s;
#pragma unroll
    for (int i = 0; i < 8; ++i) vb[i] = __float2bfloat16(v[i] * inv);
    *(float4*)&p[tid * 8] = *(float4*)vb;
}

extern "C" void kernel_launch(void* const* d_in, const int* in_sizes, int n_in,
                              void* d_out, int out_size, void* d_ws, size_t ws_size,
                              hipStream_t stream)
{
    const int Bb = 4, T = 2048, E = 512, H = 8;
    const int HE = H * E;            // 4096
    const int N3 = 3 * HE;           // 12288
    const int N2 = 2 * HE;           // 8192 (Q|K row width)
    const int M  = Bb * T;           // 8192
    const long NX = (long)M * E;     // 4,194,304

    // ---- size-signature input assignment (order-robust) ----
    const void* xr = nullptr;
    const void* Wr[4] = {nullptr, nullptr, nullptr, nullptr};
    const void* br[3] = {nullptr, nullptr, nullptr};
    const void* bor = nullptr;
    int nw = 0, nb = 0;
    for (int i = 0; i < n_in; ++i) {
        int s = in_sizes[i];
        if      (s == (int)NX)      xr = d_in[i];
        else if (s == E * HE)       { if (nw < 4) Wr[nw++] = d_in[i]; }
        else if (s == HE)           { if (nb < 3) br[nb++] = d_in[i]; }
        else if (s == E)            bor = d_in[i];
    }
    if (!xr || nw < 4 || nb < 3 || !bor) {
        xr = d_in[0]; Wr[0] = d_in[1]; br[0] = d_in[2]; Wr[1] = d_in[3];
        br[1] = d_in[4]; Wr[2] = d_in[5]; br[2] = d_in[6]; Wr[3] = d_in[7];
        bor = d_in[8];
    }

    const float qscale = 0.04419417382415922f;  // 1/sqrt(512)
    const int   QC = 1 << 30;
    dim3 blk(256);

    // ---- workspace layout (bf16 elements) ----
    bf16* pool = (bf16*)d_ws;
    int*  flag = (int*)(void*)pool;
    bf16* xc   = pool + 8;
    bf16* bqc  = xc  + NX;
    bf16* bkc  = bqc + HE;
    bf16* bvc  = bkc + HE;
    bf16* boc  = bvc + HE;
    bf16* WqT  = boc + E;
    const size_t w2m = (size_t)E * HE;
    bf16* WkT  = WqT + w2m;
    bf16* WvT  = WkT + w2m;
    bf16* WoT  = WvT + w2m;
    bf16* Ofin = WoT + w2m;
    bf16* p0   = Ofin + NX;

    const size_t wsE    = ws_size / sizeof(bf16);
    const size_t fixedE = (size_t)(p0 - pool);
    const size_t preE   = (size_t)(Ofin - pool);   // fixed region w/o Ofin
    const size_t wQK   = (size_t)T * N2;
    const size_t wQKV  = (size_t)T * N3;
    const size_t wBat  = (size_t)T * HE;
    const size_t wHd   = (size_t)T * E;
    const size_t sAll  = (size_t)H * T * T;
    const size_t sOne  = (size_t)T * T;
    const size_t wBig  = (size_t)M * HE;
    const size_t wL    = 32768;   // fp32 L[H][T] as bf16-el units
    const size_t wL2   = 65536;   // fp32 L[2][H][T] as bf16-el units
    // Tier B3q (pair-merged QKV, batch-paired PV; Opair aliases QKb2[1]):
    //   preE + QKb2(2*wQK) + Vt2 + S2 + L2  ~= 248.1 MiB
    const size_t needB3q = preE + 2 * wQK + 2 * wBat + 2 * sAll + wL2;
    const size_t needB2 = fixedE + wQK + wBat + sAll + wBig + wL;  // ~208 MiB
    const size_t needB  = fixedE + wQKV + 2 * wBat + sAll;
    const size_t needC  = fixedE + 5 * wBat + sOne;
    const size_t needD  = fixedE + 5 * wHd  + sOne;
    if (wsE < needD) return;

    // ---- stage 0: dtype probe + canonicalize ----
    probe_dtype<<<dim3(1), blk, 0, stream>>>((const float*)xr, flag);
    convert_to_bf16<<<dim3((unsigned)((NX / 8 + 255) / 256)), blk, 0, stream>>>(
        xr, xc, NX, flag);
    convert_to_bf16<<<dim3(2), blk, 0, stream>>>(br[0], bqc, HE, flag);
    convert_to_bf16<<<dim3(2), blk, 0, stream>>>(br[1], bkc, HE, flag);
    convert_to_bf16<<<dim3(2), blk, 0, stream>>>(br[2], bvc, HE, flag);
    convert_to_bf16<<<dim3(1), blk, 0, stream>>>(bor, boc, E, flag);
    transpose_any<<<dim3(HE / 64, E / 64, 1), blk, 0, stream>>>(Wr[0], WqT, HE, E, flag);
    transpose_any<<<dim3(HE / 64, E / 64, 1), blk, 0, stream>>>(Wr[1], WkT, HE, E, flag);
    transpose_any<<<dim3(HE / 64, E / 64, 1), blk, 0, stream>>>(Wr[2], WvT, HE, E, flag);
    transpose_any<<<dim3(E / 64, HE / 64, 1), blk, 0, stream>>>(Wr[3], WoT, E, HE, flag);

    if (wsE >= needB3q) {
        // ---- Tier B3q: pair-merged QKV (768 blocks, 3 exact machine-waves),
        //      per-batch QK, batch-paired PV, per-pair out-proj+emit.
        //      QKb2 = [2][T][N2] contiguous; Opair aliases QKb2[1]
        //      (lifetimes disjoint); Ppair aliases S2. ----
        bf16* QKb2 = Ofin;                   // [2][T][N2] pair Q|K
        bf16* Vtb2 = QKb2 + 2 * wQK;         // 2 x [h,e,t]
        bf16* S2   = Vtb2 + 2 * wBat;        // 2 x exp(scores) [h,t,s]
        float* Lb2 = (float*)(S2 + 2 * sAll); // fp32 [2][H][T]
        bf16* Opair = QKb2 + wQK;            // pair O [2T, HE] (QKb2[1] dead)
        bf16* Ppair = S2;                    // split-K P (S2 dead)
        const long MpE = (long)2 * T * E;    // pair out elements

        for (int pb = 0; pb < Bb / 2; ++pb) {
            // merged QKV for the pair: M=4096, grid (48,16)=768 blocks
            gemm256<4, 2><<<dim3(N3 / 256, 2 * T / 256, 1), dim3(512), 0, stream>>>(
                xc + (size_t)pb * 2 * T * E, WqT, QKb2, bqc, E, E, N2,
                0, 0, 0, E, qscale, HE, Vtb2, N2, nullptr, (long)wBat);
            zero_f32<<<dim3(128), blk, 0, stream>>>(Lb2, 2 * H * T);
            for (int i = 0; i < 2; ++i) {
                gemm256<1, 1><<<dim3(T / 256, T / 256, H), dim3(512), 0, stream>>>(
                    QKb2 + (size_t)i * wQK + HE, QKb2 + (size_t)i * wQK,
                    S2 + (size_t)i * sAll, nullptr, N2, N2, T,
                    (long)E, (long)E, (long)T * T, E, 1.f, QC, nullptr, 0,
                    Lb2 + (size_t)i * H * T, 0);
            }
            // PV for both batches of the pair in one 256-block dispatch
            // (reads S2 + Vt2; writes Opair = QKb2[1], which is dead now)
            gemm_pv3<<<dim3(256, 1, 1), dim3(512), 0, stream>>>(
                Vtb2, S2, Opair, Lb2, T, T, HE,
                (long)E * T, (long)T * T, (long)E,
                (long)wBat, (long)sAll, (long)T * HE, T);
            // per-pair out-proj: split-K=2 via z; P lives in dead S2 region
            gemm128n<6, 7><<<dim3(2 * T / 256, E / 128, 2), dim3(512), 0, stream>>>(
                WoT, Opair, Ppair, nullptr, HE, HE, E,
                0, 0, MpE, HE / 2, HE / 2);
            reduce_emit<<<dim3((unsigned)((MpE / 8 + 255) / 256)), blk, 0, stream>>>(
                Ppair, boc, d_out, MpE, E, flag, (long)pb * MpE);
        }
        return;
    }

    if (wsE >= needB2) {
        // ---- Tier B2 fallback: single-batch QKV + PV (gemm128n<5,5>) ----
        bf16* QKb = p0;
        bf16* Vtb = QKb + wQK;
        bf16* S   = Vtb + wBat;
        bf16* Oatt = S + sAll;
        float* Lbuf = (float*)(Oatt + wBig);

        for (int b = 0; b < Bb; ++b) {
            const bf16* xb = xc + (size_t)b * T * E;
            gemm256<4, 2><<<dim3(N3 / 256, T / 256, 1), dim3(512), 0, stream>>>(
                xb, WqT, QKb, bqc, E, E, N2, 0, 0, 0, E, qscale, HE, Vtb, N2,
                nullptr, (long)wBat);
            zero_f32<<<dim3(64), blk, 0, stream>>>(Lbuf, H * T);
            gemm256<1, 1><<<dim3(T / 256, T / 256, H), dim3(512), 0, stream>>>(
                QKb + HE, QKb, S, nullptr, N2, N2, T,
                (long)E, (long)E, (long)T * T, E, 1.f, QC, nullptr, 0, Lbuf, 0);
            gemm128n<5, 5><<<dim3(T / 256, E / 128, H), dim3(512), 0, stream>>>(
                Vtb, S, Oatt + (size_t)b * T * HE, Lbuf, T, T, HE,
                (long)E * T, (long)T * T, (long)E, T, 0);
        }
        gemm128n<6, 6><<<dim3(M / 256, E / 128, 2), dim3(512), 0, stream>>>(
            WoT, Oatt, QKb, nullptr, HE, HE, E,
            0, 0, (long)M * E, HE / 2, HE / 2);
        reduce_emit<<<dim3((unsigned)((NX / 8 + 255) / 256)), blk, 0, stream>>>(
            QKb, boc, d_out, NX, E, flag, 0);
        return;
    }

    if (wsE >= needB) {
        // ---- Tier B fallback: softmax path ----
        bf16* QKVb = p0;
        bf16* Vtb  = QKVb + wQKV;
        bf16* Oatt = Vtb + wBat;
        bf16* S    = Oatt + wBat;

        for (int b = 0; b < Bb; ++b) {
            const bf16* xb = xc + (size_t)b * T * E;
            gemm_bt<0><<<dim3(N3 / 128, T / 128, 1), blk, 0, stream>>>(
                xb, WqT, QKVb, bqc, E, E, N3, 0, 0, 0, E, qscale, HE, nullptr, 0);
            transpose_bf16<<<dim3(E / 64, T / 64, H), blk, 0, stream>>>(
                QKVb + 2 * HE, Vtb, N3, T, H, (long)E, (long)E * T, 0, 0);
            gemm_bt<0><<<dim3(T / 128, T / 128, H), blk, 0, stream>>>(
                QKVb, QKVb + HE, S, nullptr, N3, N3, T,
                (long)E, (long)E, (long)T * T, E, 1.f, QC, nullptr, 0);
            softmax_rows2048<<<dim3(H * T, 1, 1), blk, 0, stream>>>(S);
            gemm_bt<0><<<dim3(E / 128, T / 128, H), blk, 0, stream>>>(
                S, Vtb, Oatt, nullptr, T, T, HE,
                (long)T * T, (long)E * T, (long)E, T, 1.f, QC, nullptr, 0);
            gemm_bt_splitk<false><<<dim3(E / 128, T / 128, 8), blk, 0, stream>>>(
                Oatt, WoT, (bf16*)S, HE, HE, E, 0, 0, 0, (long)T * E, 8, HE / 8);
            reduce_splitk<<<dim3((unsigned)(((long)T * E / 8 + 255) / 256)), blk, 0, stream>>>(
                (bf16*)S, boc, Ofin + (size_t)b * T * E, (long)T * E, E, 8);
        }
    } else if (wsE >= needC) {
        // ---- Tier C fallback ----
        bf16* Qb  = p0;
        bf16* Kb  = Qb  + wBat;
        bf16* Vb  = Kb  + wBat;
        bf16* Vtb = Vb  + wBat;
        bf16* Ob  = Vtb + wBat;
        bf16* S   = Ob  + wBat;

        for (int b = 0; b < Bb; ++b) {
            const bf16* xb = xc + (size_t)b * T * E;
            gemm_bt<0><<<dim3(HE / 128, T / 128, 1), blk, 0, stream>>>(
                xb, WqT, Qb, bqc, E, E, HE, 0, 0, 0, E, qscale, QC, nullptr, 0);
            gemm_bt<0><<<dim3(HE / 128, T / 128, 1), blk, 0, stream>>>(
                xb, WkT, Kb, bkc, E, E, HE, 0, 0, 0, E, 1.f, QC, nullptr, 0);
            gemm_bt<0><<<dim3(HE / 128, T / 128, 1), blk, 0, stream>>>(
                xb, WvT, Vb, bvc, E, E, HE, 0, 0, 0, E, 1.f, QC, nullptr, 0);
            transpose_bf16<<<dim3(E / 64, T / 64, H), blk, 0, stream>>>(
                Vb, Vtb, HE, T, H, (long)E, (long)E * T, 0, 0);
            for (int h = 0; h < H; ++h) {
                gemm_bt<0><<<dim3(T / 128, T / 128, 1), blk, 0, stream>>>(
                    Qb + (size_t)h * E, Kb + (size_t)h * E, S, nullptr,
                    HE, HE, T, 0, 0, 0, E, 1.f, QC, nullptr, 0);
                softmax_rows2048<<<dim3(T, 1, 1), blk, 0, stream>>>(S);
                gemm_bt<0><<<dim3(E / 128, T / 128, 1), blk, 0, stream>>>(
                    S, Vtb + (size_t)h * E * T, Ob + (size_t)h * E, nullptr,
                    T, T, HE, 0, 0, 0, T, 1.f, QC, nullptr, 0);
            }
            gemm_bt<0><<<dim3(E / 128, T / 128, 1), blk, 0, stream>>>(
                Ob, WoT, Ofin + (size_t)b * T * E, boc,
                HE, HE, E, 0, 0, 0, HE, 1.f, QC, nullptr, 0);
        }
    } else {
        // ---- Tier D fallback ----
        bf16* Qh  = p0;
        bf16* Kh  = Qh  + wHd;
        bf16* Vh  = Kh  + wHd;
        bf16* Vth = Vh  + wHd;
        bf16* Oh  = Vth + wHd;
        bf16* S   = Oh  + wHd;

        for (int b = 0; b < Bb; ++b) {
            const bf16* xb = xc + (size_t)b * T * E;
            bf16* outb = Ofin + (size_t)b * T * E;
            for (int h = 0; h < H; ++h) {
                const size_t hw = (size_t)h * E * E;
                gemm_bt<0><<<dim3(E / 128, T / 128, 1), blk, 0, stream>>>(
                    xb, WqT + hw, Qh, bqc + (size_t)h * E, E, E, E,
                    0, 0, 0, E, qscale, QC, nullptr, 0);
                gemm_bt<0><<<dim3(E / 128, T / 128, 1), blk, 0, stream>>>(
                    xb, WkT + hw, Kh, bkc + (size_t)h * E, E, E, E,
                    0, 0, 0, E, 1.f, QC, nullptr, 0);
                gemm_bt<0><<<dim3(E / 128, T / 128, 1), blk, 0, stream>>>(
                    xb, WvT + hw, Vh, bvc + (size_t)h * E, E, E, E,
                    0, 0, 0, E, 1.f, QC, nullptr, 0);
                transpose_bf16<<<dim3(E / 64, T / 64, 1), blk, 0, stream>>>(
                    Vh, Vth, E, T, 1, 0, 0, 0, 0);
                gemm_bt<0><<<dim3(T / 128, T / 128, 1), blk, 0, stream>>>(
                    Qh, Kh, S, nullptr, E, E, T, 0, 0, 0, E, 1.f, QC, nullptr, 0);
                softmax_rows2048<<<dim3(T, 1, 1), blk, 0, stream>>>(S);
                gemm_bt<0><<<dim3(E / 128, T / 128, 1), blk, 0, stream>>>(
                    S, Vth, Oh, nullptr, T, T, E, 0, 0, 0, T, 1.f, QC, nullptr, 0);
                if (h == 0)
                    gemm_bt<0><<<dim3(E / 128, T / 128, 1), blk, 0, stream>>>(
                        Oh, WoT, outb, boc, E, HE, E, 0, 0, 0, E, 1.f, QC, nullptr, 0);
                else
                    gemm_bt<2><<<dim3(E / 128, T / 128, 1), blk, 0, stream>>>(
                        Oh, WoT + (size_t)h * E, outb, nullptr,
                        E, HE, E, 0, 0, 0, E, 1.f, QC, nullptr, 0);
            }
        }
    }

    // ---- emit in the probed dtype (fallback tiers only) ----
    emit_out<<<dim3((unsigned)((NX / 8 + 255) / 256)), blk, 0, stream>>>(
        Ofin, d_out, NX, flag);
}